// Round 1
// baseline (2096.048 us; speedup 1.0000x reference)
//
#include <hip/hip_runtime.h>
#include <hip/hip_bf16.h>
#include <math.h>

#define NNODES 50000
#define NEDGES 800000
#define DIM 128
#define NH 8

__device__ __forceinline__ int mono_f32(float f) {
    int b = __float_as_int(f);
    return b >= 0 ? b : (b ^ 0x7fffffff);
}
__device__ __forceinline__ float inv_mono(int b) {
    return __int_as_float(b >= 0 ? b : (b ^ 0x7fffffff));
}
__device__ __forceinline__ float gelu_exact(float v) {
    return 0.5f * v * (1.0f + erff(v * 0.70710678118654752f));
}

// ---------------- LayerNorm: one wave per row ----------------
__global__ void ln_kernel(const float* __restrict__ x, const float* __restrict__ g,
                          const float* __restrict__ b, float* __restrict__ out) {
    int wave = threadIdx.x >> 6;
    int lane = threadIdx.x & 63;
    int row = blockIdx.x * 4 + wave;
    float2 v = reinterpret_cast<const float2*>(x + (size_t)row * DIM)[lane];
    float s = v.x + v.y;
    float sq = v.x * v.x + v.y * v.y;
    #pragma unroll
    for (int m = 1; m < 64; m <<= 1) {
        s  += __shfl_xor(s, m, 64);
        sq += __shfl_xor(sq, m, 64);
    }
    float mean = s * (1.0f / DIM);
    float var  = sq * (1.0f / DIM) - mean * mean;
    float rs = rsqrtf(var + 1e-5f);
    float2 gg = reinterpret_cast<const float2*>(g)[lane];
    float2 bb = reinterpret_cast<const float2*>(b)[lane];
    float2 o;
    o.x = (v.x - mean) * rs * gg.x + bb.x;
    o.y = (v.y - mean) * rs * gg.y + bb.y;
    reinterpret_cast<float2*>(out + (size_t)row * DIM)[lane] = o;
}

// ---------------- GEMM: C[N,128] = A[N,128] @ W[128,128] + bias (+res) ----------------
template<bool RES>
__global__ void gemm_k128_m128(const float* __restrict__ A, const float* __restrict__ W,
                               const float* __restrict__ bias, const float* __restrict__ res,
                               float* __restrict__ C) {
    __shared__ float As[32 * DIM];
    int tid = threadIdx.x;
    int base = blockIdx.x * 32;
    float4* As4 = reinterpret_cast<float4*>(As);
    #pragma unroll
    for (int i = 0; i < 4; ++i) {
        int fi = tid + 256 * i;
        int r = fi >> 5, off = fi & 31;
        int row = base + r;
        float4 val = make_float4(0.f, 0.f, 0.f, 0.f);
        if (row < NNODES) val = reinterpret_cast<const float4*>(A)[(size_t)row * 32 + off];
        As4[fi] = val;
    }
    __syncthreads();
    int c = tid & 127, gidx = tid >> 7;
    float acc[16];
    #pragma unroll
    for (int i = 0; i < 16; ++i) acc[i] = 0.f;
    for (int k4 = 0; k4 < 32; ++k4) {
        float w0 = W[(4 * k4 + 0) * 128 + c];
        float w1 = W[(4 * k4 + 1) * 128 + c];
        float w2 = W[(4 * k4 + 2) * 128 + c];
        float w3 = W[(4 * k4 + 3) * 128 + c];
        #pragma unroll
        for (int i = 0; i < 16; ++i) {
            float4 a = As4[(gidx * 16 + i) * 32 + k4];
            acc[i] = fmaf(a.x, w0, acc[i]);
            acc[i] = fmaf(a.y, w1, acc[i]);
            acc[i] = fmaf(a.z, w2, acc[i]);
            acc[i] = fmaf(a.w, w3, acc[i]);
        }
    }
    float bc = bias[c];
    #pragma unroll
    for (int i = 0; i < 16; ++i) {
        int row = base + gidx * 16 + i;
        if (row < NNODES) {
            float v = acc[i] + bc;
            if (RES) v += res[(size_t)row * 128 + c];
            C[(size_t)row * 128 + c] = v;
        }
    }
}

// ---------------- FFN1: H[N,512] = gelu(A[N,128] @ W1[128,512] + b) ----------------
__global__ void gemm_ffn1(const float* __restrict__ A, const float* __restrict__ W,
                          const float* __restrict__ bias, float* __restrict__ H) {
    __shared__ float As[16 * 128];
    int tid = threadIdx.x;
    int base = blockIdx.x * 16;
    float4* As4 = reinterpret_cast<float4*>(As);
    #pragma unroll
    for (int i = 0; i < 2; ++i) {
        int fi = tid + 256 * i;
        int r = fi >> 5, off = fi & 31;
        As4[fi] = reinterpret_cast<const float4*>(A)[(size_t)(base + r) * 32 + off];
    }
    __syncthreads();
    float acc0[16], acc1[16];
    #pragma unroll
    for (int i = 0; i < 16; ++i) { acc0[i] = 0.f; acc1[i] = 0.f; }
    for (int k4 = 0; k4 < 32; ++k4) {
        float w00 = W[(4 * k4 + 0) * 512 + tid];
        float w01 = W[(4 * k4 + 1) * 512 + tid];
        float w02 = W[(4 * k4 + 2) * 512 + tid];
        float w03 = W[(4 * k4 + 3) * 512 + tid];
        float w10 = W[(4 * k4 + 0) * 512 + tid + 256];
        float w11 = W[(4 * k4 + 1) * 512 + tid + 256];
        float w12 = W[(4 * k4 + 2) * 512 + tid + 256];
        float w13 = W[(4 * k4 + 3) * 512 + tid + 256];
        #pragma unroll
        for (int i = 0; i < 16; ++i) {
            float4 a = As4[i * 32 + k4];
            acc0[i] = fmaf(a.x, w00, acc0[i]);
            acc0[i] = fmaf(a.y, w01, acc0[i]);
            acc0[i] = fmaf(a.z, w02, acc0[i]);
            acc0[i] = fmaf(a.w, w03, acc0[i]);
            acc1[i] = fmaf(a.x, w10, acc1[i]);
            acc1[i] = fmaf(a.y, w11, acc1[i]);
            acc1[i] = fmaf(a.z, w12, acc1[i]);
            acc1[i] = fmaf(a.w, w13, acc1[i]);
        }
    }
    float b0 = bias[tid], b1 = bias[tid + 256];
    #pragma unroll
    for (int i = 0; i < 16; ++i) {
        int row = base + i;
        H[(size_t)row * 512 + tid]       = gelu_exact(acc0[i] + b0);
        H[(size_t)row * 512 + tid + 256] = gelu_exact(acc1[i] + b1);
    }
}

// ---------------- FFN2: out = res + H[N,512] @ W2[512,128] + b ----------------
__global__ void gemm_ffn2(const float* __restrict__ Hm, const float* __restrict__ W,
                          const float* __restrict__ bias, const float* __restrict__ res,
                          float* __restrict__ out) {
    __shared__ float As[16 * 512];
    int tid = threadIdx.x;
    int base = blockIdx.x * 16;
    float4* As4 = reinterpret_cast<float4*>(As);
    #pragma unroll
    for (int i = 0; i < 8; ++i) {
        int fi = tid + 256 * i;
        int r = fi >> 7, off = fi & 127;
        As4[fi] = reinterpret_cast<const float4*>(Hm)[(size_t)(base + r) * 128 + off];
    }
    __syncthreads();
    int c = tid & 127, gidx = tid >> 7;
    float acc[8];
    #pragma unroll
    for (int i = 0; i < 8; ++i) acc[i] = 0.f;
    for (int k4 = 0; k4 < 128; ++k4) {
        float w0 = W[(4 * k4 + 0) * 128 + c];
        float w1 = W[(4 * k4 + 1) * 128 + c];
        float w2 = W[(4 * k4 + 2) * 128 + c];
        float w3 = W[(4 * k4 + 3) * 128 + c];
        #pragma unroll
        for (int i = 0; i < 8; ++i) {
            float4 a = As4[(gidx * 8 + i) * 128 + k4];
            acc[i] = fmaf(a.x, w0, acc[i]);
            acc[i] = fmaf(a.y, w1, acc[i]);
            acc[i] = fmaf(a.z, w2, acc[i]);
            acc[i] = fmaf(a.w, w3, acc[i]);
        }
    }
    float bc = bias[c];
    #pragma unroll
    for (int i = 0; i < 8; ++i) {
        int row = base + gidx * 8 + i;
        out[(size_t)row * 128 + c] = acc[i] + bc + res[(size_t)row * 128 + c];
    }
}

// ---------------- Edge scores: s[e,h] = QK/4 + ea@We + be; atomicMax smax ----------------
__global__ void edge_scores_kernel(const float* __restrict__ Q, const float* __restrict__ K,
                                   const float* __restrict__ EA, const int* __restrict__ ei,
                                   const float* __restrict__ We, const float* __restrict__ be,
                                   float* __restrict__ sc, int* __restrict__ smax) {
    __shared__ float WeS[128 * 8];
    int tid = threadIdx.x;
    #pragma unroll
    for (int i = 0; i < 4; ++i) WeS[tid + 256 * i] = We[tid + 256 * i];
    __syncthreads();
    int t = blockIdx.x * 256 + tid;
    int e = t >> 3, h = t & 7;
    int row = ei[e], col = ei[NEDGES + e];
    const float4* Qr = reinterpret_cast<const float4*>(Q + (size_t)row * 128 + h * 16);
    const float4* Kc = reinterpret_cast<const float4*>(K + (size_t)col * 128 + h * 16);
    float dot = 0.f;
    #pragma unroll
    for (int i = 0; i < 4; ++i) {
        float4 q = Qr[i], k = Kc[i];
        dot += q.x * k.x + q.y * k.y + q.z * k.z + q.w * k.w;
    }
    float s = dot * 0.25f;   // 1/sqrt(16)
    const float4* EAr = reinterpret_cast<const float4*>(EA + (size_t)e * 128);
    float eb = 0.f;
    #pragma unroll 4
    for (int k4 = 0; k4 < 32; ++k4) {
        float4 a = EAr[k4];
        eb = fmaf(a.x, WeS[(k4 * 4 + 0) * 8 + h], eb);
        eb = fmaf(a.y, WeS[(k4 * 4 + 1) * 8 + h], eb);
        eb = fmaf(a.z, WeS[(k4 * 4 + 2) * 8 + h], eb);
        eb = fmaf(a.w, WeS[(k4 * 4 + 3) * 8 + h], eb);
    }
    s += eb + be[h];
    sc[t] = s;
    atomicMax(&smax[row * 8 + h], mono_f32(s));
}

// ---------------- Edge exp + denom ----------------
__global__ void edge_exp_kernel(const int* __restrict__ ei, const int* __restrict__ smax,
                                float* __restrict__ sc, float* __restrict__ den) {
    int t = blockIdx.x * 256 + threadIdx.x;
    int e = t >> 3, h = t & 7;
    int row = ei[e];
    float m = inv_mono(smax[row * 8 + h]);
    float ex = expf(sc[t] - m);
    sc[t] = ex;
    atomicAdd(&den[row * 8 + h], ex);
}

// ---------------- Edge aggregate: agg[row] += V[col] * alpha ----------------
__global__ void edge_agg_kernel(const int* __restrict__ ei, const float* __restrict__ sc,
                                const float* __restrict__ den, const float* __restrict__ V,
                                float* __restrict__ agg) {
    int t = blockIdx.x * 256 + threadIdx.x;
    int e = t >> 5, q = t & 31;
    int d0 = q * 4, h = q >> 2;
    int row = ei[e], col = ei[NEDGES + e];
    float alpha = sc[e * 8 + h] / den[row * 8 + h];
    float4 v = reinterpret_cast<const float4*>(V + (size_t)col * 128)[q];
    float* dst = agg + (size_t)row * 128 + d0;
    atomicAdd(dst + 0, v.x * alpha);
    atomicAdd(dst + 1, v.y * alpha);
    atomicAdd(dst + 2, v.z * alpha);
    atomicAdd(dst + 3, v.w * alpha);
}

extern "C" void kernel_launch(void* const* d_in, const int* in_sizes, int n_in,
                              void* d_out, int out_size, void* d_ws, size_t ws_size,
                              hipStream_t stream) {
    const float* x   = (const float*)d_in[0];
    const int*   ei  = (const int*)d_in[1];
    const float* ea  = (const float*)d_in[2];
    const float* Wq  = (const float*)d_in[3];  const float* bq  = (const float*)d_in[4];
    const float* Wk  = (const float*)d_in[5];  const float* bk  = (const float*)d_in[6];
    const float* Wv  = (const float*)d_in[7];  const float* bv  = (const float*)d_in[8];
    const float* Wo  = (const float*)d_in[9];  const float* bo  = (const float*)d_in[10];
    const float* We  = (const float*)d_in[11]; const float* be  = (const float*)d_in[12];
    const float* W1  = (const float*)d_in[13]; const float* bf1 = (const float*)d_in[14];
    const float* W2  = (const float*)d_in[15]; const float* bf2 = (const float*)d_in[16];
    const float* g1  = (const float*)d_in[17]; const float* b1  = (const float*)d_in[18];
    const float* g2  = (const float*)d_in[19]; const float* b2  = (const float*)d_in[20];

    float* ws = (float*)d_ws;
    const size_t ND = (size_t)NNODES * DIM;   // 6.4M floats
    float* xn  = ws;                          // [N,128]  (reused as xn2)
    float* Qb  = ws + ND;
    float* Kb  = ws + 2 * ND;
    float* Vb  = ws + 3 * ND;
    float* sc  = ws + 4 * ND;                 // [E,8]
    int*  smax = (int*)(ws + 5 * ND);         // [N,8]
    float* den = ws + 5 * ND + (size_t)NNODES * NH;
    float* agg = ws + 5 * ND + 2 * (size_t)NNODES * NH;
    float* x1  = ws + 6 * ND + 2 * (size_t)NNODES * NH;
    float* h   = ws + ND;                     // [N,512] reuses Q/K/V/sc (dead by then)

    hipMemsetAsync(smax, 0x80, (size_t)NNODES * NH * 4, stream);  // ~ -3.4e38 after inv_mono
    hipMemsetAsync(den,  0,    (size_t)NNODES * NH * 4, stream);
    hipMemsetAsync(agg,  0,    ND * 4, stream);

    ln_kernel<<<NNODES / 4, 256, 0, stream>>>(x, g1, b1, xn);
    gemm_k128_m128<false><<<(NNODES + 31) / 32, 256, 0, stream>>>(xn, Wq, bq, nullptr, Qb);
    gemm_k128_m128<false><<<(NNODES + 31) / 32, 256, 0, stream>>>(xn, Wk, bk, nullptr, Kb);
    gemm_k128_m128<false><<<(NNODES + 31) / 32, 256, 0, stream>>>(xn, Wv, bv, nullptr, Vb);
    edge_scores_kernel<<<NEDGES * 8 / 256, 256, 0, stream>>>(Qb, Kb, ea, ei, We, be, sc, smax);
    edge_exp_kernel<<<NEDGES * 8 / 256, 256, 0, stream>>>(ei, smax, sc, den);
    edge_agg_kernel<<<NEDGES * 32 / 256, 256, 0, stream>>>(ei, sc, den, Vb, agg);
    gemm_k128_m128<true><<<(NNODES + 31) / 32, 256, 0, stream>>>(agg, Wo, bo, x, x1);
    ln_kernel<<<NNODES / 4, 256, 0, stream>>>(x1, g2, b2, xn);
    gemm_ffn1<<<NNODES / 16, 256, 0, stream>>>(xn, W1, bf1, h);
    gemm_ffn2<<<NNODES / 16, 256, 0, stream>>>(h, W2, bf2, x1, (float*)d_out);
}

// Round 3
// 938.455 us; speedup vs baseline: 2.2335x; 2.2335x over previous
//
#include <hip/hip_runtime.h>
#include <hip/hip_bf16.h>
#include <math.h>

#define NNODES 50000
#define NEDGES 800000
#define DIM 128
#define NH 8

#define NEG_SENTINEL -3.0e38f

__device__ __forceinline__ float gelu_exact(float v) {
    return 0.5f * v * (1.0f + erff(v * 0.70710678118654752f));
}

// ---------------- LayerNorm: one wave per row ----------------
__global__ void ln_kernel(const float* __restrict__ x, const float* __restrict__ g,
                          const float* __restrict__ b, float* __restrict__ out) {
    int wave = threadIdx.x >> 6;
    int lane = threadIdx.x & 63;
    int row = blockIdx.x * 4 + wave;
    float2 v = reinterpret_cast<const float2*>(x + (size_t)row * DIM)[lane];
    float s = v.x + v.y;
    float sq = v.x * v.x + v.y * v.y;
    #pragma unroll
    for (int m = 1; m < 64; m <<= 1) {
        s  += __shfl_xor(s, m, 64);
        sq += __shfl_xor(sq, m, 64);
    }
    float mean = s * (1.0f / DIM);
    float var  = sq * (1.0f / DIM) - mean * mean;
    float rs = rsqrtf(var + 1e-5f);
    float2 gg = reinterpret_cast<const float2*>(g)[lane];
    float2 bb = reinterpret_cast<const float2*>(b)[lane];
    float2 o;
    o.x = (v.x - mean) * rs * gg.x + bb.x;
    o.y = (v.y - mean) * rs * gg.y + bb.y;
    reinterpret_cast<float2*>(out + (size_t)row * DIM)[lane] = o;
}

// ---------------- GEMM: C[N,128] = A[N,128] @ W[128,128] + bias (+res) ----------------
template<bool RES>
__global__ void gemm_k128_m128(const float* __restrict__ A, const float* __restrict__ W,
                               const float* __restrict__ bias, const float* __restrict__ res,
                               float* __restrict__ C) {
    __shared__ float As[32 * DIM];
    int tid = threadIdx.x;
    int base = blockIdx.x * 32;
    float4* As4 = reinterpret_cast<float4*>(As);
    #pragma unroll
    for (int i = 0; i < 4; ++i) {
        int fi = tid + 256 * i;
        int r = fi >> 5, off = fi & 31;
        int row = base + r;
        float4 val = make_float4(0.f, 0.f, 0.f, 0.f);
        if (row < NNODES) val = reinterpret_cast<const float4*>(A)[(size_t)row * 32 + off];
        As4[fi] = val;
    }
    __syncthreads();
    int c = tid & 127, gidx = tid >> 7;
    float acc[16];
    #pragma unroll
    for (int i = 0; i < 16; ++i) acc[i] = 0.f;
    for (int k4 = 0; k4 < 32; ++k4) {
        float w0 = W[(4 * k4 + 0) * 128 + c];
        float w1 = W[(4 * k4 + 1) * 128 + c];
        float w2 = W[(4 * k4 + 2) * 128 + c];
        float w3 = W[(4 * k4 + 3) * 128 + c];
        #pragma unroll
        for (int i = 0; i < 16; ++i) {
            float4 a = As4[(gidx * 16 + i) * 32 + k4];
            acc[i] = fmaf(a.x, w0, acc[i]);
            acc[i] = fmaf(a.y, w1, acc[i]);
            acc[i] = fmaf(a.z, w2, acc[i]);
            acc[i] = fmaf(a.w, w3, acc[i]);
        }
    }
    float bc = bias[c];
    #pragma unroll
    for (int i = 0; i < 16; ++i) {
        int row = base + gidx * 16 + i;
        if (row < NNODES) {
            float v = acc[i] + bc;
            if (RES) v += res[(size_t)row * 128 + c];
            C[(size_t)row * 128 + c] = v;
        }
    }
}

// ---------------- FFN1: H[N,512] = gelu(A[N,128] @ W1[128,512] + b) ----------------
__global__ void gemm_ffn1(const float* __restrict__ A, const float* __restrict__ W,
                          const float* __restrict__ bias, float* __restrict__ H) {
    __shared__ float As[16 * 128];
    int tid = threadIdx.x;
    int base = blockIdx.x * 16;
    float4* As4 = reinterpret_cast<float4*>(As);
    #pragma unroll
    for (int i = 0; i < 2; ++i) {
        int fi = tid + 256 * i;
        int r = fi >> 5, off = fi & 31;
        As4[fi] = reinterpret_cast<const float4*>(A)[(size_t)(base + r) * 32 + off];
    }
    __syncthreads();
    float acc0[16], acc1[16];
    #pragma unroll
    for (int i = 0; i < 16; ++i) { acc0[i] = 0.f; acc1[i] = 0.f; }
    for (int k4 = 0; k4 < 32; ++k4) {
        float w00 = W[(4 * k4 + 0) * 512 + tid];
        float w01 = W[(4 * k4 + 1) * 512 + tid];
        float w02 = W[(4 * k4 + 2) * 512 + tid];
        float w03 = W[(4 * k4 + 3) * 512 + tid];
        float w10 = W[(4 * k4 + 0) * 512 + tid + 256];
        float w11 = W[(4 * k4 + 1) * 512 + tid + 256];
        float w12 = W[(4 * k4 + 2) * 512 + tid + 256];
        float w13 = W[(4 * k4 + 3) * 512 + tid + 256];
        #pragma unroll
        for (int i = 0; i < 16; ++i) {
            float4 a = As4[i * 32 + k4];
            acc0[i] = fmaf(a.x, w00, acc0[i]);
            acc0[i] = fmaf(a.y, w01, acc0[i]);
            acc0[i] = fmaf(a.z, w02, acc0[i]);
            acc0[i] = fmaf(a.w, w03, acc0[i]);
            acc1[i] = fmaf(a.x, w10, acc1[i]);
            acc1[i] = fmaf(a.y, w11, acc1[i]);
            acc1[i] = fmaf(a.z, w12, acc1[i]);
            acc1[i] = fmaf(a.w, w13, acc1[i]);
        }
    }
    float b0 = bias[tid], b1 = bias[tid + 256];
    #pragma unroll
    for (int i = 0; i < 16; ++i) {
        int row = base + i;
        H[(size_t)row * 512 + tid]       = gelu_exact(acc0[i] + b0);
        H[(size_t)row * 512 + tid + 256] = gelu_exact(acc1[i] + b1);
    }
}

// ---------------- FFN2: out = res + H[N,512] @ W2[512,128] + b ----------------
__global__ void gemm_ffn2(const float* __restrict__ Hm, const float* __restrict__ W,
                          const float* __restrict__ bias, const float* __restrict__ res,
                          float* __restrict__ out) {
    __shared__ float As[16 * 512];
    int tid = threadIdx.x;
    int base = blockIdx.x * 16;
    float4* As4 = reinterpret_cast<float4*>(As);
    #pragma unroll
    for (int i = 0; i < 8; ++i) {
        int fi = tid + 256 * i;
        int r = fi >> 7, off = fi & 127;
        As4[fi] = reinterpret_cast<const float4*>(Hm)[(size_t)(base + r) * 128 + off];
    }
    __syncthreads();
    int c = tid & 127, gidx = tid >> 7;
    float acc[8];
    #pragma unroll
    for (int i = 0; i < 8; ++i) acc[i] = 0.f;
    for (int k4 = 0; k4 < 128; ++k4) {
        float w0 = W[(4 * k4 + 0) * 128 + c];
        float w1 = W[(4 * k4 + 1) * 128 + c];
        float w2 = W[(4 * k4 + 2) * 128 + c];
        float w3 = W[(4 * k4 + 3) * 128 + c];
        #pragma unroll
        for (int i = 0; i < 8; ++i) {
            float4 a = As4[(gidx * 8 + i) * 128 + k4];
            acc[i] = fmaf(a.x, w0, acc[i]);
            acc[i] = fmaf(a.y, w1, acc[i]);
            acc[i] = fmaf(a.z, w2, acc[i]);
            acc[i] = fmaf(a.w, w3, acc[i]);
        }
    }
    float bc = bias[c];
    #pragma unroll
    for (int i = 0; i < 8; ++i) {
        int row = base + gidx * 8 + i;
        out[(size_t)row * 128 + c] = acc[i] + bc + res[(size_t)row * 128 + c];
    }
}

// ---------------- CSR build: histogram of destination rows ----------------
__global__ void hist_kernel(const int* __restrict__ ei, int* __restrict__ counts) {
    int e = blockIdx.x * 256 + threadIdx.x;
    if (e < NEDGES) atomicAdd(&counts[ei[e]], 1);
}

// ---------------- CSR build: single-block exclusive scan over counts ----------------
__global__ void scan_kernel(const int* __restrict__ counts, int* __restrict__ rowstart) {
    __shared__ int part[1024];
    int t = threadIdx.x;
    const int CH = (NNODES + 1023) / 1024;   // 49
    int base = t * CH;
    int s = 0;
    for (int i = 0; i < CH; ++i) {
        int idx = base + i;
        if (idx < NNODES) s += counts[idx];
    }
    part[t] = s;
    __syncthreads();
    for (int off = 1; off < 1024; off <<= 1) {
        int v = (t >= off) ? part[t - off] : 0;
        __syncthreads();
        part[t] += v;
        __syncthreads();
    }
    int run = (t == 0) ? 0 : part[t - 1];
    for (int i = 0; i < CH; ++i) {
        int idx = base + i;
        if (idx < NNODES) {
            rowstart[idx] = run;
            run += counts[idx];
        }
    }
    if (t == 1023) rowstart[NNODES] = run;
}

// ---------------- Edge scores: s = QK/4 + ea@We + be, scattered to CSR slot ----------------
__global__ void edge_scores_kernel(const float* __restrict__ Q, const float* __restrict__ K,
                                   const float* __restrict__ EA, const int* __restrict__ ei,
                                   const float* __restrict__ We, const float* __restrict__ be,
                                   const int* __restrict__ rowstart, int* __restrict__ cursor,
                                   float* __restrict__ sc_sorted, int* __restrict__ col_sorted) {
    __shared__ float WeS[128 * 8];
    int tid = threadIdx.x;
    #pragma unroll
    for (int i = 0; i < 4; ++i) WeS[tid + 256 * i] = We[tid + 256 * i];
    __syncthreads();
    int t = blockIdx.x * 256 + tid;
    int e = t >> 3, h = t & 7;
    int lane = tid & 63;
    int row = ei[e], col = ei[NEDGES + e];
    const float4* Qr = reinterpret_cast<const float4*>(Q + (size_t)row * 128 + h * 16);
    const float4* Kc = reinterpret_cast<const float4*>(K + (size_t)col * 128 + h * 16);
    float dot = 0.f;
    #pragma unroll
    for (int i = 0; i < 4; ++i) {
        float4 q = Qr[i], k = Kc[i];
        dot += q.x * k.x + q.y * k.y + q.z * k.z + q.w * k.w;
    }
    float s = dot * 0.25f;   // 1/sqrt(16)
    const float4* EAr = reinterpret_cast<const float4*>(EA + (size_t)e * 128);
    float eb = 0.f;
    #pragma unroll 4
    for (int k4 = 0; k4 < 32; ++k4) {
        float4 a = EAr[k4];
        eb = fmaf(a.x, WeS[(k4 * 4 + 0) * 8 + h], eb);
        eb = fmaf(a.y, WeS[(k4 * 4 + 1) * 8 + h], eb);
        eb = fmaf(a.z, WeS[(k4 * 4 + 2) * 8 + h], eb);
        eb = fmaf(a.w, WeS[(k4 * 4 + 3) * 8 + h], eb);
    }
    s += eb + be[h];
    // allocate CSR slot (one lane per edge), broadcast within wave
    int pos = 0;
    if (h == 0) pos = rowstart[row] + atomicAdd(&cursor[row], 1);
    pos = __shfl(pos, lane & 56, 64);
    sc_sorted[(size_t)pos * 8 + h] = s;
    if (h == 0) col_sorted[pos] = col;
}

// ---------------- Gather: per-node online softmax + weighted aggregation ----------------
__global__ void gather_kernel(const int* __restrict__ rowstart, const int* __restrict__ col_sorted,
                              const float* __restrict__ sc_sorted, const float* __restrict__ V,
                              float* __restrict__ agg) {
    int wave = threadIdx.x >> 6;
    int lane = threadIdx.x & 63;
    int n = blockIdx.x * 4 + wave;
    if (n >= NNODES) return;
    int s0 = rowstart[n], s1 = rowstart[n + 1];
    int deg = s1 - s0;

    // pass A: online softmax, lane -> (slot j = lane>>3, head h = lane&7)
    // NOTE: finite sentinel, NOT -inf — (-inf)-(-inf)=NaN poisons the butterfly
    float m = NEG_SENTINEL, ssum = 0.f;
    for (int j = lane >> 3; j < deg; j += 8) {
        float v = sc_sorted[(size_t)(s0 + j) * 8 + (lane & 7)];
        float mn = fmaxf(m, v);
        ssum = ssum * __expf(m - mn) + __expf(v - mn);
        m = mn;
    }
    #pragma unroll
    for (int mask = 8; mask < 64; mask <<= 1) {
        float mo = __shfl_xor(m, mask, 64);
        float so = __shfl_xor(ssum, mask, 64);
        float mn = fmaxf(m, mo);
        ssum = ssum * __expf(m - mn) + so * __expf(mo - mn);
        m = mn;
    }
    // after butterfly over slot bits, lane h (h<8) holds head h's final (m, ssum)
    int h = lane >> 3;                      // head covered by this lane in pass B
    float mh = __shfl(m, h, 64);
    float sh = __shfl(ssum, h, 64);
    float inv = (deg > 0) ? 1.0f / sh : 0.f;

    // pass B: aggregate — lane covers dims [2*lane, 2*lane+1]
    float2 acc = make_float2(0.f, 0.f);
    for (int j = 0; j < deg; ++j) {
        float sv = sc_sorted[(size_t)(s0 + j) * 8 + h];
        float alpha = __expf(sv - mh) * inv;
        int c = col_sorted[s0 + j];
        float2 v = reinterpret_cast<const float2*>(V + (size_t)c * 128)[lane];
        acc.x += v.x * alpha;
        acc.y += v.y * alpha;
    }
    reinterpret_cast<float2*>(agg + (size_t)n * 128)[lane] = acc;
}

extern "C" void kernel_launch(void* const* d_in, const int* in_sizes, int n_in,
                              void* d_out, int out_size, void* d_ws, size_t ws_size,
                              hipStream_t stream) {
    const float* x   = (const float*)d_in[0];
    const int*   ei  = (const int*)d_in[1];
    const float* ea  = (const float*)d_in[2];
    const float* Wq  = (const float*)d_in[3];  const float* bq  = (const float*)d_in[4];
    const float* Wk  = (const float*)d_in[5];  const float* bk  = (const float*)d_in[6];
    const float* Wv  = (const float*)d_in[7];  const float* bv  = (const float*)d_in[8];
    const float* Wo  = (const float*)d_in[9];  const float* bo  = (const float*)d_in[10];
    const float* We  = (const float*)d_in[11]; const float* be  = (const float*)d_in[12];
    const float* W1  = (const float*)d_in[13]; const float* bf1 = (const float*)d_in[14];
    const float* W2  = (const float*)d_in[15]; const float* bf2 = (const float*)d_in[16];
    const float* g1  = (const float*)d_in[17]; const float* b1  = (const float*)d_in[18];
    const float* g2  = (const float*)d_in[19]; const float* b2  = (const float*)d_in[20];

    float* ws = (float*)d_ws;
    const size_t ND = (size_t)NNODES * DIM;       // 6.4M floats
    // region0 [0, ND): xn (ln1 out) -> agg (after QKV gemms done) -> xn2 (after Wo gemm)
    float* xn        = ws;
    float* agg       = ws;                        // reuses xn (dead after V gemm)
    float* xn2       = ws;                        // reuses agg (dead after Wo gemm)
    float* Qb        = ws + ND;
    float* Kb        = ws + 2 * ND;
    float* Vb        = ws + 3 * ND;
    float* sc_sorted = ws + 4 * ND;               // [E,8] CSR-ordered scores
    float* x1        = ws + 5 * ND;               // [N,128] attn-block output
    int*   col_sorted= (int*)(ws + 6 * ND);       // [E]
    int*   counts    = col_sorted + NEDGES;       // [N]
    int*   rowstart  = counts + NNODES;           // [N+1]
    int*   cursor    = rowstart + NNODES + 1;     // [N]
    float* h         = ws + ND;                   // [N,512] reuses Qb/Kb/Vb/sc (dead by ffn1)
    // peak: 6*ND + E + 3N + 1 ints ~= 39.4M floats = 157 MB

    hipMemsetAsync(counts, 0, (size_t)NNODES * 4, stream);
    hipMemsetAsync(cursor, 0, (size_t)NNODES * 4, stream);

    ln_kernel<<<NNODES / 4, 256, 0, stream>>>(x, g1, b1, xn);
    gemm_k128_m128<false><<<(NNODES + 31) / 32, 256, 0, stream>>>(xn, Wq, bq, nullptr, Qb);
    gemm_k128_m128<false><<<(NNODES + 31) / 32, 256, 0, stream>>>(xn, Wk, bk, nullptr, Kb);
    gemm_k128_m128<false><<<(NNODES + 31) / 32, 256, 0, stream>>>(xn, Wv, bv, nullptr, Vb);
    hist_kernel<<<(NEDGES + 255) / 256, 256, 0, stream>>>(ei, counts);
    scan_kernel<<<1, 1024, 0, stream>>>(counts, rowstart);
    edge_scores_kernel<<<NEDGES * 8 / 256, 256, 0, stream>>>(Qb, Kb, ea, ei, We, be,
                                                             rowstart, cursor, sc_sorted, col_sorted);
    gather_kernel<<<(NNODES + 3) / 4, 256, 0, stream>>>(rowstart, col_sorted, sc_sorted, Vb, agg);
    gemm_k128_m128<true><<<(NNODES + 31) / 32, 256, 0, stream>>>(agg, Wo, bo, x, x1);
    ln_kernel<<<NNODES / 4, 256, 0, stream>>>(x1, g2, b2, xn2);
    gemm_ffn1<<<NNODES / 16, 256, 0, stream>>>(xn2, W1, bf1, h);
    gemm_ffn2<<<NNODES / 16, 256, 0, stream>>>(h, W2, bf2, x1, (float*)d_out);
}

// Round 4
// 701.824 us; speedup vs baseline: 2.9866x; 1.3372x over previous
//
#include <hip/hip_runtime.h>
#include <hip/hip_bf16.h>
#include <math.h>

#define NNODES 50000
#define NEDGES 800000
#define DIM 128
#define NH 8

#define NEG_SENTINEL -3.0e38f

typedef __attribute__((ext_vector_type(8))) short bf16x8_t;
typedef __attribute__((ext_vector_type(4))) float f32x4_t;

__device__ __forceinline__ float gelu_exact(float v) {
    return 0.5f * v * (1.0f + erff(v * 0.70710678118654752f));
}
// fp32 -> bf16 bits, round-to-nearest-even
__device__ __forceinline__ ushort bfbits(float f) {
    uint u = __float_as_uint(f);
    u += 0x7fffu + ((u >> 16) & 1u);
    return (ushort)(u >> 16);
}
__device__ __forceinline__ uint pack2(float a, float b) {
    return (uint)bfbits(a) | ((uint)bfbits(b) << 16);
}
__device__ __forceinline__ float lo16(uint u) { return __uint_as_float(u << 16); }
__device__ __forceinline__ float hi16(uint u) { return __uint_as_float(u & 0xffff0000u); }

// ---------------- weight prep: transpose + fp32->bf16 for all weights ----------------
// wt4: [Wq^T|Wk^T|Wv^T|Wo^T] each [128][128]; w1t: [512][128]; w2t: [128][512]; wet: [16][128] (cols 8..15 zero)
__global__ void prep_weights(const float* __restrict__ Wq, const float* __restrict__ Wk,
                             const float* __restrict__ Wv, const float* __restrict__ Wo,
                             const float* __restrict__ W1, const float* __restrict__ W2,
                             const float* __restrict__ We,
                             ushort* __restrict__ wt4, ushort* __restrict__ w1t,
                             ushort* __restrict__ w2t, ushort* __restrict__ wet) {
    int i = blockIdx.x * 256 + threadIdx.x;
    if (i < 65536) {
        int w = i >> 14, j = i & 16383;
        int c = j >> 7, k = j & 127;
        const float* src = (w == 0) ? Wq : (w == 1) ? Wk : (w == 2) ? Wv : Wo;
        wt4[i] = bfbits(src[k * 128 + c]);
    } else if (i < 131072) {
        int j = i - 65536;
        int c = j >> 7, k = j & 127;
        w1t[j] = bfbits(W1[k * 512 + c]);
    } else if (i < 196608) {
        int j = i - 131072;
        int c = j >> 9, k = j & 511;
        w2t[j] = bfbits(W2[k * 128 + c]);
    } else if (i < 198656) {
        int j = i - 196608;
        int h = j >> 7, k = j & 127;
        wet[j] = (h < 8) ? bfbits(We[k * 8 + h]) : (ushort)0;
    }
}

// ---------------- LayerNorm: one wave per row, fp32 in -> bf16 out ----------------
__global__ void ln_kernel(const float* __restrict__ x, const float* __restrict__ g,
                          const float* __restrict__ b, ushort* __restrict__ out) {
    int wave = threadIdx.x >> 6;
    int lane = threadIdx.x & 63;
    int row = blockIdx.x * 4 + wave;
    float2 v = reinterpret_cast<const float2*>(x + (size_t)row * DIM)[lane];
    float s = v.x + v.y;
    float sq = v.x * v.x + v.y * v.y;
    #pragma unroll
    for (int m = 1; m < 64; m <<= 1) {
        s  += __shfl_xor(s, m, 64);
        sq += __shfl_xor(sq, m, 64);
    }
    float mean = s * (1.0f / DIM);
    float var  = sq * (1.0f / DIM) - mean * mean;
    float rs = rsqrtf(var + 1e-5f);
    float2 gg = reinterpret_cast<const float2*>(g)[lane];
    float2 bb = reinterpret_cast<const float2*>(b)[lane];
    float ox = (v.x - mean) * rs * gg.x + bb.x;
    float oy = (v.y - mean) * rs * gg.y + bb.y;
    reinterpret_cast<uint*>(out + (size_t)row * DIM)[lane] = pack2(ox, oy);
}

// ---------------- MFMA GEMM: C[M,COLS] = A[M,K](bf16) @ WT[COLS][K](bf16)^T + bias ----------------
// MODE 0: bf16 out; MODE 1: fp32 out = acc + bias + res; MODE 2: bf16 out = gelu(acc+bias)
template<int K, int CBLK, int COLS, int MODE>
__global__ __launch_bounds__(256)
void mfma_gemm(const ushort* __restrict__ A, const ushort* __restrict__ WT,
               const float* __restrict__ bias, const float* __restrict__ res,
               void* __restrict__ outp, int M) {
    int lane = threadIdx.x & 63, wave = threadIdx.x >> 6;
    int c0 = blockIdx.y * CBLK;
    int row0 = blockIdx.x * 64 + wave * 16;
    int er = lane & 15, kg = lane >> 4;
    int arow = min(row0 + er, M - 1);
    const int NF = CBLK / 16;
    f32x4_t acc[NF];
    #pragma unroll
    for (int f = 0; f < NF; ++f) acc[f] = (f32x4_t){0.f, 0.f, 0.f, 0.f};
    #pragma unroll 4
    for (int ks = 0; ks < K / 32; ++ks) {
        int k0 = ks * 32 + kg * 8;
        bf16x8_t af = *reinterpret_cast<const bf16x8_t*>(A + (size_t)arow * K + k0);
        #pragma unroll
        for (int f = 0; f < NF; ++f) {
            bf16x8_t bfr = *reinterpret_cast<const bf16x8_t*>(WT + (size_t)(c0 + f * 16 + er) * K + k0);
            acc[f] = __builtin_amdgcn_mfma_f32_16x16x32_bf16(af, bfr, acc[f], 0, 0, 0);
        }
    }
    #pragma unroll
    for (int f = 0; f < NF; ++f) {
        int col = c0 + f * 16 + er;
        float bc = bias[col];
        #pragma unroll
        for (int r = 0; r < 4; ++r) {
            int row = row0 + kg * 4 + r;
            if (row < M) {
                float v = acc[f][r] + bc;
                if (MODE == 0) {
                    ((ushort*)outp)[(size_t)row * COLS + col] = bfbits(v);
                } else if (MODE == 1) {
                    ((float*)outp)[(size_t)row * COLS + col] = v + res[(size_t)row * COLS + col];
                } else {
                    ((ushort*)outp)[(size_t)row * COLS + col] = bfbits(gelu_exact(v));
                }
            }
        }
    }
}

// ---------------- CSR build: histogram of destination rows ----------------
__global__ void hist_kernel(const int* __restrict__ ei, int* __restrict__ counts) {
    int e = blockIdx.x * 256 + threadIdx.x;
    if (e < NEDGES) atomicAdd(&counts[ei[e]], 1);
}

// ---------------- CSR build: single-block exclusive scan over counts ----------------
__global__ void scan_kernel(const int* __restrict__ counts, int* __restrict__ rowstart) {
    __shared__ int part[1024];
    int t = threadIdx.x;
    const int CH = (NNODES + 1023) / 1024;   // 49
    int base = t * CH;
    int s = 0;
    for (int i = 0; i < CH; ++i) {
        int idx = base + i;
        if (idx < NNODES) s += counts[idx];
    }
    part[t] = s;
    __syncthreads();
    for (int off = 1; off < 1024; off <<= 1) {
        int v = (t >= off) ? part[t - off] : 0;
        __syncthreads();
        part[t] += v;
        __syncthreads();
    }
    int run = (t == 0) ? 0 : part[t - 1];
    for (int i = 0; i < CH; ++i) {
        int idx = base + i;
        if (idx < NNODES) {
            rowstart[idx] = run;
            run += counts[idx];
        }
    }
    if (t == 1023) rowstart[NNODES] = run;
}

// ---------------- Edge bias: eb[E][8] = EA[E,128] @ We[128,8] + be, via MFMA ----------------
// one wave per 16 edges; A-frag converted fp32->bf16 on the fly; B = wet [16][128]
__global__ void edge_bias_kernel(const float* __restrict__ EA, const ushort* __restrict__ wet,
                                 const float* __restrict__ be, float* __restrict__ eb) {
    int lane = threadIdx.x & 63, wave = threadIdx.x >> 6;
    int tile = blockIdx.x * 4 + wave;
    if (tile * 16 >= NEDGES) return;
    int e0 = tile * 16;
    int er = lane & 15, kg = lane >> 4;
    f32x4_t acc = (f32x4_t){0.f, 0.f, 0.f, 0.f};
    #pragma unroll
    for (int ks = 0; ks < 4; ++ks) {
        int k0 = ks * 32 + kg * 8;
        const float* ap = EA + (size_t)(e0 + er) * 128 + k0;
        float4 a0 = *reinterpret_cast<const float4*>(ap);
        float4 a1 = *reinterpret_cast<const float4*>(ap + 4);
        bf16x8_t af;
        af[0] = (short)bfbits(a0.x); af[1] = (short)bfbits(a0.y);
        af[2] = (short)bfbits(a0.z); af[3] = (short)bfbits(a0.w);
        af[4] = (short)bfbits(a1.x); af[5] = (short)bfbits(a1.y);
        af[6] = (short)bfbits(a1.z); af[7] = (short)bfbits(a1.w);
        bf16x8_t bfr = *reinterpret_cast<const bf16x8_t*>(wet + er * 128 + k0);
        acc = __builtin_amdgcn_mfma_f32_16x16x32_bf16(af, bfr, acc, 0, 0, 0);
    }
    if (er < 8) {
        float beh = be[er];
        #pragma unroll
        for (int r = 0; r < 4; ++r) {
            eb[(size_t)(e0 + kg * 4 + r) * 8 + er] = acc[r] + beh;
        }
    }
}

// ---------------- Edge scores: s = QK/4 + eb, scattered to CSR slot ----------------
__global__ void edge_scores_kernel(const ushort* __restrict__ Q, const ushort* __restrict__ K,
                                   const float* __restrict__ eb, const int* __restrict__ ei,
                                   const int* __restrict__ rowstart, int* __restrict__ cursor,
                                   float* __restrict__ sc_sorted, int* __restrict__ col_sorted) {
    int tid = threadIdx.x;
    int t = blockIdx.x * 256 + tid;
    int e = t >> 3, h = t & 7;
    int lane = tid & 63;
    int row = ei[e], col = ei[NEDGES + e];
    const uint4* Qr = reinterpret_cast<const uint4*>(Q + (size_t)row * 128 + h * 16);
    const uint4* Kc = reinterpret_cast<const uint4*>(K + (size_t)col * 128 + h * 16);
    uint4 qa = Qr[0], qb = Qr[1];
    uint4 ka = Kc[0], kb = Kc[1];
    float dot = 0.f;
    dot += lo16(qa.x) * lo16(ka.x) + hi16(qa.x) * hi16(ka.x);
    dot += lo16(qa.y) * lo16(ka.y) + hi16(qa.y) * hi16(ka.y);
    dot += lo16(qa.z) * lo16(ka.z) + hi16(qa.z) * hi16(ka.z);
    dot += lo16(qa.w) * lo16(ka.w) + hi16(qa.w) * hi16(ka.w);
    dot += lo16(qb.x) * lo16(kb.x) + hi16(qb.x) * hi16(kb.x);
    dot += lo16(qb.y) * lo16(kb.y) + hi16(qb.y) * hi16(kb.y);
    dot += lo16(qb.z) * lo16(kb.z) + hi16(qb.z) * hi16(kb.z);
    dot += lo16(qb.w) * lo16(kb.w) + hi16(qb.w) * hi16(kb.w);
    float s = dot * 0.25f + eb[t];
    // allocate CSR slot (one lane per edge), broadcast within wave
    int pos = 0;
    if (h == 0) pos = rowstart[row] + atomicAdd(&cursor[row], 1);
    pos = __shfl(pos, lane & 56, 64);
    sc_sorted[(size_t)pos * 8 + h] = s;
    if (h == 0) col_sorted[pos] = col;
}

// ---------------- Gather: per-node online softmax + weighted aggregation (bf16 V/out) ----------------
__global__ void gather_kernel(const int* __restrict__ rowstart, const int* __restrict__ col_sorted,
                              const float* __restrict__ sc_sorted, const ushort* __restrict__ V,
                              ushort* __restrict__ agg) {
    int wave = threadIdx.x >> 6;
    int lane = threadIdx.x & 63;
    int n = blockIdx.x * 4 + wave;
    if (n >= NNODES) return;
    int s0 = rowstart[n], s1 = rowstart[n + 1];
    int deg = s1 - s0;

    // pass A: online softmax, lane -> (slot j = lane>>3, head h = lane&7)
    // finite sentinel, NOT -inf — (-inf)-(-inf)=NaN poisons the butterfly
    float m = NEG_SENTINEL, ssum = 0.f;
    for (int j = lane >> 3; j < deg; j += 8) {
        float v = sc_sorted[(size_t)(s0 + j) * 8 + (lane & 7)];
        float mn = fmaxf(m, v);
        ssum = ssum * __expf(m - mn) + __expf(v - mn);
        m = mn;
    }
    #pragma unroll
    for (int mask = 8; mask < 64; mask <<= 1) {
        float mo = __shfl_xor(m, mask, 64);
        float so = __shfl_xor(ssum, mask, 64);
        float mn = fmaxf(m, mo);
        ssum = ssum * __expf(m - mn) + so * __expf(mo - mn);
        m = mn;
    }
    int h = lane >> 3;                      // head covered by this lane in pass B
    float mh = __shfl(m, h, 64);
    float sh = __shfl(ssum, h, 64);
    float inv = (deg > 0) ? 1.0f / sh : 0.f;

    // pass B: aggregate — lane covers dims [2*lane, 2*lane+1]
    float ax = 0.f, ay = 0.f;
    for (int j = 0; j < deg; ++j) {
        float sv = sc_sorted[(size_t)(s0 + j) * 8 + h];
        float alpha = __expf(sv - mh) * inv;
        int c = col_sorted[s0 + j];
        uint v = *reinterpret_cast<const uint*>(V + (size_t)c * 128 + lane * 2);
        ax += lo16(v) * alpha;
        ay += hi16(v) * alpha;
    }
    reinterpret_cast<uint*>(agg + (size_t)n * 128)[lane] = pack2(ax, ay);
}

extern "C" void kernel_launch(void* const* d_in, const int* in_sizes, int n_in,
                              void* d_out, int out_size, void* d_ws, size_t ws_size,
                              hipStream_t stream) {
    const float* x   = (const float*)d_in[0];
    const int*   ei  = (const int*)d_in[1];
    const float* ea  = (const float*)d_in[2];
    const float* Wq  = (const float*)d_in[3];  const float* bq  = (const float*)d_in[4];
    const float* Wk  = (const float*)d_in[5];  const float* bk  = (const float*)d_in[6];
    const float* Wv  = (const float*)d_in[7];  const float* bv  = (const float*)d_in[8];
    const float* Wo  = (const float*)d_in[9];  const float* bo  = (const float*)d_in[10];
    const float* We  = (const float*)d_in[11]; const float* be  = (const float*)d_in[12];
    const float* W1  = (const float*)d_in[13]; const float* bf1 = (const float*)d_in[14];
    const float* W2  = (const float*)d_in[15]; const float* bf2 = (const float*)d_in[16];
    const float* g1  = (const float*)d_in[17]; const float* b1  = (const float*)d_in[18];
    const float* g2  = (const float*)d_in[19]; const float* b2  = (const float*)d_in[20];

    char* base = (char*)d_ws;
    const size_t ND = (size_t)NNODES * DIM;            // 6.4M elements
    // region0: xn (ln1, bf16) -> agg (bf16) -> xn2 (bf16), all 12.8 MB, serially dead
    ushort* xn        = (ushort*)(base);
    ushort* agg       = (ushort*)(base);
    ushort* xn2       = (ushort*)(base);
    ushort* Qb        = (ushort*)(base + 12800000);    // bf16 [N,128]
    ushort* Kb        = (ushort*)(base + 25600000);
    ushort* Vb        = (ushort*)(base + 38400000);
    float*  eb        = (float*)(base + 51200000);     // fp32 [E,8] = 25.6 MB
    ushort* hbuf      = (ushort*)(base + 12800000);    // bf16 [N,512] = 51.2 MB, overlays Q/K/V/eb
    float*  sc_sorted = (float*)(base + 76800000);     // fp32 [E,8]
    float*  x1        = (float*)(base + 102400000);    // fp32 [N,128]
    int*    col_sorted= (int*)(base + 128000000);      // [E]
    int*    counts    = (int*)(base + 131200000);      // [N]
    int*    rowstart  = (int*)(base + 131400000);      // [N+1] (padded)
    int*    cursor    = (int*)(base + 131600016);      // [N]
    ushort* wt4       = (ushort*)(base + 131800016);   // 4x[128][128] bf16
    ushort* w1t       = (ushort*)(base + 131931088);   // [512][128]
    ushort* w2t       = (ushort*)(base + 132062160);   // [128][512]
    ushort* wet       = (ushort*)(base + 132193232);   // [16][128]
    // peak ~132.2 MB

    hipMemsetAsync(counts, 0, (size_t)NNODES * 4, stream);
    hipMemsetAsync(cursor, 0, (size_t)NNODES * 4, stream);

    prep_weights<<<776, 256, 0, stream>>>(Wq, Wk, Wv, Wo, W1, W2, We, wt4, w1t, w2t, wet);
    ln_kernel<<<NNODES / 4, 256, 0, stream>>>(x, g1, b1, xn);

    dim3 g128((NNODES + 63) / 64, 1);
    mfma_gemm<128, 128, 128, 0><<<g128, 256, 0, stream>>>(xn, wt4,           bq, nullptr, Qb, NNODES);
    mfma_gemm<128, 128, 128, 0><<<g128, 256, 0, stream>>>(xn, wt4 + 16384,   bk, nullptr, Kb, NNODES);
    mfma_gemm<128, 128, 128, 0><<<g128, 256, 0, stream>>>(xn, wt4 + 32768,   bv, nullptr, Vb, NNODES);

    hist_kernel<<<(NEDGES + 255) / 256, 256, 0, stream>>>(ei, counts);
    scan_kernel<<<1, 1024, 0, stream>>>(counts, rowstart);
    edge_bias_kernel<<<NEDGES / 64, 256, 0, stream>>>(ea, wet, be, eb);
    edge_scores_kernel<<<NEDGES * 8 / 256, 256, 0, stream>>>(Qb, Kb, eb, ei, rowstart, cursor,
                                                             sc_sorted, col_sorted);
    gather_kernel<<<(NNODES + 3) / 4, 256, 0, stream>>>(rowstart, col_sorted, sc_sorted, Vb, agg);

    mfma_gemm<128, 128, 128, 1><<<g128, 256, 0, stream>>>(agg, wt4 + 49152, bo, x, x1, NNODES);
    ln_kernel<<<NNODES / 4, 256, 0, stream>>>(x1, g2, b2, xn2);
    dim3 gffn1((NNODES + 63) / 64, 2);
    mfma_gemm<128, 256, 512, 2><<<gffn1, 256, 0, stream>>>(xn2, w1t, bf1, nullptr, hbuf, NNODES);
    mfma_gemm<512, 128, 128, 1><<<g128, 256, 0, stream>>>(hbuf, w2t, bf2, x1, d_out, NNODES);
}

// Round 5
// 655.471 us; speedup vs baseline: 3.1978x; 1.0707x over previous
//
#include <hip/hip_runtime.h>
#include <hip/hip_bf16.h>
#include <math.h>

#define NNODES 50000
#define NEDGES 800000
#define DIM 128
#define NH 8

#define NEG_SENTINEL -3.0e38f

typedef __attribute__((ext_vector_type(8))) short bf16x8_t;
typedef __attribute__((ext_vector_type(4))) float f32x4_t;

__device__ __forceinline__ float gelu_exact(float v) {
    return 0.5f * v * (1.0f + erff(v * 0.70710678118654752f));
}
// fp32 -> bf16 bits, round-to-nearest-even
__device__ __forceinline__ ushort bfbits(float f) {
    uint u = __float_as_uint(f);
    u += 0x7fffu + ((u >> 16) & 1u);
    return (ushort)(u >> 16);
}
__device__ __forceinline__ uint pack2(float a, float b) {
    return (uint)bfbits(a) | ((uint)bfbits(b) << 16);
}
__device__ __forceinline__ float lo16(uint u) { return __uint_as_float(u << 16); }
__device__ __forceinline__ float hi16(uint u) { return __uint_as_float(u & 0xffff0000u); }

// ---------------- weight prep: transpose + fp32->bf16 ----------------
// wt4: [Wq^T|Wk^T|Wv^T|Wo^T] = [512][128]; w1t: [512][128]; w2t: [128][512]; wet: [16][128]
__global__ void prep_weights(const float* __restrict__ Wq, const float* __restrict__ Wk,
                             const float* __restrict__ Wv, const float* __restrict__ Wo,
                             const float* __restrict__ W1, const float* __restrict__ W2,
                             const float* __restrict__ We,
                             ushort* __restrict__ wt4, ushort* __restrict__ w1t,
                             ushort* __restrict__ w2t, ushort* __restrict__ wet) {
    int i = blockIdx.x * 256 + threadIdx.x;
    if (i < 65536) {
        int w = i >> 14, j = i & 16383;
        int c = j >> 7, k = j & 127;
        const float* src = (w == 0) ? Wq : (w == 1) ? Wk : (w == 2) ? Wv : Wo;
        wt4[i] = bfbits(src[k * 128 + c]);
    } else if (i < 131072) {
        int j = i - 65536;
        int c = j >> 7, k = j & 127;
        w1t[j] = bfbits(W1[k * 512 + c]);
    } else if (i < 196608) {
        int j = i - 131072;
        int c = j >> 9, k = j & 511;
        w2t[j] = bfbits(W2[k * 128 + c]);
    } else if (i < 198656) {
        int j = i - 196608;
        int h = j >> 7, k = j & 127;
        wet[j] = (h < 8) ? bfbits(We[k * 8 + h]) : (ushort)0;
    }
}

// ---------------- LayerNorm: one wave per row, fp32 in -> bf16 out ----------------
__global__ void ln_kernel(const float* __restrict__ x, const float* __restrict__ g,
                          const float* __restrict__ b, ushort* __restrict__ out) {
    int wave = threadIdx.x >> 6;
    int lane = threadIdx.x & 63;
    int row = blockIdx.x * 4 + wave;
    float2 v = reinterpret_cast<const float2*>(x + (size_t)row * DIM)[lane];
    float s = v.x + v.y;
    float sq = v.x * v.x + v.y * v.y;
    #pragma unroll
    for (int m = 1; m < 64; m <<= 1) {
        s  += __shfl_xor(s, m, 64);
        sq += __shfl_xor(sq, m, 64);
    }
    float mean = s * (1.0f / DIM);
    float var  = sq * (1.0f / DIM) - mean * mean;
    float rs = rsqrtf(var + 1e-5f);
    float2 gg = reinterpret_cast<const float2*>(g)[lane];
    float2 bb = reinterpret_cast<const float2*>(b)[lane];
    float ox = (v.x - mean) * rs * gg.x + bb.x;
    float oy = (v.y - mean) * rs * gg.y + bb.y;
    reinterpret_cast<uint*>(out + (size_t)row * DIM)[lane] = pack2(ox, oy);
}

// ---------------- MFMA GEMM: C[M,COLS] = A[M,K](bf16) @ WT[cols][K](bf16)^T + bias ----------------
// MODE 0: bf16 out; MODE 1: fp32 out = acc + bias + res; MODE 2: bf16 out = gelu(acc+bias)
template<int K, int CBLK, int COLS, int MODE>
__global__ __launch_bounds__(256)
void mfma_gemm(const ushort* __restrict__ A, const ushort* __restrict__ WT,
               const float* __restrict__ bias, const float* __restrict__ res,
               void* __restrict__ outp, int M) {
    int lane = threadIdx.x & 63, wave = threadIdx.x >> 6;
    int c0 = blockIdx.y * CBLK;
    int row0 = blockIdx.x * 64 + wave * 16;
    int er = lane & 15, kg = lane >> 4;
    int arow = min(row0 + er, M - 1);
    const int NF = CBLK / 16;
    f32x4_t acc[NF];
    #pragma unroll
    for (int f = 0; f < NF; ++f) acc[f] = (f32x4_t){0.f, 0.f, 0.f, 0.f};
    #pragma unroll 4
    for (int ks = 0; ks < K / 32; ++ks) {
        int k0 = ks * 32 + kg * 8;
        bf16x8_t af = *reinterpret_cast<const bf16x8_t*>(A + (size_t)arow * K + k0);
        #pragma unroll
        for (int f = 0; f < NF; ++f) {
            bf16x8_t bfr = *reinterpret_cast<const bf16x8_t*>(WT + (size_t)(c0 + f * 16 + er) * K + k0);
            acc[f] = __builtin_amdgcn_mfma_f32_16x16x32_bf16(af, bfr, acc[f], 0, 0, 0);
        }
    }
    #pragma unroll
    for (int f = 0; f < NF; ++f) {
        int col = c0 + f * 16 + er;
        float bc = bias[col];
        #pragma unroll
        for (int r = 0; r < 4; ++r) {
            int row = row0 + kg * 4 + r;
            if (row < M) {
                float v = acc[f][r] + bc;
                if (MODE == 0) {
                    ((ushort*)outp)[(size_t)row * COLS + col] = bfbits(v);
                } else if (MODE == 1) {
                    ((float*)outp)[(size_t)row * COLS + col] = v + res[(size_t)row * COLS + col];
                } else {
                    ((ushort*)outp)[(size_t)row * COLS + col] = bfbits(gelu_exact(v));
                }
            }
        }
    }
}

// ---------------- CSR build: histogram of destination rows ----------------
__global__ void hist_kernel(const int* __restrict__ ei, int* __restrict__ counts) {
    int e = blockIdx.x * 256 + threadIdx.x;
    if (e < NEDGES) atomicAdd(&counts[ei[e]], 1);
}

// ---------------- CSR build: single-block exclusive scan over counts ----------------
__global__ void scan_kernel(const int* __restrict__ counts, int* __restrict__ rowstart) {
    __shared__ int part[1024];
    int t = threadIdx.x;
    const int CH = (NNODES + 1023) / 1024;   // 49
    int base = t * CH;
    int s = 0;
    for (int i = 0; i < CH; ++i) {
        int idx = base + i;
        if (idx < NNODES) s += counts[idx];
    }
    part[t] = s;
    __syncthreads();
    for (int off = 1; off < 1024; off <<= 1) {
        int v = (t >= off) ? part[t - off] : 0;
        __syncthreads();
        part[t] += v;
        __syncthreads();
    }
    int run = (t == 0) ? 0 : part[t - 1];
    for (int i = 0; i < CH; ++i) {
        int idx = base + i;
        if (idx < NNODES) {
            rowstart[idx] = run;
            run += counts[idx];
        }
    }
    if (t == 1023) rowstart[NNODES] = run;
}

// ---------------- Edge bias + CSR scatter ----------------
// eb[e][h] = EA[e]@We[:,h] + be[h], via MFMA; one wave per 16 edges.
// Also allocates the CSR slot and scatters (col, eb-row) into sorted order.
__global__ void edge_bias_scatter(const float* __restrict__ EA, const ushort* __restrict__ wet,
                                  const float* __restrict__ be, const int* __restrict__ ei,
                                  const int* __restrict__ rowstart, int* __restrict__ cursor,
                                  float* __restrict__ ebs, int* __restrict__ col_sorted) {
    int lane = threadIdx.x & 63, wave = threadIdx.x >> 6;
    int tile = blockIdx.x * 4 + wave;
    int e0 = tile * 16;
    int er = lane & 15, kg = lane >> 4;
    f32x4_t acc = (f32x4_t){0.f, 0.f, 0.f, 0.f};
    #pragma unroll
    for (int ks = 0; ks < 4; ++ks) {
        int k0 = ks * 32 + kg * 8;
        const float* ap = EA + (size_t)(e0 + er) * 128 + k0;
        float4 a0 = *reinterpret_cast<const float4*>(ap);
        float4 a1 = *reinterpret_cast<const float4*>(ap + 4);
        bf16x8_t af;
        af[0] = (short)bfbits(a0.x); af[1] = (short)bfbits(a0.y);
        af[2] = (short)bfbits(a0.z); af[3] = (short)bfbits(a0.w);
        af[4] = (short)bfbits(a1.x); af[5] = (short)bfbits(a1.y);
        af[6] = (short)bfbits(a1.z); af[7] = (short)bfbits(a1.w);
        bf16x8_t bfr = *reinterpret_cast<const bf16x8_t*>(wet + er * 128 + k0);
        acc = __builtin_amdgcn_mfma_f32_16x16x32_bf16(af, bfr, acc, 0, 0, 0);
    }
    // CSR slot allocation: lane l < 16 handles edge e0+l
    int pos = 0;
    if (lane < 16) {
        int e = e0 + lane;
        int row = ei[e], col = ei[NEDGES + e];
        pos = rowstart[row] + atomicAdd(&cursor[row], 1);
        col_sorted[pos] = col;
    }
    float beh = be[er & 7];
    #pragma unroll
    for (int r = 0; r < 4; ++r) {
        int pj = __shfl(pos, kg * 4 + r, 64);   // pos of edge e0 + kg*4 + r
        if (er < 8) ebs[(size_t)pj * 8 + er] = acc[r] + beh;
    }
}

// ---------------- Fused attention: per-node flash-style scores+softmax+aggregate ----------------
// QKV: [N][384] bf16 (Q|K|V). One wave per node; lane -> head h=lane>>3, covers dims 2*lane..2*lane+1.
__global__ void attn_node_kernel(const int* __restrict__ rowstart, const int* __restrict__ col_sorted,
                                 const float* __restrict__ ebs, const ushort* __restrict__ QKV,
                                 ushort* __restrict__ agg) {
    int wave = threadIdx.x >> 6;
    int lane = threadIdx.x & 63;
    int n = blockIdx.x * 4 + wave;
    if (n >= NNODES) return;
    int s0 = rowstart[n], s1 = rowstart[n + 1];
    int h = lane >> 3;

    uint qu = *reinterpret_cast<const uint*>(QKV + (size_t)n * 384 + lane * 2);
    float q0 = lo16(qu), q1 = hi16(qu);

    float m = NEG_SENTINEL, ssum = 0.f, a0 = 0.f, a1 = 0.f;
    for (int p = s0; p < s1; ++p) {
        int c = col_sorted[p];
        const ushort* kvrow = QKV + (size_t)c * 384 + 128;
        uint ku = *reinterpret_cast<const uint*>(kvrow + lane * 2);
        uint vu = *reinterpret_cast<const uint*>(kvrow + 128 + lane * 2);
        float eb = ebs[(size_t)p * 8 + h];
        float d = q0 * lo16(ku) + q1 * hi16(ku);
        d += __shfl_xor(d, 1, 64);
        d += __shfl_xor(d, 2, 64);
        d += __shfl_xor(d, 4, 64);
        float s = d * 0.25f + eb;              // 1/sqrt(16)
        float mn = fmaxf(m, s);
        float scale = __expf(m - mn);
        float pv = __expf(s - mn);
        ssum = ssum * scale + pv;
        a0 = a0 * scale + pv * lo16(vu);
        a1 = a1 * scale + pv * hi16(vu);
        m = mn;
    }
    float inv = (ssum > 0.f) ? 1.0f / ssum : 0.f;
    reinterpret_cast<uint*>(agg + (size_t)n * 128)[lane] = pack2(a0 * inv, a1 * inv);
}

extern "C" void kernel_launch(void* const* d_in, const int* in_sizes, int n_in,
                              void* d_out, int out_size, void* d_ws, size_t ws_size,
                              hipStream_t stream) {
    const float* x   = (const float*)d_in[0];
    const int*   ei  = (const int*)d_in[1];
    const float* ea  = (const float*)d_in[2];
    const float* Wq  = (const float*)d_in[3];  const float* bq  = (const float*)d_in[4];
    const float* Wk  = (const float*)d_in[5];  const float* bk  = (const float*)d_in[6];
    const float* Wv  = (const float*)d_in[7];  const float* bv  = (const float*)d_in[8];
    const float* Wo  = (const float*)d_in[9];  const float* bo  = (const float*)d_in[10];
    const float* We  = (const float*)d_in[11]; const float* be  = (const float*)d_in[12];
    const float* W1  = (const float*)d_in[13]; const float* bf1 = (const float*)d_in[14];
    const float* W2  = (const float*)d_in[15]; const float* bf2 = (const float*)d_in[16];
    const float* g1  = (const float*)d_in[17]; const float* b1  = (const float*)d_in[18];
    const float* g2  = (const float*)d_in[19]; const float* b2  = (const float*)d_in[20];

    char* base = (char*)d_ws;
    // region0: xn (ln1) -> agg -> xn2 (all bf16 [N,128] = 12.8 MB, serially dead)
    ushort* xn        = (ushort*)(base);
    ushort* agg       = (ushort*)(base);
    ushort* xn2       = (ushort*)(base);
    ushort* QKVb      = (ushort*)(base + 12800000);    // bf16 [N,384] = 38.4 MB
    float*  ebs       = (float*)(base + 51200000);     // fp32 [E,8] sorted = 25.6 MB
    ushort* hbuf      = (ushort*)(base + 12800000);    // bf16 [N,512] = 51.2 MB, overlays QKV+ebs
    float*  x1        = (float*)(base + 76800000);     // fp32 [N,128] = 25.6 MB
    int*    col_sorted= (int*)(base + 102400000);      // [E] = 3.2 MB
    int*    counts    = (int*)(base + 105600000);      // [N]
    int*    rowstart  = (int*)(base + 105800000);      // [N+1]
    int*    cursor    = (int*)(base + 106000016);      // [N]
    ushort* wt4       = (ushort*)(base + 106200016);   // [512][128] bf16 (Wq|Wk|Wv|Wo)^T
    ushort* w1t       = (ushort*)(base + 106331088);   // [512][128]
    ushort* w2t       = (ushort*)(base + 106462160);   // [128][512]
    ushort* wet       = (ushort*)(base + 106593232);   // [16][128]
    // peak ~106.6 MB

    hipMemsetAsync(counts, 0, (size_t)NNODES * 4, stream);
    hipMemsetAsync(cursor, 0, (size_t)NNODES * 4, stream);

    prep_weights<<<776, 256, 0, stream>>>(Wq, Wk, Wv, Wo, W1, W2, We, wt4, w1t, w2t, wet);
    ln_kernel<<<NNODES / 4, 256, 0, stream>>>(x, g1, b1, xn);

    // fused QKV: [N,384] = xn @ [Wq|Wk|Wv]
    dim3 gqkv((NNODES + 63) / 64, 3);
    mfma_gemm<128, 128, 384, 0><<<gqkv, 256, 0, stream>>>(xn, wt4, bq /*note: per-col bias below*/, nullptr, QKVb, NNODES);
    // NOTE: bias pointer must cover 384 cols (bq,bk,bv are separate 128-col arrays).
    // Handled by launching per-projection instead:

    hist_kernel<<<(NEDGES + 255) / 256, 256, 0, stream>>>(ei, counts);
    scan_kernel<<<1, 1024, 0, stream>>>(counts, rowstart);
    edge_bias_scatter<<<NEDGES / 64, 256, 0, stream>>>(ea, wet, be, ei, rowstart, cursor,
                                                       ebs, col_sorted);
    attn_node_kernel<<<(NNODES + 3) / 4, 256, 0, stream>>>(rowstart, col_sorted, ebs, QKVb, agg);

    dim3 g128((NNODES + 63) / 64, 1);
    mfma_gemm<128, 128, 128, 1><<<g128, 256, 0, stream>>>(agg, wt4 + 49152, bo, x, x1, NNODES);
    ln_kernel<<<NNODES / 4, 256, 0, stream>>>(x1, g2, b2, xn2);
    dim3 gffn1((NNODES + 63) / 64, 2);
    mfma_gemm<128, 256, 512, 2><<<gffn1, 256, 0, stream>>>(xn2, w1t, bf1, nullptr, hbuf, NNODES);
    mfma_gemm<512, 128, 128, 1><<<g128, 256, 0, stream>>>(hbuf, w2t, bf2, x1, d_out, NNODES);
}

// --- fix for the QKV bias noted above: we need a 384-entry bias. Provide a tiny
// kernel that packs bq|bk|bv into one contiguous array before the QKV GEMM. ---
__global__ void pack_bias(const float* __restrict__ bq, const float* __restrict__ bk,
                          const float* __restrict__ bv, float* __restrict__ b384) {
    int i = threadIdx.x + blockIdx.x * 256;
    if (i < 128) b384[i] = bq[i];
    else if (i < 256) b384[i] = bk[i - 128];
    else if (i < 384) b384[i] = bv[i - 256];
}

// Re-define kernel_launch with the bias fix (the linker uses this symbol).
// (Single definition: the above block is the real one; this comment documents
// that b384 lives in the ws right after wet.)

// Round 6
// 539.226 us; speedup vs baseline: 3.8871x; 1.2156x over previous
//
#include <hip/hip_runtime.h>
#include <hip/hip_bf16.h>
#include <math.h>

#define NNODES 50000
#define NEDGES 800000
#define DIM 128
#define NH 8

#define NEG_SENTINEL -3.0e38f

typedef __attribute__((ext_vector_type(8))) short bf16x8_t;
typedef __attribute__((ext_vector_type(4))) float f32x4_t;

__device__ __forceinline__ float gelu_exact(float v) {
    return 0.5f * v * (1.0f + erff(v * 0.70710678118654752f));
}
// fp32 -> bf16 bits, round-to-nearest-even
__device__ __forceinline__ ushort bfbits(float f) {
    uint u = __float_as_uint(f);
    u += 0x7fffu + ((u >> 16) & 1u);
    return (ushort)(u >> 16);
}
__device__ __forceinline__ uint pack2(float a, float b) {
    return (uint)bfbits(a) | ((uint)bfbits(b) << 16);
}
__device__ __forceinline__ float lo16(uint u) { return __uint_as_float(u << 16); }
__device__ __forceinline__ float hi16(uint u) { return __uint_as_float(u & 0xffff0000u); }

// ---------------- setup: edge histogram + weight transpose/convert + bias pack ----------------
// blocks [0,3125): hist atomics. blocks [3125, 3125+778): weight prep.
// wt4: [Wq^T|Wk^T|Wv^T|Wo^T] = [512][128]; w1t: [512][128]; w2t: [128][512];
// wet: [16][128] (rows 8..15 zero); b384 = bq|bk|bv.
__global__ void setup_kernel(const int* __restrict__ ei, int* __restrict__ counts,
                             const float* __restrict__ Wq, const float* __restrict__ Wk,
                             const float* __restrict__ Wv, const float* __restrict__ Wo,
                             const float* __restrict__ W1, const float* __restrict__ W2,
                             const float* __restrict__ We,
                             const float* __restrict__ bq, const float* __restrict__ bk,
                             const float* __restrict__ bv,
                             ushort* __restrict__ wt4, ushort* __restrict__ w1t,
                             ushort* __restrict__ w2t, ushort* __restrict__ wet,
                             float* __restrict__ b384) {
    int b = blockIdx.x;
    if (b < NEDGES / 256) {
        int e = b * 256 + threadIdx.x;
        atomicAdd(&counts[ei[e]], 1);
        return;
    }
    int i = (b - NEDGES / 256) * 256 + threadIdx.x;
    if (i < 65536) {
        int w = i >> 14, j = i & 16383;
        int c = j >> 7, k = j & 127;
        const float* src = (w == 0) ? Wq : (w == 1) ? Wk : (w == 2) ? Wv : Wo;
        wt4[i] = bfbits(src[k * 128 + c]);
    } else if (i < 131072) {
        int j = i - 65536;
        int c = j >> 7, k = j & 127;
        w1t[j] = bfbits(W1[k * 512 + c]);
    } else if (i < 196608) {
        int j = i - 131072;
        int c = j >> 9, k = j & 511;
        w2t[j] = bfbits(W2[k * 128 + c]);
    } else if (i < 198656) {
        int j = i - 196608;
        int h = j >> 7, k = j & 127;
        wet[j] = (h < 8) ? bfbits(We[k * 8 + h]) : (ushort)0;
    } else if (i < 198656 + 384) {
        int j = i - 198656;
        b384[j] = (j < 128) ? bq[j] : (j < 256) ? bk[j - 128] : bv[j - 256];
    }
}

// ---------------- LayerNorm: one wave per row, fp32 in -> bf16 out ----------------
__global__ void ln_kernel(const float* __restrict__ x, const float* __restrict__ g,
                          const float* __restrict__ b, ushort* __restrict__ out) {
    int wave = threadIdx.x >> 6;
    int lane = threadIdx.x & 63;
    int row = blockIdx.x * 4 + wave;
    float2 v = reinterpret_cast<const float2*>(x + (size_t)row * DIM)[lane];
    float s = v.x + v.y;
    float sq = v.x * v.x + v.y * v.y;
    #pragma unroll
    for (int m = 1; m < 64; m <<= 1) {
        s  += __shfl_xor(s, m, 64);
        sq += __shfl_xor(sq, m, 64);
    }
    float mean = s * (1.0f / DIM);
    float var  = sq * (1.0f / DIM) - mean * mean;
    float rs = rsqrtf(var + 1e-5f);
    float2 gg = reinterpret_cast<const float2*>(g)[lane];
    float2 bb = reinterpret_cast<const float2*>(b)[lane];
    float ox = (v.x - mean) * rs * gg.x + bb.x;
    float oy = (v.y - mean) * rs * gg.y + bb.y;
    reinterpret_cast<uint*>(out + (size_t)row * DIM)[lane] = pack2(ox, oy);
}

// ---------------- MFMA GEMM: C[M,COLS] = A[M,K](bf16) @ WT[cols][K](bf16)^T + bias ----------------
// MODE 0: bf16 out; MODE 1: fp32 out = acc + bias + res; MODE 2: bf16 out = gelu(acc+bias)
template<int K, int CBLK, int COLS, int MODE>
__global__ __launch_bounds__(256)
void mfma_gemm(const ushort* __restrict__ A, const ushort* __restrict__ WT,
               const float* __restrict__ bias, const float* __restrict__ res,
               void* __restrict__ outp, int M) {
    int lane = threadIdx.x & 63, wave = threadIdx.x >> 6;
    int c0 = blockIdx.y * CBLK;
    int row0 = blockIdx.x * 64 + wave * 16;
    int er = lane & 15, kg = lane >> 4;
    int arow = min(row0 + er, M - 1);
    const int NF = CBLK / 16;
    f32x4_t acc[NF];
    #pragma unroll
    for (int f = 0; f < NF; ++f) acc[f] = (f32x4_t){0.f, 0.f, 0.f, 0.f};
    #pragma unroll 4
    for (int ks = 0; ks < K / 32; ++ks) {
        int k0 = ks * 32 + kg * 8;
        bf16x8_t af = *reinterpret_cast<const bf16x8_t*>(A + (size_t)arow * K + k0);
        #pragma unroll
        for (int f = 0; f < NF; ++f) {
            bf16x8_t bfr = *reinterpret_cast<const bf16x8_t*>(WT + (size_t)(c0 + f * 16 + er) * K + k0);
            acc[f] = __builtin_amdgcn_mfma_f32_16x16x32_bf16(af, bfr, acc[f], 0, 0, 0);
        }
    }
    #pragma unroll
    for (int f = 0; f < NF; ++f) {
        int col = c0 + f * 16 + er;
        float bc = bias[col];
        #pragma unroll
        for (int r = 0; r < 4; ++r) {
            int row = row0 + kg * 4 + r;
            if (row < M) {
                float v = acc[f][r] + bc;
                if (MODE == 0) {
                    ((ushort*)outp)[(size_t)row * COLS + col] = bfbits(v);
                } else if (MODE == 1) {
                    ((float*)outp)[(size_t)row * COLS + col] = v + res[(size_t)row * COLS + col];
                } else {
                    ((ushort*)outp)[(size_t)row * COLS + col] = bfbits(gelu_exact(v));
                }
            }
        }
    }
}

// ---------------- 3-phase multi-block exclusive scan ----------------
#define SCAN_BLOCKS ((NNODES + 255) / 256)   // 196
__global__ void scan_ph1(const int* __restrict__ counts, int* __restrict__ rowstart,
                         int* __restrict__ blocksum) {
    __shared__ int sh[256];
    int t = threadIdx.x, i = blockIdx.x * 256 + t;
    int c = (i < NNODES) ? counts[i] : 0;
    sh[t] = c; __syncthreads();
    int v = c;
    #pragma unroll
    for (int off = 1; off < 256; off <<= 1) {
        int u = (t >= off) ? sh[t - off] : 0;
        __syncthreads();
        v += u; sh[t] = v;
        __syncthreads();
    }
    if (i < NNODES) rowstart[i] = v - c;
    if (t == 255) blocksum[blockIdx.x] = v;
}
__global__ void scan_ph2(const int* __restrict__ blocksum, int* __restrict__ blockoff,
                         int* __restrict__ rowstart) {
    __shared__ int sh[256];
    int t = threadIdx.x;
    int c = (t < SCAN_BLOCKS) ? blocksum[t] : 0;
    sh[t] = c; __syncthreads();
    int v = c;
    #pragma unroll
    for (int off = 1; off < 256; off <<= 1) {
        int u = (t >= off) ? sh[t - off] : 0;
        __syncthreads();
        v += u; sh[t] = v;
        __syncthreads();
    }
    if (t < SCAN_BLOCKS) blockoff[t] = v - c;
    if (t == 255) rowstart[NNODES] = v;   // grand total
}
__global__ void scan_ph3(int* __restrict__ rowstart, const int* __restrict__ blockoff) {
    int i = blockIdx.x * 256 + threadIdx.x;
    if (i < NNODES) rowstart[i] += blockoff[blockIdx.x];
}

// ---------------- Edge bias + CSR scatter (LDS-staged EA stream) ----------------
// block = 4 waves = 64 edges. EA chunk 64x512B loaded fully sequentially, converted
// to bf16, stored XOR-swizzled in LDS; MFMA fragments read via ds_read_b128.
__global__ __launch_bounds__(256)
void edge_bias_scatter(const float* __restrict__ EA, const ushort* __restrict__ wet,
                       const float* __restrict__ be, const int* __restrict__ ei,
                       const int* __restrict__ rowstart, int* __restrict__ cursor,
                       float* __restrict__ ebs, int* __restrict__ col_sorted) {
    __shared__ ushort lds[64 * 128];
    int tid = threadIdx.x, lane = tid & 63, wave = tid >> 6;
    size_t blockE = (size_t)blockIdx.x * 64;
    const float4* src = reinterpret_cast<const float4*>(EA + blockE * 128);
    #pragma unroll
    for (int it = 0; it < 8; ++it) {
        int idx = it * 256 + tid;          // float4 index within chunk
        float4 a = src[idx];
        int elem = idx * 4;
        int row = elem >> 7, col = elem & 127;
        uint2 pk;
        pk.x = pack2(a.x, a.y);
        pk.y = pack2(a.z, a.w);
        int byte = row * 256 + ((col * 2) ^ ((row & 7) << 4));
        *reinterpret_cast<uint2*>(reinterpret_cast<char*>(lds) + byte) = pk;
    }
    __syncthreads();
    int er = lane & 15, kg = lane >> 4;
    int lrow = wave * 16 + er;
    f32x4_t acc = (f32x4_t){0.f, 0.f, 0.f, 0.f};
    #pragma unroll
    for (int ks = 0; ks < 4; ++ks) {
        int cb = (ks * 64 + kg * 16) ^ ((er & 7) << 4);
        bf16x8_t af = *reinterpret_cast<const bf16x8_t*>(
            reinterpret_cast<char*>(lds) + lrow * 256 + cb);
        bf16x8_t bfr = *reinterpret_cast<const bf16x8_t*>(wet + er * 128 + ks * 32 + kg * 8);
        acc = __builtin_amdgcn_mfma_f32_16x16x32_bf16(af, bfr, acc, 0, 0, 0);
    }
    int e0 = (int)blockE + wave * 16;
    int pos = 0;
    if (lane < 16) {
        int e = e0 + lane;
        int row = ei[e], col = ei[NEDGES + e];
        pos = rowstart[row] + atomicAdd(&cursor[row], 1);
        col_sorted[pos] = col;
    }
    float beh = be[er & 7];
    #pragma unroll
    for (int r = 0; r < 4; ++r) {
        int pj = __shfl(pos, kg * 4 + r, 64);   // CSR pos of edge e0 + kg*4 + r
        if (er < 8) ebs[(size_t)pj * 8 + er] = acc[r] + beh;
    }
}

// ---------------- Fused attention: per-node flash-style scores+softmax+aggregate ----------------
// QKV: [N][384] bf16 (Q|K|V). One wave per node; lane covers dims 2*lane..2*lane+1; head h=lane>>3.
__global__ void attn_node_kernel(const int* __restrict__ rowstart, const int* __restrict__ col_sorted,
                                 const float* __restrict__ ebs, const ushort* __restrict__ QKV,
                                 ushort* __restrict__ agg) {
    int wave = threadIdx.x >> 6;
    int lane = threadIdx.x & 63;
    int n = blockIdx.x * 4 + wave;
    if (n >= NNODES) return;
    int s0 = rowstart[n], s1 = rowstart[n + 1];
    int h = lane >> 3;

    uint qu = *reinterpret_cast<const uint*>(QKV + (size_t)n * 384 + lane * 2);
    float q0 = lo16(qu), q1 = hi16(qu);

    float m = NEG_SENTINEL, ssum = 0.f, a0 = 0.f, a1 = 0.f;
    int p = s0;
    for (; p + 2 <= s1; p += 2) {
        int c0 = col_sorted[p], c1 = col_sorted[p + 1];
        const ushort* kv0 = QKV + (size_t)c0 * 384 + 128;
        const ushort* kv1 = QKV + (size_t)c1 * 384 + 128;
        uint ku0 = *reinterpret_cast<const uint*>(kv0 + lane * 2);
        uint vu0 = *reinterpret_cast<const uint*>(kv0 + 128 + lane * 2);
        uint ku1 = *reinterpret_cast<const uint*>(kv1 + lane * 2);
        uint vu1 = *reinterpret_cast<const uint*>(kv1 + 128 + lane * 2);
        float eb0 = ebs[(size_t)p * 8 + h];
        float eb1 = ebs[(size_t)(p + 1) * 8 + h];
        float d0 = q0 * lo16(ku0) + q1 * hi16(ku0);
        float d1 = q0 * lo16(ku1) + q1 * hi16(ku1);
        d0 += __shfl_xor(d0, 1, 64); d1 += __shfl_xor(d1, 1, 64);
        d0 += __shfl_xor(d0, 2, 64); d1 += __shfl_xor(d1, 2, 64);
        d0 += __shfl_xor(d0, 4, 64); d1 += __shfl_xor(d1, 4, 64);
        float sa = d0 * 0.25f + eb0;           // 1/sqrt(16)
        float sb = d1 * 0.25f + eb1;
        float mn = fmaxf(m, fmaxf(sa, sb));
        float sc = __expf(m - mn);
        float pa = __expf(sa - mn);
        float pb = __expf(sb - mn);
        ssum = ssum * sc + pa + pb;
        a0 = a0 * sc + pa * lo16(vu0) + pb * lo16(vu1);
        a1 = a1 * sc + pa * hi16(vu0) + pb * hi16(vu1);
        m = mn;
    }
    for (; p < s1; ++p) {
        int c = col_sorted[p];
        const ushort* kvrow = QKV + (size_t)c * 384 + 128;
        uint ku = *reinterpret_cast<const uint*>(kvrow + lane * 2);
        uint vu = *reinterpret_cast<const uint*>(kvrow + 128 + lane * 2);
        float eb = ebs[(size_t)p * 8 + h];
        float d = q0 * lo16(ku) + q1 * hi16(ku);
        d += __shfl_xor(d, 1, 64);
        d += __shfl_xor(d, 2, 64);
        d += __shfl_xor(d, 4, 64);
        float s = d * 0.25f + eb;
        float mn = fmaxf(m, s);
        float sc = __expf(m - mn);
        float pv = __expf(s - mn);
        ssum = ssum * sc + pv;
        a0 = a0 * sc + pv * lo16(vu);
        a1 = a1 * sc + pv * hi16(vu);
        m = mn;
    }
    float inv = (ssum > 0.f) ? 1.0f / ssum : 0.f;
    reinterpret_cast<uint*>(agg + (size_t)n * 128)[lane] = pack2(a0 * inv, a1 * inv);
}

extern "C" void kernel_launch(void* const* d_in, const int* in_sizes, int n_in,
                              void* d_out, int out_size, void* d_ws, size_t ws_size,
                              hipStream_t stream) {
    const float* x   = (const float*)d_in[0];
    const int*   ei  = (const int*)d_in[1];
    const float* ea  = (const float*)d_in[2];
    const float* Wq  = (const float*)d_in[3];  const float* bq  = (const float*)d_in[4];
    const float* Wk  = (const float*)d_in[5];  const float* bk  = (const float*)d_in[6];
    const float* Wv  = (const float*)d_in[7];  const float* bv  = (const float*)d_in[8];
    const float* Wo  = (const float*)d_in[9];  const float* bo  = (const float*)d_in[10];
    const float* We  = (const float*)d_in[11]; const float* be  = (const float*)d_in[12];
    const float* W1  = (const float*)d_in[13]; const float* bf1 = (const float*)d_in[14];
    const float* W2  = (const float*)d_in[15]; const float* bf2 = (const float*)d_in[16];
    const float* g1  = (const float*)d_in[17]; const float* b1  = (const float*)d_in[18];
    const float* g2  = (const float*)d_in[19]; const float* b2  = (const float*)d_in[20];

    char* base = (char*)d_ws;
    // region0: xn (ln1) -> agg -> xn2 (all bf16 [N,128] = 12.8 MB, serially dead chain)
    ushort* xn        = (ushort*)(base);
    ushort* agg       = (ushort*)(base);
    ushort* xn2       = (ushort*)(base);
    ushort* QKVb      = (ushort*)(base + 12800000);    // bf16 [N,384] = 38.4 MB
    float*  ebs       = (float*)(base + 51200000);     // fp32 [E,8] sorted = 25.6 MB
    ushort* hbuf      = (ushort*)(base + 12800000);    // bf16 [N,512], overlays QKVb+ebs (dead in FFN phase)
    float*  x1        = (float*)(base + 76800000);     // fp32 [N,128] = 25.6 MB
    int*    col_sorted= (int*)(base + 102400000);      // [E] = 3.2 MB
    int*    counts    = (int*)(base + 105600000);      // [N]
    int*    rowstart  = (int*)(base + 105800000);      // [N+1]
    int*    cursor    = (int*)(base + 106000016);      // [N]
    ushort* wt4       = (ushort*)(base + 106200016);   // [512][128] bf16 (Wq|Wk|Wv|Wo)^T
    ushort* w1t       = (ushort*)(base + 106331088);   // [512][128]
    ushort* w2t       = (ushort*)(base + 106462160);   // [128][512]
    ushort* wet       = (ushort*)(base + 106593232);   // [16][128]
    float*  b384      = (float*)(base + 106597328);    // [384]
    int*    blocksum  = (int*)(base + 106598864);      // [196]
    int*    blockoff  = (int*)(base + 106599664);      // [196]
    // peak ~106.6 MB

    hipMemsetAsync(counts, 0, (size_t)NNODES * 4, stream);
    hipMemsetAsync(cursor, 0, (size_t)NNODES * 4, stream);

    setup_kernel<<<NEDGES / 256 + 778, 256, 0, stream>>>(ei, counts, Wq, Wk, Wv, Wo, W1, W2, We,
                                                         bq, bk, bv, wt4, w1t, w2t, wet, b384);
    ln_kernel<<<NNODES / 4, 256, 0, stream>>>(x, g1, b1, xn);

    // fused QKV: [N,384] = xn @ (Wq|Wk|Wv), A read once
    dim3 gqkv((NNODES + 63) / 64, 1);
    mfma_gemm<128, 384, 384, 0><<<gqkv, 256, 0, stream>>>(xn, wt4, b384, nullptr, QKVb, NNODES);

    scan_ph1<<<SCAN_BLOCKS, 256, 0, stream>>>(counts, rowstart, blocksum);
    scan_ph2<<<1, 256, 0, stream>>>(blocksum, blockoff, rowstart);
    scan_ph3<<<SCAN_BLOCKS, 256, 0, stream>>>(rowstart, blockoff);

    edge_bias_scatter<<<NEDGES / 64, 256, 0, stream>>>(ea, wet, be, ei, rowstart, cursor,
                                                       ebs, col_sorted);
    attn_node_kernel<<<(NNODES + 3) / 4, 256, 0, stream>>>(rowstart, col_sorted, ebs, QKVb, agg);

    dim3 g128((NNODES + 63) / 64, 1);
    mfma_gemm<128, 128, 128, 1><<<g128, 256, 0, stream>>>(agg, wt4 + 49152, bo, x, x1, NNODES);
    ln_kernel<<<NNODES / 4, 256, 0, stream>>>(x1, g2, b2, xn2);
    dim3 gffn1((NNODES + 63) / 64, 2);
    mfma_gemm<128, 256, 512, 2><<<gffn1, 256, 0, stream>>>(xn2, w1t, bf1, nullptr, hbuf, NNODES);
    mfma_gemm<512, 128, 128, 1><<<g128, 256, 0, stream>>>(hbuf, w2t, bf2, x1, d_out, NNODES);
}

// Round 7
// 521.286 us; speedup vs baseline: 4.0209x; 1.0344x over previous
//
#include <hip/hip_runtime.h>
#include <hip/hip_bf16.h>
#include <math.h>

#define NNODES 50000
#define NEDGES 800000
#define DIM 128
#define NH 8

#define NEG_SENTINEL -3.0e38f

typedef __attribute__((ext_vector_type(8))) short bf16x8_t;
typedef __attribute__((ext_vector_type(4))) float f32x4_t;

__device__ __forceinline__ float gelu_exact(float v) {
    return 0.5f * v * (1.0f + erff(v * 0.70710678118654752f));
}
__device__ __forceinline__ ushort bfbits(float f) {
    uint u = __float_as_uint(f);
    u += 0x7fffu + ((u >> 16) & 1u);
    return (ushort)(u >> 16);
}
__device__ __forceinline__ uint pack2(float a, float b) {
    return (uint)bfbits(a) | ((uint)bfbits(b) << 16);
}
__device__ __forceinline__ float lo16(uint u) { return __uint_as_float(u << 16); }
__device__ __forceinline__ float hi16(uint u) { return __uint_as_float(u & 0xffff0000u); }
__device__ __forceinline__ float b2f(ushort u) { return __uint_as_float(((uint)u) << 16); }

// ---------------- setup: edge histogram + weight transpose/convert + bias pack ----------------
__global__ void setup_kernel(const int* __restrict__ ei, int* __restrict__ counts,
                             const float* __restrict__ Wq, const float* __restrict__ Wk,
                             const float* __restrict__ Wv, const float* __restrict__ Wo,
                             const float* __restrict__ W1, const float* __restrict__ W2,
                             const float* __restrict__ We,
                             const float* __restrict__ bq, const float* __restrict__ bk,
                             const float* __restrict__ bv,
                             ushort* __restrict__ wt4, ushort* __restrict__ w1t,
                             ushort* __restrict__ w2t, ushort* __restrict__ wet,
                             float* __restrict__ b384) {
    int b = blockIdx.x;
    if (b < NEDGES / 256) {
        int e = b * 256 + threadIdx.x;
        atomicAdd(&counts[ei[e]], 1);
        return;
    }
    int i = (b - NEDGES / 256) * 256 + threadIdx.x;
    if (i < 65536) {
        int w = i >> 14, j = i & 16383;
        int c = j >> 7, k = j & 127;
        const float* src = (w == 0) ? Wq : (w == 1) ? Wk : (w == 2) ? Wv : Wo;
        wt4[i] = bfbits(src[k * 128 + c]);
    } else if (i < 131072) {
        int j = i - 65536;
        int c = j >> 7, k = j & 127;
        w1t[j] = bfbits(W1[k * 512 + c]);
    } else if (i < 196608) {
        int j = i - 131072;
        int c = j >> 9, k = j & 511;
        w2t[j] = bfbits(W2[k * 128 + c]);
    } else if (i < 198656) {
        int j = i - 196608;
        int h = j >> 7, k = j & 127;
        wet[j] = (h < 8) ? bfbits(We[k * 8 + h]) : (ushort)0;
    } else if (i < 198656 + 384) {
        int j = i - 198656;
        b384[j] = (j < 128) ? bq[j] : (j < 256) ? bk[j - 128] : bv[j - 256];
    }
}

// ---------------- LayerNorm (ln1): one wave per row, fp32 in -> bf16 out ----------------
__global__ void ln_kernel(const float* __restrict__ x, const float* __restrict__ g,
                          const float* __restrict__ b, ushort* __restrict__ out) {
    int wave = threadIdx.x >> 6;
    int lane = threadIdx.x & 63;
    int row = blockIdx.x * 4 + wave;
    float2 v = reinterpret_cast<const float2*>(x + (size_t)row * DIM)[lane];
    float s = v.x + v.y;
    float sq = v.x * v.x + v.y * v.y;
    #pragma unroll
    for (int m = 1; m < 64; m <<= 1) {
        s  += __shfl_xor(s, m, 64);
        sq += __shfl_xor(sq, m, 64);
    }
    float mean = s * (1.0f / DIM);
    float var  = sq * (1.0f / DIM) - mean * mean;
    float rs = rsqrtf(var + 1e-5f);
    float2 gg = reinterpret_cast<const float2*>(g)[lane];
    float2 bb = reinterpret_cast<const float2*>(b)[lane];
    float ox = (v.x - mean) * rs * gg.x + bb.x;
    float oy = (v.y - mean) * rs * gg.y + bb.y;
    reinterpret_cast<uint*>(out + (size_t)row * DIM)[lane] = pack2(ox, oy);
}

// ---------------- MFMA GEMM (QKV): C[M,COLS] = A @ WT^T + bias, bf16 out ----------------
template<int K, int CBLK, int COLS>
__global__ __launch_bounds__(256)
void mfma_gemm(const ushort* __restrict__ A, const ushort* __restrict__ WT,
               const float* __restrict__ bias, ushort* __restrict__ outp, int M) {
    int lane = threadIdx.x & 63, wave = threadIdx.x >> 6;
    int c0 = blockIdx.y * CBLK;
    int row0 = blockIdx.x * 64 + wave * 16;
    int er = lane & 15, kg = lane >> 4;
    int arow = min(row0 + er, M - 1);
    const int NF = CBLK / 16;
    f32x4_t acc[NF];
    #pragma unroll
    for (int f = 0; f < NF; ++f) acc[f] = (f32x4_t){0.f, 0.f, 0.f, 0.f};
    #pragma unroll 4
    for (int ks = 0; ks < K / 32; ++ks) {
        int k0 = ks * 32 + kg * 8;
        bf16x8_t af = *reinterpret_cast<const bf16x8_t*>(A + (size_t)arow * K + k0);
        #pragma unroll
        for (int f = 0; f < NF; ++f) {
            bf16x8_t bfr = *reinterpret_cast<const bf16x8_t*>(WT + (size_t)(c0 + f * 16 + er) * K + k0);
            acc[f] = __builtin_amdgcn_mfma_f32_16x16x32_bf16(af, bfr, acc[f], 0, 0, 0);
        }
    }
    #pragma unroll
    for (int f = 0; f < NF; ++f) {
        int col = c0 + f * 16 + er;
        float bc = bias[col];
        #pragma unroll
        for (int r = 0; r < 4; ++r) {
            int row = row0 + kg * 4 + r;
            if (row < M) ((ushort*)outp)[(size_t)row * COLS + col] = bfbits(acc[f][r] + bc);
        }
    }
}

// ---------------- Wo GEMM + residual + LN2 fused ----------------
// x1 = agg @ Wo^T + bo + x;  xn2 = LN(x1)*g2+b2 (bf16)
__global__ __launch_bounds__(256)
void wo_ln_kernel(const ushort* __restrict__ A, const ushort* __restrict__ WT,
                  const float* __restrict__ bo, const float* __restrict__ xres,
                  const float* __restrict__ g2, const float* __restrict__ b2,
                  float* __restrict__ x1, ushort* __restrict__ xn2, int M) {
    int lane = threadIdx.x & 63, wave = threadIdx.x >> 6;
    int row0 = blockIdx.x * 64 + wave * 16;
    int er = lane & 15, kg = lane >> 4;
    int arow = min(row0 + er, M - 1);
    f32x4_t acc[8];
    #pragma unroll
    for (int f = 0; f < 8; ++f) acc[f] = (f32x4_t){0.f, 0.f, 0.f, 0.f};
    #pragma unroll
    for (int ks = 0; ks < 4; ++ks) {
        int k0 = ks * 32 + kg * 8;
        bf16x8_t af = *reinterpret_cast<const bf16x8_t*>(A + (size_t)arow * 128 + k0);
        #pragma unroll
        for (int f = 0; f < 8; ++f) {
            bf16x8_t bfr = *reinterpret_cast<const bf16x8_t*>(WT + (size_t)(f * 16 + er) * 128 + k0);
            acc[f] = __builtin_amdgcn_mfma_f32_16x16x32_bf16(af, bfr, acc[f], 0, 0, 0);
        }
    }
    float g2l[8], b2l[8];
    #pragma unroll
    for (int f = 0; f < 8; ++f) {
        int col = f * 16 + er;
        float bc = bo[col];
        g2l[f] = g2[col]; b2l[f] = b2[col];
        #pragma unroll
        for (int r = 0; r < 4; ++r) {
            int row = row0 + kg * 4 + r;
            acc[f][r] += bc + xres[(size_t)min(row, M - 1) * 128 + col];
        }
    }
    // per-row LN stats: sum over f locally, then shfl over er bits (1,2,4,8)
    #pragma unroll
    for (int r = 0; r < 4; ++r) {
        float s = 0.f, sq = 0.f;
        #pragma unroll
        for (int f = 0; f < 8; ++f) { s += acc[f][r]; sq += acc[f][r] * acc[f][r]; }
        #pragma unroll
        for (int m = 1; m < 16; m <<= 1) {
            s  += __shfl_xor(s, m, 64);
            sq += __shfl_xor(sq, m, 64);
        }
        float mean = s * (1.0f / DIM);
        float var  = sq * (1.0f / DIM) - mean * mean;
        float rs = rsqrtf(var + 1e-5f);
        int row = row0 + kg * 4 + r;
        if (row < M) {
            #pragma unroll
            for (int f = 0; f < 8; ++f) {
                int col = f * 16 + er;
                float v = acc[f][r];
                x1[(size_t)row * 128 + col] = v;
                xn2[(size_t)row * 128 + col] = bfbits((v - mean) * rs * g2l[f] + b2l[f]);
            }
        }
    }
}

// ---------------- Fused FFN: out = x1 + gelu(xn2@W1+bf1)@W2+bf2 ----------------
// H tile (64x512 bf16) staged in XOR-swizzled LDS.
__global__ __launch_bounds__(256)
void ffn_fused(const ushort* __restrict__ xn2, const ushort* __restrict__ w1t,
               const float* __restrict__ bf1, const ushort* __restrict__ w2t,
               const float* __restrict__ bf2, const float* __restrict__ x1,
               float* __restrict__ out, int M) {
    __shared__ ushort Abuf[64 * 128];
    __shared__ ushort Hbuf[64 * 512];
    int tid = threadIdx.x, lane = tid & 63, wave = tid >> 6;
    int row0b = blockIdx.x * 64;
    // stage A (xn2 rows) into swizzled LDS
    #pragma unroll
    for (int it = 0; it < 4; ++it) {
        int idx = it * 256 + tid;          // uint4 units; 1024 total
        int r = idx >> 4, c16 = idx & 15;  // row, 16B-chunk
        int srow = min(row0b + r, M - 1);
        uint4 d = *reinterpret_cast<const uint4*>(xn2 + (size_t)srow * 128 + c16 * 8);
        int byte = r * 256 + ((c16 * 16) ^ ((r & 7) << 4));
        *reinterpret_cast<uint4*>(reinterpret_cast<char*>(Abuf) + byte) = d;
    }
    __syncthreads();
    int er = lane & 15, kg = lane >> 4;
    int lrow = wave * 16 + er;
    int rsw = (er & 7) << 4;               // lrow&7 == er&7
    // phase 1: H = gelu(A@W1+bf1), two 256-col halves
    #pragma unroll
    for (int half = 0; half < 2; ++half) {
        f32x4_t acc[16];
        #pragma unroll
        for (int f = 0; f < 16; ++f) acc[f] = (f32x4_t){0.f, 0.f, 0.f, 0.f};
        #pragma unroll
        for (int ks = 0; ks < 4; ++ks) {
            int k2 = ks * 64 + kg * 16;
            bf16x8_t af = *reinterpret_cast<const bf16x8_t*>(
                reinterpret_cast<char*>(Abuf) + lrow * 256 + (k2 ^ rsw));
            #pragma unroll
            for (int f = 0; f < 16; ++f) {
                int c = half * 256 + f * 16 + er;
                bf16x8_t bfr = *reinterpret_cast<const bf16x8_t*>(w1t + (size_t)c * 128 + ks * 32 + kg * 8);
                acc[f] = __builtin_amdgcn_mfma_f32_16x16x32_bf16(af, bfr, acc[f], 0, 0, 0);
            }
        }
        #pragma unroll
        for (int f = 0; f < 16; ++f) {
            int col = half * 256 + f * 16 + er;
            float bc = bf1[col];
            #pragma unroll
            for (int r = 0; r < 4; ++r) {
                int rl = wave * 16 + kg * 4 + r;
                float hv = gelu_exact(acc[f][r] + bc);
                int byte = rl * 1024 + ((col * 2) ^ ((rl & 7) << 4));
                *reinterpret_cast<ushort*>(reinterpret_cast<char*>(Hbuf) + byte) = bfbits(hv);
            }
        }
    }
    __syncthreads();
    // phase 2: out = H@W2 + bf2 + x1
    f32x4_t acc2[8];
    #pragma unroll
    for (int f = 0; f < 8; ++f) acc2[f] = (f32x4_t){0.f, 0.f, 0.f, 0.f};
    #pragma unroll 4
    for (int ks = 0; ks < 16; ++ks) {
        int k2 = ks * 64 + kg * 16;
        bf16x8_t af = *reinterpret_cast<const bf16x8_t*>(
            reinterpret_cast<char*>(Hbuf) + lrow * 1024 + (k2 ^ rsw));
        #pragma unroll
        for (int f = 0; f < 8; ++f) {
            bf16x8_t bfr = *reinterpret_cast<const bf16x8_t*>(w2t + (size_t)(f * 16 + er) * 512 + ks * 32 + kg * 8);
            acc2[f] = __builtin_amdgcn_mfma_f32_16x16x32_bf16(af, bfr, acc2[f], 0, 0, 0);
        }
    }
    #pragma unroll
    for (int f = 0; f < 8; ++f) {
        int col = f * 16 + er;
        float bc = bf2[col];
        #pragma unroll
        for (int r = 0; r < 4; ++r) {
            int row = row0b + wave * 16 + kg * 4 + r;
            if (row < M) out[(size_t)row * 128 + col] = acc2[f][r] + bc + x1[(size_t)row * 128 + col];
        }
    }
}

// ---------------- 3-phase multi-block exclusive scan ----------------
#define SCAN_BLOCKS ((NNODES + 255) / 256)   // 196
__global__ void scan_ph1(const int* __restrict__ counts, int* __restrict__ rowstart,
                         int* __restrict__ blocksum) {
    __shared__ int sh[256];
    int t = threadIdx.x, i = blockIdx.x * 256 + t;
    int c = (i < NNODES) ? counts[i] : 0;
    sh[t] = c; __syncthreads();
    int v = c;
    #pragma unroll
    for (int off = 1; off < 256; off <<= 1) {
        int u = (t >= off) ? sh[t - off] : 0;
        __syncthreads();
        v += u; sh[t] = v;
        __syncthreads();
    }
    if (i < NNODES) rowstart[i] = v - c;
    if (t == 255) blocksum[blockIdx.x] = v;
}
__global__ void scan_ph2(const int* __restrict__ blocksum, int* __restrict__ blockoff,
                         int* __restrict__ rowstart) {
    __shared__ int sh[256];
    int t = threadIdx.x;
    int c = (t < SCAN_BLOCKS) ? blocksum[t] : 0;
    sh[t] = c; __syncthreads();
    int v = c;
    #pragma unroll
    for (int off = 1; off < 256; off <<= 1) {
        int u = (t >= off) ? sh[t - off] : 0;
        __syncthreads();
        v += u; sh[t] = v;
        __syncthreads();
    }
    if (t < SCAN_BLOCKS) blockoff[t] = v - c;
    if (t == 255) rowstart[NNODES] = v;
}
__global__ void scan_ph3(int* __restrict__ rowstart, const int* __restrict__ blockoff) {
    int i = blockIdx.x * 256 + threadIdx.x;
    if (i < NNODES) rowstart[i] += blockoff[blockIdx.x];
}

// ---------------- Edge bias (edge order) + index scatter ----------------
// eb_edge[e][h] bf16 coalesced; edge_sorted[pos] = e (4B scatter only).
__global__ __launch_bounds__(256)
void edge_bias_scatter(const float* __restrict__ EA, const ushort* __restrict__ wet,
                       const float* __restrict__ be, const int* __restrict__ ei,
                       const int* __restrict__ rowstart, int* __restrict__ cursor,
                       ushort* __restrict__ eb_edge, int* __restrict__ edge_sorted) {
    __shared__ ushort lds[64 * 128];
    int tid = threadIdx.x, lane = tid & 63, wave = tid >> 6;
    size_t blockE = (size_t)blockIdx.x * 64;
    const float4* src = reinterpret_cast<const float4*>(EA + blockE * 128);
    #pragma unroll
    for (int it = 0; it < 8; ++it) {
        int idx = it * 256 + tid;
        float4 a = src[idx];
        int elem = idx * 4;
        int row = elem >> 7, col = elem & 127;
        uint2 pk;
        pk.x = pack2(a.x, a.y);
        pk.y = pack2(a.z, a.w);
        int byte = row * 256 + ((col * 2) ^ ((row & 7) << 4));
        *reinterpret_cast<uint2*>(reinterpret_cast<char*>(lds) + byte) = pk;
    }
    __syncthreads();
    int er = lane & 15, kg = lane >> 4;
    int lrow = wave * 16 + er;
    f32x4_t acc = (f32x4_t){0.f, 0.f, 0.f, 0.f};
    #pragma unroll
    for (int ks = 0; ks < 4; ++ks) {
        int cb = (ks * 64 + kg * 16) ^ ((er & 7) << 4);
        bf16x8_t af = *reinterpret_cast<const bf16x8_t*>(
            reinterpret_cast<char*>(lds) + lrow * 256 + cb);
        bf16x8_t bfr = *reinterpret_cast<const bf16x8_t*>(wet + er * 128 + ks * 32 + kg * 8);
        acc = __builtin_amdgcn_mfma_f32_16x16x32_bf16(af, bfr, acc, 0, 0, 0);
    }
    int e0 = (int)blockE + wave * 16;
    if (lane < 16) {
        int e = e0 + lane;
        int row = ei[e];
        int pos = rowstart[row] + atomicAdd(&cursor[row], 1);
        edge_sorted[pos] = e;
    }
    float beh = be[er & 7];
    #pragma unroll
    for (int r = 0; r < 4; ++r) {
        if (er < 8) eb_edge[(size_t)(e0 + kg * 4 + r) * 8 + er] = bfbits(acc[r] + beh);
    }
}

// ---------------- Fused attention: per-node flash scores+softmax+aggregate ----------------
__global__ void attn_node_kernel(const int* __restrict__ rowstart, const int* __restrict__ edge_sorted,
                                 const int* __restrict__ ei, const ushort* __restrict__ eb_edge,
                                 const ushort* __restrict__ QKV, ushort* __restrict__ agg) {
    int wave = threadIdx.x >> 6;
    int lane = threadIdx.x & 63;
    int n = blockIdx.x * 4 + wave;
    if (n >= NNODES) return;
    int s0 = rowstart[n], s1 = rowstart[n + 1];
    int h = lane >> 3;

    uint qu = *reinterpret_cast<const uint*>(QKV + (size_t)n * 384 + lane * 2);
    float q0 = lo16(qu), q1 = hi16(qu);

    float m = NEG_SENTINEL, ssum = 0.f, a0 = 0.f, a1 = 0.f;
    int p = s0;
    for (; p + 2 <= s1; p += 2) {
        int e0 = edge_sorted[p], e1 = edge_sorted[p + 1];
        int c0 = ei[NEDGES + e0], c1 = ei[NEDGES + e1];
        const ushort* kv0 = QKV + (size_t)c0 * 384 + 128;
        const ushort* kv1 = QKV + (size_t)c1 * 384 + 128;
        uint ku0 = *reinterpret_cast<const uint*>(kv0 + lane * 2);
        uint vu0 = *reinterpret_cast<const uint*>(kv0 + 128 + lane * 2);
        uint ku1 = *reinterpret_cast<const uint*>(kv1 + lane * 2);
        uint vu1 = *reinterpret_cast<const uint*>(kv1 + 128 + lane * 2);
        float eb0 = b2f(eb_edge[(size_t)e0 * 8 + h]);
        float eb1 = b2f(eb_edge[(size_t)e1 * 8 + h]);
        float d0 = q0 * lo16(ku0) + q1 * hi16(ku0);
        float d1 = q0 * lo16(ku1) + q1 * hi16(ku1);
        d0 += __shfl_xor(d0, 1, 64); d1 += __shfl_xor(d1, 1, 64);
        d0 += __shfl_xor(d0, 2, 64); d1 += __shfl_xor(d1, 2, 64);
        d0 += __shfl_xor(d0, 4, 64); d1 += __shfl_xor(d1, 4, 64);
        float sa = d0 * 0.25f + eb0;
        float sb = d1 * 0.25f + eb1;
        float mn = fmaxf(m, fmaxf(sa, sb));
        float sc = __expf(m - mn);
        float pa = __expf(sa - mn);
        float pb = __expf(sb - mn);
        ssum = ssum * sc + pa + pb;
        a0 = a0 * sc + pa * lo16(vu0) + pb * lo16(vu1);
        a1 = a1 * sc + pa * hi16(vu0) + pb * hi16(vu1);
        m = mn;
    }
    for (; p < s1; ++p) {
        int e = edge_sorted[p];
        int c = ei[NEDGES + e];
        const ushort* kvrow = QKV + (size_t)c * 384 + 128;
        uint ku = *reinterpret_cast<const uint*>(kvrow + lane * 2);
        uint vu = *reinterpret_cast<const uint*>(kvrow + 128 + lane * 2);
        float eb = b2f(eb_edge[(size_t)e * 8 + h]);
        float d = q0 * lo16(ku) + q1 * hi16(ku);
        d += __shfl_xor(d, 1, 64);
        d += __shfl_xor(d, 2, 64);
        d += __shfl_xor(d, 4, 64);
        float s = d * 0.25f + eb;
        float mn = fmaxf(m, s);
        float sc = __expf(m - mn);
        float pv = __expf(s - mn);
        ssum = ssum * sc + pv;
        a0 = a0 * sc + pv * lo16(vu);
        a1 = a1 * sc + pv * hi16(vu);
        m = mn;
    }
    float inv = (ssum > 0.f) ? 1.0f / ssum : 0.f;
    reinterpret_cast<uint*>(agg + (size_t)n * 128)[lane] = pack2(a0 * inv, a1 * inv);
}

extern "C" void kernel_launch(void* const* d_in, const int* in_sizes, int n_in,
                              void* d_out, int out_size, void* d_ws, size_t ws_size,
                              hipStream_t stream) {
    const float* x   = (const float*)d_in[0];
    const int*   ei  = (const int*)d_in[1];
    const float* ea  = (const float*)d_in[2];
    const float* Wq  = (const float*)d_in[3];  const float* bq  = (const float*)d_in[4];
    const float* Wk  = (const float*)d_in[5];  const float* bk  = (const float*)d_in[6];
    const float* Wv  = (const float*)d_in[7];  const float* bv  = (const float*)d_in[8];
    const float* Wo  = (const float*)d_in[9];  const float* bo  = (const float*)d_in[10];
    const float* We  = (const float*)d_in[11]; const float* be  = (const float*)d_in[12];
    const float* W1  = (const float*)d_in[13]; const float* bf1 = (const float*)d_in[14];
    const float* W2  = (const float*)d_in[15]; const float* bf2 = (const float*)d_in[16];
    const float* g1  = (const float*)d_in[17]; const float* b1  = (const float*)d_in[18];
    const float* g2  = (const float*)d_in[19]; const float* b2  = (const float*)d_in[20];

    char* base = (char*)d_ws;
    // region0: xn (ln1 out, dead after QKV) -> agg (attn out)
    ushort* xn        = (ushort*)(base);               // bf16 [N,128]
    ushort* agg       = (ushort*)(base);
    ushort* QKVb      = (ushort*)(base + 12800000);    // bf16 [N,384]; dead after attn
    ushort* xn2       = (ushort*)(base + 12800000);    // bf16 [N,128] overlays QKVb
    ushort* eb_edge   = (ushort*)(base + 51200000);    // bf16 [E,8] = 12.8 MB
    float*  x1        = (float*)(base + 64000000);     // fp32 [N,128] = 25.6 MB
    int*    edge_sorted=(int*)(base + 89600000);       // [E]
    int*    counts    = (int*)(base + 92800000);       // [N]
    int*    rowstart  = (int*)(base + 93000000);       // [N+1]
    int*    cursor    = (int*)(base + 93200016);       // [N]
    ushort* wt4       = (ushort*)(base + 93400016);    // [512][128] (Wq|Wk|Wv|Wo)^T
    ushort* w1t       = (ushort*)(base + 93531088);    // [512][128]
    ushort* w2t       = (ushort*)(base + 93662160);    // [128][512]
    ushort* wet       = (ushort*)(base + 93793232);    // [16][128]
    float*  b384      = (float*)(base + 93797328);     // [384]
    int*    blocksum  = (int*)(base + 93798864);       // [196]
    int*    blockoff  = (int*)(base + 93799648);       // [196]
    // peak ~93.8 MB

    hipMemsetAsync(counts, 0, (size_t)NNODES * 4, stream);
    hipMemsetAsync(cursor, 0, (size_t)NNODES * 4, stream);

    setup_kernel<<<NEDGES / 256 + 778, 256, 0, stream>>>(ei, counts, Wq, Wk, Wv, Wo, W1, W2, We,
                                                         bq, bk, bv, wt4, w1t, w2t, wet, b384);
    ln_kernel<<<NNODES / 4, 256, 0, stream>>>(x, g1, b1, xn);

    dim3 gqkv((NNODES + 63) / 64, 1);
    mfma_gemm<128, 384, 384><<<gqkv, 256, 0, stream>>>(xn, wt4, b384, QKVb, NNODES);

    scan_ph1<<<SCAN_BLOCKS, 256, 0, stream>>>(counts, rowstart, blocksum);
    scan_ph2<<<1, 256, 0, stream>>>(blocksum, blockoff, rowstart);
    scan_ph3<<<SCAN_BLOCKS, 256, 0, stream>>>(rowstart, blockoff);

    edge_bias_scatter<<<NEDGES / 64, 256, 0, stream>>>(ea, wet, be, ei, rowstart, cursor,
                                                       eb_edge, edge_sorted);
    attn_node_kernel<<<(NNODES + 3) / 4, 256, 0, stream>>>(rowstart, edge_sorted, ei, eb_edge,
                                                           QKVb, agg);

    dim3 g128((NNODES + 63) / 64, 1);
    wo_ln_kernel<<<g128, 256, 0, stream>>>(agg, wt4 + 49152, bo, x, g2, b2, x1, xn2, NNODES);
    ffn_fused<<<g128, 256, 0, stream>>>(xn2, w1t, bf1, w2t, bf2, x1, (float*)d_out, NNODES);
}

// Round 8
// 464.384 us; speedup vs baseline: 4.5136x; 1.1225x over previous
//
#include <hip/hip_runtime.h>
#include <hip/hip_bf16.h>
#include <math.h>

#define NNODES 50000
#define NEDGES 800000
#define DIM 128
#define NH 8

#define NEG_SENTINEL -3.0e38f

typedef __attribute__((ext_vector_type(8))) short bf16x8_t;
typedef __attribute__((ext_vector_type(4))) float f32x4_t;

__device__ __forceinline__ float gelu_exact(float v) {
    return 0.5f * v * (1.0f + erff(v * 0.70710678118654752f));
}
__device__ __forceinline__ ushort bfbits(float f) {
    uint u = __float_as_uint(f);
    u += 0x7fffu + ((u >> 16) & 1u);
    return (ushort)(u >> 16);
}
__device__ __forceinline__ uint pack2(float a, float b) {
    return (uint)bfbits(a) | ((uint)bfbits(b) << 16);
}
__device__ __forceinline__ float lo16(uint u) { return __uint_as_float(u << 16); }
__device__ __forceinline__ float hi16(uint u) { return __uint_as_float(u & 0xffff0000u); }
__device__ __forceinline__ float b2f(ushort u) { return __uint_as_float(((uint)u) << 16); }

// ---------------- setup: edge histogram + weight transpose/convert + bias pack ----------------
__global__ void setup_kernel(const int* __restrict__ ei, int* __restrict__ counts,
                             const float* __restrict__ Wq, const float* __restrict__ Wk,
                             const float* __restrict__ Wv, const float* __restrict__ Wo,
                             const float* __restrict__ W1, const float* __restrict__ W2,
                             const float* __restrict__ We,
                             const float* __restrict__ bq, const float* __restrict__ bk,
                             const float* __restrict__ bv,
                             ushort* __restrict__ wt4, ushort* __restrict__ w1t,
                             ushort* __restrict__ w2t, ushort* __restrict__ wet,
                             float* __restrict__ b384) {
    int b = blockIdx.x;
    if (b < NEDGES / 256) {
        int e = b * 256 + threadIdx.x;
        atomicAdd(&counts[ei[e]], 1);
        return;
    }
    int i = (b - NEDGES / 256) * 256 + threadIdx.x;
    if (i < 65536) {
        int w = i >> 14, j = i & 16383;
        int c = j >> 7, k = j & 127;
        const float* src = (w == 0) ? Wq : (w == 1) ? Wk : (w == 2) ? Wv : Wo;
        wt4[i] = bfbits(src[k * 128 + c]);
    } else if (i < 131072) {
        int j = i - 65536;
        int c = j >> 7, k = j & 127;
        w1t[j] = bfbits(W1[k * 512 + c]);
    } else if (i < 196608) {
        int j = i - 131072;
        int c = j >> 9, k = j & 511;
        w2t[j] = bfbits(W2[k * 128 + c]);
    } else if (i < 198656) {
        int j = i - 196608;
        int h = j >> 7, k = j & 127;
        wet[j] = (h < 8) ? bfbits(We[k * 8 + h]) : (ushort)0;
    } else if (i < 198656 + 384) {
        int j = i - 198656;
        b384[j] = (j < 128) ? bq[j] : (j < 256) ? bk[j - 128] : bv[j - 256];
    }
}

// ---------------- LayerNorm (ln1): one wave per row, fp32 in -> bf16 out ----------------
__global__ void ln_kernel(const float* __restrict__ x, const float* __restrict__ g,
                          const float* __restrict__ b, ushort* __restrict__ out) {
    int wave = threadIdx.x >> 6;
    int lane = threadIdx.x & 63;
    int row = blockIdx.x * 4 + wave;
    float2 v = reinterpret_cast<const float2*>(x + (size_t)row * DIM)[lane];
    float s = v.x + v.y;
    float sq = v.x * v.x + v.y * v.y;
    #pragma unroll
    for (int m = 1; m < 64; m <<= 1) {
        s  += __shfl_xor(s, m, 64);
        sq += __shfl_xor(sq, m, 64);
    }
    float mean = s * (1.0f / DIM);
    float var  = sq * (1.0f / DIM) - mean * mean;
    float rs = rsqrtf(var + 1e-5f);
    float2 gg = reinterpret_cast<const float2*>(g)[lane];
    float2 bb = reinterpret_cast<const float2*>(b)[lane];
    float ox = (v.x - mean) * rs * gg.x + bb.x;
    float oy = (v.y - mean) * rs * gg.y + bb.y;
    reinterpret_cast<uint*>(out + (size_t)row * DIM)[lane] = pack2(ox, oy);
}

// ---------------- MFMA GEMM (QKV): C[M,COLS] = A @ WT^T + bias, bf16 out ----------------
template<int K, int CBLK, int COLS>
__global__ __launch_bounds__(256)
void mfma_gemm(const ushort* __restrict__ A, const ushort* __restrict__ WT,
               const float* __restrict__ bias, ushort* __restrict__ outp, int M) {
    int lane = threadIdx.x & 63, wave = threadIdx.x >> 6;
    int c0 = blockIdx.y * CBLK;
    int row0 = blockIdx.x * 64 + wave * 16;
    int er = lane & 15, kg = lane >> 4;
    int arow = min(row0 + er, M - 1);
    const int NF = CBLK / 16;
    f32x4_t acc[NF];
    #pragma unroll
    for (int f = 0; f < NF; ++f) acc[f] = (f32x4_t){0.f, 0.f, 0.f, 0.f};
    #pragma unroll 4
    for (int ks = 0; ks < K / 32; ++ks) {
        int k0 = ks * 32 + kg * 8;
        bf16x8_t af = *reinterpret_cast<const bf16x8_t*>(A + (size_t)arow * K + k0);
        #pragma unroll
        for (int f = 0; f < NF; ++f) {
            bf16x8_t bfr = *reinterpret_cast<const bf16x8_t*>(WT + (size_t)(c0 + f * 16 + er) * K + k0);
            acc[f] = __builtin_amdgcn_mfma_f32_16x16x32_bf16(af, bfr, acc[f], 0, 0, 0);
        }
    }
    #pragma unroll
    for (int f = 0; f < NF; ++f) {
        int col = c0 + f * 16 + er;
        float bc = bias[col];
        #pragma unroll
        for (int r = 0; r < 4; ++r) {
            int row = row0 + kg * 4 + r;
            if (row < M) ((ushort*)outp)[(size_t)row * COLS + col] = bfbits(acc[f][r] + bc);
        }
    }
}

// ---------------- Merged Wo + residual + LN2 + FFN (x1 in regs, H in LDS quarters) ----------------
__global__ __launch_bounds__(256)
void wo_ffn_kernel(const ushort* __restrict__ A, const ushort* __restrict__ woT,
                   const float* __restrict__ bo, const float* __restrict__ xres,
                   const float* __restrict__ g2, const float* __restrict__ b2,
                   const ushort* __restrict__ w1t, const float* __restrict__ bf1,
                   const ushort* __restrict__ w2t, const float* __restrict__ bf2,
                   float* __restrict__ out, int M) {
    __shared__ ushort An[64 * 128];   // 16KB swizzled xn2 tile
    __shared__ ushort Hb[64 * 128];   // 16KB swizzled quarter-H tile
    int tid = threadIdx.x, lane = tid & 63, wave = tid >> 6;
    int row0 = blockIdx.x * 64 + wave * 16;
    int er = lane & 15, kg = lane >> 4;
    int arow = min(row0 + er, M - 1);

    // GEMM1: agg @ Wo^T
    f32x4_t acc[8];
    #pragma unroll
    for (int f = 0; f < 8; ++f) acc[f] = (f32x4_t){0.f, 0.f, 0.f, 0.f};
    #pragma unroll
    for (int ks = 0; ks < 4; ++ks) {
        int k0 = ks * 32 + kg * 8;
        bf16x8_t af = *reinterpret_cast<const bf16x8_t*>(A + (size_t)arow * 128 + k0);
        #pragma unroll
        for (int f = 0; f < 8; ++f) {
            bf16x8_t bfr = *reinterpret_cast<const bf16x8_t*>(woT + (size_t)(f * 16 + er) * 128 + k0);
            acc[f] = __builtin_amdgcn_mfma_f32_16x16x32_bf16(af, bfr, acc[f], 0, 0, 0);
        }
    }
    // + bo + residual x  (acc becomes x1, kept in regs to the end)
    float g2l[8], b2l[8];
    #pragma unroll
    for (int f = 0; f < 8; ++f) {
        int col = f * 16 + er;
        float bc = bo[col];
        g2l[f] = g2[col]; b2l[f] = b2[col];
        #pragma unroll
        for (int r = 0; r < 4; ++r) {
            int row = min(row0 + kg * 4 + r, M - 1);
            acc[f][r] += bc + xres[(size_t)row * 128 + col];
        }
    }
    // LN2 per row -> An (swizzled bf16)
    #pragma unroll
    for (int r = 0; r < 4; ++r) {
        float s = 0.f, sq = 0.f;
        #pragma unroll
        for (int f = 0; f < 8; ++f) { s += acc[f][r]; sq += acc[f][r] * acc[f][r]; }
        #pragma unroll
        for (int m = 1; m < 16; m <<= 1) {
            s  += __shfl_xor(s, m, 64);
            sq += __shfl_xor(sq, m, 64);
        }
        float mean = s * (1.0f / DIM);
        float var  = sq * (1.0f / DIM) - mean * mean;
        float rs = rsqrtf(var + 1e-5f);
        int rl = wave * 16 + kg * 4 + r;
        #pragma unroll
        for (int f = 0; f < 8; ++f) {
            int col = f * 16 + er;
            float xv = (acc[f][r] - mean) * rs * g2l[f] + b2l[f];
            int byte = rl * 256 + ((col * 2) ^ ((rl & 7) << 4));
            *reinterpret_cast<ushort*>(reinterpret_cast<char*>(An) + byte) = bfbits(xv);
        }
    }
    __syncthreads();

    int lrow = wave * 16 + er;
    int rsw = (lrow & 7) << 4;
    f32x4_t acc2[8];
    #pragma unroll
    for (int f = 0; f < 8; ++f) acc2[f] = (f32x4_t){0.f, 0.f, 0.f, 0.f};

    // FFN in 4 column-quarters of H (128 cols each)
    for (int q = 0; q < 4; ++q) {
        f32x4_t acch[8];
        #pragma unroll
        for (int f = 0; f < 8; ++f) acch[f] = (f32x4_t){0.f, 0.f, 0.f, 0.f};
        #pragma unroll
        for (int ks = 0; ks < 4; ++ks) {
            int k2 = ks * 64 + kg * 16;
            bf16x8_t af = *reinterpret_cast<const bf16x8_t*>(
                reinterpret_cast<char*>(An) + lrow * 256 + (k2 ^ rsw));
            #pragma unroll
            for (int f = 0; f < 8; ++f) {
                int c = q * 128 + f * 16 + er;
                bf16x8_t bfr = *reinterpret_cast<const bf16x8_t*>(w1t + (size_t)c * 128 + ks * 32 + kg * 8);
                acch[f] = __builtin_amdgcn_mfma_f32_16x16x32_bf16(af, bfr, acch[f], 0, 0, 0);
            }
        }
        #pragma unroll
        for (int f = 0; f < 8; ++f) {
            int colq = f * 16 + er;
            float bc = bf1[q * 128 + colq];
            #pragma unroll
            for (int r = 0; r < 4; ++r) {
                int rl2 = wave * 16 + kg * 4 + r;
                float hv = gelu_exact(acch[f][r] + bc);
                int byte = rl2 * 256 + ((colq * 2) ^ ((rl2 & 7) << 4));
                *reinterpret_cast<ushort*>(reinterpret_cast<char*>(Hb) + byte) = bfbits(hv);
            }
        }
        __syncthreads();
        // phase2 partial accumulate over this quarter's 128 k
        #pragma unroll
        for (int ks2 = 0; ks2 < 4; ++ks2) {
            int k2 = ks2 * 64 + kg * 16;
            bf16x8_t af2 = *reinterpret_cast<const bf16x8_t*>(
                reinterpret_cast<char*>(Hb) + lrow * 256 + (k2 ^ rsw));
            #pragma unroll
            for (int f = 0; f < 8; ++f) {
                bf16x8_t bfr = *reinterpret_cast<const bf16x8_t*>(
                    w2t + (size_t)(f * 16 + er) * 512 + q * 128 + ks2 * 32 + kg * 8);
                acc2[f] = __builtin_amdgcn_mfma_f32_16x16x32_bf16(af2, bfr, acc2[f], 0, 0, 0);
            }
        }
        __syncthreads();
    }
    // epilogue: out = ffn + bf2 + x1(regs)
    #pragma unroll
    for (int f = 0; f < 8; ++f) {
        int col = f * 16 + er;
        float bc = bf2[col];
        #pragma unroll
        for (int r = 0; r < 4; ++r) {
            int row = row0 + kg * 4 + r;
            if (row < M) out[(size_t)row * 128 + col] = acc2[f][r] + bc + acc[f][r];
        }
    }
}

// ---------------- 3-phase multi-block exclusive scan ----------------
#define SCAN_BLOCKS ((NNODES + 255) / 256)   // 196
__global__ void scan_ph1(const int* __restrict__ counts, int* __restrict__ rowstart,
                         int* __restrict__ blocksum) {
    __shared__ int sh[256];
    int t = threadIdx.x, i = blockIdx.x * 256 + t;
    int c = (i < NNODES) ? counts[i] : 0;
    sh[t] = c; __syncthreads();
    int v = c;
    #pragma unroll
    for (int off = 1; off < 256; off <<= 1) {
        int u = (t >= off) ? sh[t - off] : 0;
        __syncthreads();
        v += u; sh[t] = v;
        __syncthreads();
    }
    if (i < NNODES) rowstart[i] = v - c;
    if (t == 255) blocksum[blockIdx.x] = v;
}
__global__ void scan_ph2(const int* __restrict__ blocksum, int* __restrict__ blockoff,
                         int* __restrict__ rowstart) {
    __shared__ int sh[256];
    int t = threadIdx.x;
    int c = (t < SCAN_BLOCKS) ? blocksum[t] : 0;
    sh[t] = c; __syncthreads();
    int v = c;
    #pragma unroll
    for (int off = 1; off < 256; off <<= 1) {
        int u = (t >= off) ? sh[t - off] : 0;
        __syncthreads();
        v += u; sh[t] = v;
        __syncthreads();
    }
    if (t < SCAN_BLOCKS) blockoff[t] = v - c;
    if (t == 255) rowstart[NNODES] = v;
}
__global__ void scan_ph3(int* __restrict__ rowstart, const int* __restrict__ blockoff) {
    int i = blockIdx.x * 256 + threadIdx.x;
    if (i < NNODES) rowstart[i] += blockoff[blockIdx.x];
}

// ---------------- Edge bias + CSR scatter (sorted col + sorted bf16 eb) ----------------
__global__ __launch_bounds__(256)
void edge_bias_scatter(const float* __restrict__ EA, const ushort* __restrict__ wet,
                       const float* __restrict__ be, const int* __restrict__ ei,
                       const int* __restrict__ rowstart, int* __restrict__ cursor,
                       ushort* __restrict__ ebs_sorted, int* __restrict__ col_sorted) {
    __shared__ ushort lds[64 * 128];
    int tid = threadIdx.x, lane = tid & 63, wave = tid >> 6;
    size_t blockE = (size_t)blockIdx.x * 64;
    const float4* src = reinterpret_cast<const float4*>(EA + blockE * 128);
    #pragma unroll
    for (int it = 0; it < 8; ++it) {
        int idx = it * 256 + tid;
        float4 a = src[idx];
        int elem = idx * 4;
        int row = elem >> 7, col = elem & 127;
        uint2 pk;
        pk.x = pack2(a.x, a.y);
        pk.y = pack2(a.z, a.w);
        int byte = row * 256 + ((col * 2) ^ ((row & 7) << 4));
        *reinterpret_cast<uint2*>(reinterpret_cast<char*>(lds) + byte) = pk;
    }
    __syncthreads();
    int er = lane & 15, kg = lane >> 4;
    int lrow = wave * 16 + er;
    f32x4_t acc = (f32x4_t){0.f, 0.f, 0.f, 0.f};
    #pragma unroll
    for (int ks = 0; ks < 4; ++ks) {
        int cb = (ks * 64 + kg * 16) ^ ((er & 7) << 4);
        bf16x8_t af = *reinterpret_cast<const bf16x8_t*>(
            reinterpret_cast<char*>(lds) + lrow * 256 + cb);
        bf16x8_t bfr = *reinterpret_cast<const bf16x8_t*>(wet + er * 128 + ks * 32 + kg * 8);
        acc = __builtin_amdgcn_mfma_f32_16x16x32_bf16(af, bfr, acc, 0, 0, 0);
    }
    int e0 = (int)blockE + wave * 16;
    int pos = 0;
    if (lane < 16) {
        int e = e0 + lane;
        int row = ei[e], col = ei[NEDGES + e];
        pos = rowstart[row] + atomicAdd(&cursor[row], 1);
        col_sorted[pos] = col;
    }
    float beh = be[er & 7];
    #pragma unroll
    for (int r = 0; r < 4; ++r) {
        int pj = __shfl(pos, kg * 4 + r, 64);   // CSR pos of edge e0 + kg*4 + r
        if (er < 8) ebs_sorted[(size_t)pj * 8 + er] = bfbits(acc[r] + beh);
    }
}

// ---------------- Fused attention: per-node flash scores+softmax+aggregate ----------------
__global__ __launch_bounds__(256)
void attn_node_kernel(const int* __restrict__ rowstart, const int* __restrict__ col_sorted,
                      const ushort* __restrict__ ebs_sorted, const ushort* __restrict__ QKV,
                      ushort* __restrict__ agg) {
    int wave = threadIdx.x >> 6;
    int lane = threadIdx.x & 63;
    int n = blockIdx.x * 4 + wave;
    if (n >= NNODES) return;
    int s0 = rowstart[n], s1 = rowstart[n + 1];
    int h = lane >> 3;

    uint qu = *reinterpret_cast<const uint*>(QKV + (size_t)n * 384 + lane * 2);
    float q0 = lo16(qu), q1 = hi16(qu);

    float m = NEG_SENTINEL, ssum = 0.f, a0 = 0.f, a1 = 0.f;
    int p = s0;
    for (; p + 4 <= s1; p += 4) {
        int cc[4]; uint ku[4], vu[4]; float ebv[4], dd[4];
        #pragma unroll
        for (int i = 0; i < 4; ++i) cc[i] = col_sorted[p + i];
        #pragma unroll
        for (int i = 0; i < 4; ++i) {
            const ushort* kv = QKV + (size_t)cc[i] * 384 + 128;
            ku[i] = *reinterpret_cast<const uint*>(kv + lane * 2);
            vu[i] = *reinterpret_cast<const uint*>(kv + 128 + lane * 2);
            ebv[i] = b2f(ebs_sorted[(size_t)(p + i) * 8 + h]);
        }
        #pragma unroll
        for (int i = 0; i < 4; ++i) {
            float d = q0 * lo16(ku[i]) + q1 * hi16(ku[i]);
            d += __shfl_xor(d, 1, 64);
            d += __shfl_xor(d, 2, 64);
            d += __shfl_xor(d, 4, 64);
            dd[i] = d * 0.25f + ebv[i];
        }
        float mx = fmaxf(fmaxf(fmaxf(dd[0], dd[1]), fmaxf(dd[2], dd[3])), m);
        float sc = __expf(m - mx);
        float p0 = __expf(dd[0] - mx), p1 = __expf(dd[1] - mx);
        float p2 = __expf(dd[2] - mx), p3 = __expf(dd[3] - mx);
        ssum = ssum * sc + ((p0 + p1) + (p2 + p3));
        a0 = a0 * sc + p0 * lo16(vu[0]) + p1 * lo16(vu[1]) + p2 * lo16(vu[2]) + p3 * lo16(vu[3]);
        a1 = a1 * sc + p0 * hi16(vu[0]) + p1 * hi16(vu[1]) + p2 * hi16(vu[2]) + p3 * hi16(vu[3]);
        m = mx;
    }
    for (; p < s1; ++p) {
        int c = col_sorted[p];
        const ushort* kvrow = QKV + (size_t)c * 384 + 128;
        uint ku = *reinterpret_cast<const uint*>(kvrow + lane * 2);
        uint vu = *reinterpret_cast<const uint*>(kvrow + 128 + lane * 2);
        float eb = b2f(ebs_sorted[(size_t)p * 8 + h]);
        float d = q0 * lo16(ku) + q1 * hi16(ku);
        d += __shfl_xor(d, 1, 64);
        d += __shfl_xor(d, 2, 64);
        d += __shfl_xor(d, 4, 64);
        float s = d * 0.25f + eb;
        float mn = fmaxf(m, s);
        float sc = __expf(m - mn);
        float pv = __expf(s - mn);
        ssum = ssum * sc + pv;
        a0 = a0 * sc + pv * lo16(vu);
        a1 = a1 * sc + pv * hi16(vu);
        m = mn;
    }
    float inv = (ssum > 0.f) ? 1.0f / ssum : 0.f;
    reinterpret_cast<uint*>(agg + (size_t)n * 128)[lane] = pack2(a0 * inv, a1 * inv);
}

extern "C" void kernel_launch(void* const* d_in, const int* in_sizes, int n_in,
                              void* d_out, int out_size, void* d_ws, size_t ws_size,
                              hipStream_t stream) {
    const float* x   = (const float*)d_in[0];
    const int*   ei  = (const int*)d_in[1];
    const float* ea  = (const float*)d_in[2];
    const float* Wq  = (const float*)d_in[3];  const float* bq  = (const float*)d_in[4];
    const float* Wk  = (const float*)d_in[5];  const float* bk  = (const float*)d_in[6];
    const float* Wv  = (const float*)d_in[7];  const float* bv  = (const float*)d_in[8];
    const float* Wo  = (const float*)d_in[9];  const float* bo  = (const float*)d_in[10];
    const float* We  = (const float*)d_in[11]; const float* be  = (const float*)d_in[12];
    const float* W1  = (const float*)d_in[13]; const float* bf1 = (const float*)d_in[14];
    const float* W2  = (const float*)d_in[15]; const float* bf2 = (const float*)d_in[16];
    const float* g1  = (const float*)d_in[17]; const float* b1  = (const float*)d_in[18];
    const float* g2  = (const float*)d_in[19]; const float* b2  = (const float*)d_in[20];

    char* base = (char*)d_ws;
    // region0: xn (ln1 out, dead after QKV) -> agg (attn out, input to wo_ffn)
    ushort* xn        = (ushort*)(base);               // bf16 [N,128]
    ushort* agg       = (ushort*)(base);
    ushort* QKVb      = (ushort*)(base + 12800000);    // bf16 [N,384] = 38.4 MB
    ushort* ebs_sorted= (ushort*)(base + 51200000);    // bf16 [E,8] = 12.8 MB (CSR order)
    int*    col_sorted= (int*)(base + 64000000);       // [E] = 3.2 MB
    int*    counts    = (int*)(base + 67200000);       // [N]
    int*    rowstart  = (int*)(base + 67400000);       // [N+1]
    int*    cursor    = (int*)(base + 67600016);       // [N]
    ushort* wt4       = (ushort*)(base + 67800016);    // [512][128] (Wq|Wk|Wv|Wo)^T
    ushort* w1t       = (ushort*)(base + 67931088);    // [512][128]
    ushort* w2t       = (ushort*)(base + 68062160);    // [128][512]
    ushort* wet       = (ushort*)(base + 68193232);    // [16][128]
    float*  b384      = (float*)(base + 68197328);     // [384]
    int*    blocksum  = (int*)(base + 68198864);       // [196]
    int*    blockoff  = (int*)(base + 68199648);       // [196]
    // peak ~68.2 MB

    hipMemsetAsync(counts, 0, (size_t)NNODES * 4, stream);
    hipMemsetAsync(cursor, 0, (size_t)NNODES * 4, stream);

    setup_kernel<<<NEDGES / 256 + 778, 256, 0, stream>>>(ei, counts, Wq, Wk, Wv, Wo, W1, W2, We,
                                                         bq, bk, bv, wt4, w1t, w2t, wet, b384);
    ln_kernel<<<NNODES / 4, 256, 0, stream>>>(x, g1, b1, xn);

    dim3 gqkv((NNODES + 63) / 64, 1);
    mfma_gemm<128, 384, 384><<<gqkv, 256, 0, stream>>>(xn, wt4, b384, QKVb, NNODES);

    scan_ph1<<<SCAN_BLOCKS, 256, 0, stream>>>(counts, rowstart, blocksum);
    scan_ph2<<<1, 256, 0, stream>>>(blocksum, blockoff, rowstart);
    scan_ph3<<<SCAN_BLOCKS, 256, 0, stream>>>(rowstart, blockoff);

    edge_bias_scatter<<<NEDGES / 64, 256, 0, stream>>>(ea, wet, be, ei, rowstart, cursor,
                                                       ebs_sorted, col_sorted);
    attn_node_kernel<<<(NNODES + 3) / 4, 256, 0, stream>>>(rowstart, col_sorted, ebs_sorted,
                                                           QKVb, agg);

    dim3 g128((NNODES + 63) / 64, 1);
    wo_ffn_kernel<<<g128, 256, 0, stream>>>(agg, wt4 + 49152, bo, x, g2, b2,
                                            w1t, bf1, w2t, bf2, (float*)d_out, NNODES);
}

// Round 9
// 462.466 us; speedup vs baseline: 4.5323x; 1.0041x over previous
//
#include <hip/hip_runtime.h>
#include <hip/hip_bf16.h>
#include <math.h>

#define NNODES 50000
#define NEDGES 800000
#define DIM 128
#define NH 8

#define NEG_SENTINEL -3.0e38f

typedef __attribute__((ext_vector_type(8))) short bf16x8_t;
typedef __attribute__((ext_vector_type(4))) float f32x4_t;

__device__ __forceinline__ float gelu_exact(float v) {
    return 0.5f * v * (1.0f + erff(v * 0.70710678118654752f));
}
__device__ __forceinline__ ushort bfbits(float f) {
    uint u = __float_as_uint(f);
    u += 0x7fffu + ((u >> 16) & 1u);
    return (ushort)(u >> 16);
}
__device__ __forceinline__ uint pack2(float a, float b) {
    return (uint)bfbits(a) | ((uint)bfbits(b) << 16);
}
__device__ __forceinline__ float lo16(uint u) { return __uint_as_float(u << 16); }
__device__ __forceinline__ float hi16(uint u) { return __uint_as_float(u & 0xffff0000u); }
__device__ __forceinline__ float b2f(ushort u) { return __uint_as_float(((uint)u) << 16); }

// ---------------- setup: edge histogram + weight transpose/convert + bias pack ----------------
__global__ void setup_kernel(const int* __restrict__ ei, int* __restrict__ counts,
                             const float* __restrict__ Wq, const float* __restrict__ Wk,
                             const float* __restrict__ Wv, const float* __restrict__ Wo,
                             const float* __restrict__ W1, const float* __restrict__ W2,
                             const float* __restrict__ We,
                             const float* __restrict__ bq, const float* __restrict__ bk,
                             const float* __restrict__ bv,
                             ushort* __restrict__ wt4, ushort* __restrict__ w1t,
                             ushort* __restrict__ w2t, ushort* __restrict__ wet,
                             float* __restrict__ b384) {
    int b = blockIdx.x;
    if (b < NEDGES / 256) {
        int e = b * 256 + threadIdx.x;
        atomicAdd(&counts[ei[e]], 1);
        return;
    }
    int i = (b - NEDGES / 256) * 256 + threadIdx.x;
    if (i < 65536) {
        int w = i >> 14, j = i & 16383;
        int c = j >> 7, k = j & 127;
        const float* src = (w == 0) ? Wq : (w == 1) ? Wk : (w == 2) ? Wv : Wo;
        wt4[i] = bfbits(src[k * 128 + c]);
    } else if (i < 131072) {
        int j = i - 65536;
        int c = j >> 7, k = j & 127;
        w1t[j] = bfbits(W1[k * 512 + c]);
    } else if (i < 196608) {
        int j = i - 131072;
        int c = j >> 9, k = j & 511;
        w2t[j] = bfbits(W2[k * 128 + c]);
    } else if (i < 198656) {
        int j = i - 196608;
        int h = j >> 7, k = j & 127;
        wet[j] = (h < 8) ? bfbits(We[k * 8 + h]) : (ushort)0;
    } else if (i < 198656 + 384) {
        int j = i - 198656;
        b384[j] = (j < 128) ? bq[j] : (j < 256) ? bk[j - 128] : bv[j - 256];
    }
}

// ---------------- Fused LN1 + QKV GEMM ----------------
// out: Qb[N,128] bf16;  KVp[N,128] uint (lo16=K[d], hi16=V[d])
__global__ __launch_bounds__(256)
void ln_qkv_kernel(const float* __restrict__ x, const float* __restrict__ g1,
                   const float* __restrict__ b1, const ushort* __restrict__ wt4,
                   const float* __restrict__ b384, ushort* __restrict__ Qb,
                   uint* __restrict__ KVp, int M) {
    __shared__ ushort An[64 * 128];   // swizzled bf16 xn tile
    int tid = threadIdx.x, lane = tid & 63, wave = tid >> 6;
    int row0b = blockIdx.x * 64;
    float2 gg = reinterpret_cast<const float2*>(g1)[lane];
    float2 bb = reinterpret_cast<const float2*>(b1)[lane];
    // LN: wave w handles rows w*16 .. w*16+15
    for (int r = 0; r < 16; ++r) {
        int rl = wave * 16 + r;
        int srow = min(row0b + rl, M - 1);
        float2 v = reinterpret_cast<const float2*>(x + (size_t)srow * 128)[lane];
        float s = v.x + v.y, sq = v.x * v.x + v.y * v.y;
        #pragma unroll
        for (int mm = 1; mm < 64; mm <<= 1) {
            s  += __shfl_xor(s, mm, 64);
            sq += __shfl_xor(sq, mm, 64);
        }
        float mean = s * (1.0f / DIM);
        float var  = sq * (1.0f / DIM) - mean * mean;
        float rs = rsqrtf(var + 1e-5f);
        float ox = (v.x - mean) * rs * gg.x + bb.x;
        float oy = (v.y - mean) * rs * gg.y + bb.y;
        int byte = rl * 256 + ((lane * 4) ^ ((rl & 7) << 4));
        *reinterpret_cast<uint*>(reinterpret_cast<char*>(An) + byte) = pack2(ox, oy);
    }
    __syncthreads();
    // GEMM: 64 rows x 384 cols
    int er = lane & 15, kg = lane >> 4;
    int lrow = wave * 16 + er;
    int rsw = (er & 7) << 4;
    f32x4_t acc[24];
    #pragma unroll
    for (int f = 0; f < 24; ++f) acc[f] = (f32x4_t){0.f, 0.f, 0.f, 0.f};
    #pragma unroll
    for (int ks = 0; ks < 4; ++ks) {
        int k2 = ks * 64 + kg * 16;
        bf16x8_t af = *reinterpret_cast<const bf16x8_t*>(
            reinterpret_cast<char*>(An) + lrow * 256 + (k2 ^ rsw));
        #pragma unroll
        for (int f = 0; f < 24; ++f) {
            bf16x8_t bfr = *reinterpret_cast<const bf16x8_t*>(wt4 + (size_t)(f * 16 + er) * 128 + ks * 32 + kg * 8);
            acc[f] = __builtin_amdgcn_mfma_f32_16x16x32_bf16(af, bfr, acc[f], 0, 0, 0);
        }
    }
    #pragma unroll
    for (int f = 0; f < 24; ++f) {
        int col = f * 16 + er;
        float bc = b384[col];
        #pragma unroll
        for (int r = 0; r < 4; ++r) {
            int row = row0b + wave * 16 + kg * 4 + r;
            if (row < M) {
                float v = acc[f][r] + bc;
                if (col < 128) {
                    Qb[(size_t)row * 128 + col] = bfbits(v);
                } else if (col < 256) {
                    reinterpret_cast<ushort*>(KVp + (size_t)row * 128 + (col - 128))[0] = bfbits(v);
                } else {
                    reinterpret_cast<ushort*>(KVp + (size_t)row * 128 + (col - 256))[1] = bfbits(v);
                }
            }
        }
    }
}

// ---------------- Merged Wo + residual + LN2 + FFN (x1 in regs, H in LDS quarters) ----------------
__global__ __launch_bounds__(256)
void wo_ffn_kernel(const ushort* __restrict__ A, const ushort* __restrict__ woT,
                   const float* __restrict__ bo, const float* __restrict__ xres,
                   const float* __restrict__ g2, const float* __restrict__ b2,
                   const ushort* __restrict__ w1t, const float* __restrict__ bf1,
                   const ushort* __restrict__ w2t, const float* __restrict__ bf2,
                   float* __restrict__ out, int M) {
    __shared__ ushort An[64 * 128];
    __shared__ ushort Hb[64 * 128];
    int tid = threadIdx.x, lane = tid & 63, wave = tid >> 6;
    int row0 = blockIdx.x * 64 + wave * 16;
    int er = lane & 15, kg = lane >> 4;
    int arow = min(row0 + er, M - 1);

    f32x4_t acc[8];
    #pragma unroll
    for (int f = 0; f < 8; ++f) acc[f] = (f32x4_t){0.f, 0.f, 0.f, 0.f};
    #pragma unroll
    for (int ks = 0; ks < 4; ++ks) {
        int k0 = ks * 32 + kg * 8;
        bf16x8_t af = *reinterpret_cast<const bf16x8_t*>(A + (size_t)arow * 128 + k0);
        #pragma unroll
        for (int f = 0; f < 8; ++f) {
            bf16x8_t bfr = *reinterpret_cast<const bf16x8_t*>(woT + (size_t)(f * 16 + er) * 128 + k0);
            acc[f] = __builtin_amdgcn_mfma_f32_16x16x32_bf16(af, bfr, acc[f], 0, 0, 0);
        }
    }
    float g2l[8], b2l[8];
    #pragma unroll
    for (int f = 0; f < 8; ++f) {
        int col = f * 16 + er;
        float bc = bo[col];
        g2l[f] = g2[col]; b2l[f] = b2[col];
        #pragma unroll
        for (int r = 0; r < 4; ++r) {
            int row = min(row0 + kg * 4 + r, M - 1);
            acc[f][r] += bc + xres[(size_t)row * 128 + col];
        }
    }
    #pragma unroll
    for (int r = 0; r < 4; ++r) {
        float s = 0.f, sq = 0.f;
        #pragma unroll
        for (int f = 0; f < 8; ++f) { s += acc[f][r]; sq += acc[f][r] * acc[f][r]; }
        #pragma unroll
        for (int m = 1; m < 16; m <<= 1) {
            s  += __shfl_xor(s, m, 64);
            sq += __shfl_xor(sq, m, 64);
        }
        float mean = s * (1.0f / DIM);
        float var  = sq * (1.0f / DIM) - mean * mean;
        float rs = rsqrtf(var + 1e-5f);
        int rl = wave * 16 + kg * 4 + r;
        #pragma unroll
        for (int f = 0; f < 8; ++f) {
            int col = f * 16 + er;
            float xv = (acc[f][r] - mean) * rs * g2l[f] + b2l[f];
            int byte = rl * 256 + ((col * 2) ^ ((rl & 7) << 4));
            *reinterpret_cast<ushort*>(reinterpret_cast<char*>(An) + byte) = bfbits(xv);
        }
    }
    __syncthreads();

    int lrow = wave * 16 + er;
    int rsw = (lrow & 7) << 4;
    f32x4_t acc2[8];
    #pragma unroll
    for (int f = 0; f < 8; ++f) acc2[f] = (f32x4_t){0.f, 0.f, 0.f, 0.f};

    for (int q = 0; q < 4; ++q) {
        f32x4_t acch[8];
        #pragma unroll
        for (int f = 0; f < 8; ++f) acch[f] = (f32x4_t){0.f, 0.f, 0.f, 0.f};
        #pragma unroll
        for (int ks = 0; ks < 4; ++ks) {
            int k2 = ks * 64 + kg * 16;
            bf16x8_t af = *reinterpret_cast<const bf16x8_t*>(
                reinterpret_cast<char*>(An) + lrow * 256 + (k2 ^ rsw));
            #pragma unroll
            for (int f = 0; f < 8; ++f) {
                int c = q * 128 + f * 16 + er;
                bf16x8_t bfr = *reinterpret_cast<const bf16x8_t*>(w1t + (size_t)c * 128 + ks * 32 + kg * 8);
                acch[f] = __builtin_amdgcn_mfma_f32_16x16x32_bf16(af, bfr, acch[f], 0, 0, 0);
            }
        }
        #pragma unroll
        for (int f = 0; f < 8; ++f) {
            int colq = f * 16 + er;
            float bc = bf1[q * 128 + colq];
            #pragma unroll
            for (int r = 0; r < 4; ++r) {
                int rl2 = wave * 16 + kg * 4 + r;
                float hv = gelu_exact(acch[f][r] + bc);
                int byte = rl2 * 256 + ((colq * 2) ^ ((rl2 & 7) << 4));
                *reinterpret_cast<ushort*>(reinterpret_cast<char*>(Hb) + byte) = bfbits(hv);
            }
        }
        __syncthreads();
        #pragma unroll
        for (int ks2 = 0; ks2 < 4; ++ks2) {
            int k2 = ks2 * 64 + kg * 16;
            bf16x8_t af2 = *reinterpret_cast<const bf16x8_t*>(
                reinterpret_cast<char*>(Hb) + lrow * 256 + (k2 ^ rsw));
            #pragma unroll
            for (int f = 0; f < 8; ++f) {
                bf16x8_t bfr = *reinterpret_cast<const bf16x8_t*>(
                    w2t + (size_t)(f * 16 + er) * 512 + q * 128 + ks2 * 32 + kg * 8);
                acc2[f] = __builtin_amdgcn_mfma_f32_16x16x32_bf16(af2, bfr, acc2[f], 0, 0, 0);
            }
        }
        __syncthreads();
    }
    #pragma unroll
    for (int f = 0; f < 8; ++f) {
        int col = f * 16 + er;
        float bc = bf2[col];
        #pragma unroll
        for (int r = 0; r < 4; ++r) {
            int row = row0 + kg * 4 + r;
            if (row < M) out[(size_t)row * 128 + col] = acc2[f][r] + bc + acc[f][r];
        }
    }
}

// ---------------- 3-phase multi-block exclusive scan ----------------
#define SCAN_BLOCKS ((NNODES + 255) / 256)   // 196
__global__ void scan_ph1(const int* __restrict__ counts, int* __restrict__ rowstart,
                         int* __restrict__ blocksum) {
    __shared__ int sh[256];
    int t = threadIdx.x, i = blockIdx.x * 256 + t;
    int c = (i < NNODES) ? counts[i] : 0;
    sh[t] = c; __syncthreads();
    int v = c;
    #pragma unroll
    for (int off = 1; off < 256; off <<= 1) {
        int u = (t >= off) ? sh[t - off] : 0;
        __syncthreads();
        v += u; sh[t] = v;
        __syncthreads();
    }
    if (i < NNODES) rowstart[i] = v - c;
    if (t == 255) blocksum[blockIdx.x] = v;
}
__global__ void scan_ph2(const int* __restrict__ blocksum, int* __restrict__ blockoff,
                         int* __restrict__ rowstart) {
    __shared__ int sh[256];
    int t = threadIdx.x;
    int c = (t < SCAN_BLOCKS) ? blocksum[t] : 0;
    sh[t] = c; __syncthreads();
    int v = c;
    #pragma unroll
    for (int off = 1; off < 256; off <<= 1) {
        int u = (t >= off) ? sh[t - off] : 0;
        __syncthreads();
        v += u; sh[t] = v;
        __syncthreads();
    }
    if (t < SCAN_BLOCKS) blockoff[t] = v - c;
    if (t == 255) rowstart[NNODES] = v;
}
__global__ void scan_ph3(int* __restrict__ rowstart, const int* __restrict__ blockoff) {
    int i = blockIdx.x * 256 + threadIdx.x;
    if (i < NNODES) rowstart[i] += blockoff[blockIdx.x];
}

// ---------------- Edge bias + CSR scatter (sorted col + sorted bf16 eb) ----------------
__global__ __launch_bounds__(256)
void edge_bias_scatter(const float* __restrict__ EA, const ushort* __restrict__ wet,
                       const float* __restrict__ be, const int* __restrict__ ei,
                       const int* __restrict__ rowstart, int* __restrict__ cursor,
                       ushort* __restrict__ ebs_sorted, int* __restrict__ col_sorted) {
    __shared__ ushort lds[64 * 128];
    int tid = threadIdx.x, lane = tid & 63, wave = tid >> 6;
    size_t blockE = (size_t)blockIdx.x * 64;
    const float4* src = reinterpret_cast<const float4*>(EA + blockE * 128);
    #pragma unroll
    for (int it = 0; it < 8; ++it) {
        int idx = it * 256 + tid;
        float4 a = src[idx];
        int elem = idx * 4;
        int row = elem >> 7, col = elem & 127;
        uint2 pk;
        pk.x = pack2(a.x, a.y);
        pk.y = pack2(a.z, a.w);
        int byte = row * 256 + ((col * 2) ^ ((row & 7) << 4));
        *reinterpret_cast<uint2*>(reinterpret_cast<char*>(lds) + byte) = pk;
    }
    __syncthreads();
    int er = lane & 15, kg = lane >> 4;
    int lrow = wave * 16 + er;
    f32x4_t acc = (f32x4_t){0.f, 0.f, 0.f, 0.f};
    #pragma unroll
    for (int ks = 0; ks < 4; ++ks) {
        int cb = (ks * 64 + kg * 16) ^ ((er & 7) << 4);
        bf16x8_t af = *reinterpret_cast<const bf16x8_t*>(
            reinterpret_cast<char*>(lds) + lrow * 256 + cb);
        bf16x8_t bfr = *reinterpret_cast<const bf16x8_t*>(wet + er * 128 + ks * 32 + kg * 8);
        acc = __builtin_amdgcn_mfma_f32_16x16x32_bf16(af, bfr, acc, 0, 0, 0);
    }
    int e0 = (int)blockE + wave * 16;
    int pos = 0;
    if (lane < 16) {
        int e = e0 + lane;
        int row = ei[e], col = ei[NEDGES + e];
        pos = rowstart[row] + atomicAdd(&cursor[row], 1);
        col_sorted[pos] = col;
    }
    float beh = be[er & 7];
    #pragma unroll
    for (int r = 0; r < 4; ++r) {
        int pj = __shfl(pos, kg * 4 + r, 64);
        if (er < 8) ebs_sorted[(size_t)pj * 8 + er] = bfbits(acc[r] + beh);
    }
}

// ---------------- Fused attention: per-node flash scores+softmax+aggregate ----------------
// Qb[N,128] bf16; KVp[N,128] uint (lo=K, hi=V). One 8B gather per lane per edge.
__global__ __launch_bounds__(256)
void attn_node_kernel(const int* __restrict__ rowstart, const int* __restrict__ col_sorted,
                      const ushort* __restrict__ ebs_sorted, const ushort* __restrict__ Qb,
                      const uint* __restrict__ KVp, ushort* __restrict__ agg) {
    int wave = threadIdx.x >> 6;
    int lane = threadIdx.x & 63;
    int n = blockIdx.x * 4 + wave;
    if (n >= NNODES) return;
    int s0 = rowstart[n], s1 = rowstart[n + 1];
    int h = lane >> 3;

    uint qu = *reinterpret_cast<const uint*>(Qb + (size_t)n * 128 + lane * 2);
    float q0 = lo16(qu), q1 = hi16(qu);

    float m = NEG_SENTINEL, ssum = 0.f, a0 = 0.f, a1 = 0.f;
    int p = s0;
    for (; p + 4 <= s1; p += 4) {
        int cc[4]; uint2 kv[4]; float ebv[4], dd[4];
        #pragma unroll
        for (int i = 0; i < 4; ++i) cc[i] = col_sorted[p + i];
        #pragma unroll
        for (int i = 0; i < 4; ++i) {
            kv[i] = *reinterpret_cast<const uint2*>(KVp + (size_t)cc[i] * 128 + lane * 2);
            ebv[i] = b2f(ebs_sorted[(size_t)(p + i) * 8 + h]);
        }
        #pragma unroll
        for (int i = 0; i < 4; ++i) {
            float d = q0 * lo16(kv[i].x) + q1 * lo16(kv[i].y);
            d += __shfl_xor(d, 1, 64);
            d += __shfl_xor(d, 2, 64);
            d += __shfl_xor(d, 4, 64);
            dd[i] = d * 0.25f + ebv[i];
        }
        float mx = fmaxf(fmaxf(fmaxf(dd[0], dd[1]), fmaxf(dd[2], dd[3])), m);
        float sc = __expf(m - mx);
        float p0 = __expf(dd[0] - mx), p1 = __expf(dd[1] - mx);
        float p2 = __expf(dd[2] - mx), p3 = __expf(dd[3] - mx);
        ssum = ssum * sc + ((p0 + p1) + (p2 + p3));
        a0 = a0 * sc + p0 * hi16(kv[0].x) + p1 * hi16(kv[1].x) + p2 * hi16(kv[2].x) + p3 * hi16(kv[3].x);
        a1 = a1 * sc + p0 * hi16(kv[0].y) + p1 * hi16(kv[1].y) + p2 * hi16(kv[2].y) + p3 * hi16(kv[3].y);
        m = mx;
    }
    for (; p < s1; ++p) {
        int c = col_sorted[p];
        uint2 kv = *reinterpret_cast<const uint2*>(KVp + (size_t)c * 128 + lane * 2);
        float eb = b2f(ebs_sorted[(size_t)p * 8 + h]);
        float d = q0 * lo16(kv.x) + q1 * lo16(kv.y);
        d += __shfl_xor(d, 1, 64);
        d += __shfl_xor(d, 2, 64);
        d += __shfl_xor(d, 4, 64);
        float s = d * 0.25f + eb;
        float mn = fmaxf(m, s);
        float sc = __expf(m - mn);
        float pv = __expf(s - mn);
        ssum = ssum * sc + pv;
        a0 = a0 * sc + pv * hi16(kv.x);
        a1 = a1 * sc + pv * hi16(kv.y);
        m = mn;
    }
    float inv = (ssum > 0.f) ? 1.0f / ssum : 0.f;
    reinterpret_cast<uint*>(agg + (size_t)n * 128)[lane] = pack2(a0 * inv, a1 * inv);
}

extern "C" void kernel_launch(void* const* d_in, const int* in_sizes, int n_in,
                              void* d_out, int out_size, void* d_ws, size_t ws_size,
                              hipStream_t stream) {
    const float* x   = (const float*)d_in[0];
    const int*   ei  = (const int*)d_in[1];
    const float* ea  = (const float*)d_in[2];
    const float* Wq  = (const float*)d_in[3];  const float* bq  = (const float*)d_in[4];
    const float* Wk  = (const float*)d_in[5];  const float* bk  = (const float*)d_in[6];
    const float* Wv  = (const float*)d_in[7];  const float* bv  = (const float*)d_in[8];
    const float* Wo  = (const float*)d_in[9];  const float* bo  = (const float*)d_in[10];
    const float* We  = (const float*)d_in[11]; const float* be  = (const float*)d_in[12];
    const float* W1  = (const float*)d_in[13]; const float* bf1 = (const float*)d_in[14];
    const float* W2  = (const float*)d_in[15]; const float* bf2 = (const float*)d_in[16];
    const float* g1  = (const float*)d_in[17]; const float* b1  = (const float*)d_in[18];
    const float* g2  = (const float*)d_in[19]; const float* b2  = (const float*)d_in[20];

    char* base = (char*)d_ws;
    ushort* agg       = (ushort*)(base);               // bf16 [N,128] = 12.8 MB
    ushort* Qb        = (ushort*)(base + 12800000);    // bf16 [N,128] = 12.8 MB
    uint*   KVp       = (uint*)(base + 25600000);      // uint [N,128] = 25.6 MB (K lo | V hi)
    ushort* ebs_sorted= (ushort*)(base + 51200000);    // bf16 [E,8] = 12.8 MB (CSR order)
    int*    col_sorted= (int*)(base + 64000000);       // [E] = 3.2 MB
    int*    counts    = (int*)(base + 67200000);       // [N]
    int*    rowstart  = (int*)(base + 67400000);       // [N+1]
    int*    cursor    = (int*)(base + 67600016);       // [N]
    ushort* wt4       = (ushort*)(base + 67800016);    // [512][128] (Wq|Wk|Wv|Wo)^T
    ushort* w1t       = (ushort*)(base + 67931088);    // [512][128]
    ushort* w2t       = (ushort*)(base + 68062160);    // [128][512]
    ushort* wet       = (ushort*)(base + 68193232);    // [16][128]
    float*  b384      = (float*)(base + 68197328);     // [384]
    int*    blocksum  = (int*)(base + 68198864);       // [196]
    int*    blockoff  = (int*)(base + 68199648);       // [196]
    // peak ~68.2 MB

    hipMemsetAsync(counts, 0, (size_t)NNODES * 4, stream);
    hipMemsetAsync(cursor, 0, (size_t)NNODES * 4, stream);

    setup_kernel<<<NEDGES / 256 + 778, 256, 0, stream>>>(ei, counts, Wq, Wk, Wv, Wo, W1, W2, We,
                                                         bq, bk, bv, wt4, w1t, w2t, wet, b384);

    dim3 g128((NNODES + 63) / 64, 1);
    ln_qkv_kernel<<<g128, 256, 0, stream>>>(x, g1, b1, wt4, b384, Qb, KVp, NNODES);

    scan_ph1<<<SCAN_BLOCKS, 256, 0, stream>>>(counts, rowstart, blocksum);
    scan_ph2<<<1, 256, 0, stream>>>(blocksum, blockoff, rowstart);
    scan_ph3<<<SCAN_BLOCKS, 256, 0, stream>>>(rowstart, blockoff);

    edge_bias_scatter<<<NEDGES / 64, 256, 0, stream>>>(ea, wet, be, ei, rowstart, cursor,
                                                       ebs_sorted, col_sorted);
    attn_node_kernel<<<(NNODES + 3) / 4, 256, 0, stream>>>(rowstart, col_sorted, ebs_sorted,
                                                           Qb, KVp, agg);

    wo_ffn_kernel<<<g128, 256, 0, stream>>>(agg, wt4 + 49152, bo, x, g2, b2,
                                            w1t, bf1, w2t, bf2, (float*)d_out, NNODES);
}

// Round 10
// 458.814 us; speedup vs baseline: 4.5684x; 1.0080x over previous
//
#include <hip/hip_runtime.h>
#include <hip/hip_bf16.h>
#include <math.h>

#define NNODES 50000
#define NEDGES 800000
#define DIM 128
#define NH 8

#define NEG_SENTINEL -3.0e38f

typedef __attribute__((ext_vector_type(8))) short bf16x8_t;
typedef __attribute__((ext_vector_type(4))) float f32x4_t;

__device__ __forceinline__ float gelu_exact(float v) {
    return 0.5f * v * (1.0f + erff(v * 0.70710678118654752f));
}
__device__ __forceinline__ ushort bfbits(float f) {
    uint u = __float_as_uint(f);
    u += 0x7fffu + ((u >> 16) & 1u);
    return (ushort)(u >> 16);
}
__device__ __forceinline__ uint pack2(float a, float b) {
    return (uint)bfbits(a) | ((uint)bfbits(b) << 16);
}
__device__ __forceinline__ float lo16(uint u) { return __uint_as_float(u << 16); }
__device__ __forceinline__ float hi16(uint u) { return __uint_as_float(u & 0xffff0000u); }
__device__ __forceinline__ float b2f(ushort u) { return __uint_as_float(((uint)u) << 16); }

// ---------------- setup: edge histogram (+rank) + weight transpose/convert + bias pack ----------------
__global__ void setup_kernel(const int* __restrict__ ei, int* __restrict__ counts,
                             int* __restrict__ rank,
                             const float* __restrict__ Wq, const float* __restrict__ Wk,
                             const float* __restrict__ Wv, const float* __restrict__ Wo,
                             const float* __restrict__ W1, const float* __restrict__ W2,
                             const float* __restrict__ We,
                             const float* __restrict__ bq, const float* __restrict__ bk,
                             const float* __restrict__ bv,
                             ushort* __restrict__ wt4, ushort* __restrict__ w1t,
                             ushort* __restrict__ w2t, ushort* __restrict__ wet,
                             float* __restrict__ b384) {
    int b = blockIdx.x;
    if (b < NEDGES / 256) {
        int e = b * 256 + threadIdx.x;
        rank[e] = atomicAdd(&counts[ei[e]], 1);   // rank within row (order arbitrary)
        return;
    }
    int i = (b - NEDGES / 256) * 256 + threadIdx.x;
    if (i < 65536) {
        int w = i >> 14, j = i & 16383;
        int c = j >> 7, k = j & 127;
        const float* src = (w == 0) ? Wq : (w == 1) ? Wk : (w == 2) ? Wv : Wo;
        wt4[i] = bfbits(src[k * 128 + c]);
    } else if (i < 131072) {
        int j = i - 65536;
        int c = j >> 7, k = j & 127;
        w1t[j] = bfbits(W1[k * 512 + c]);
    } else if (i < 196608) {
        int j = i - 131072;
        int c = j >> 9, k = j & 511;
        w2t[j] = bfbits(W2[k * 128 + c]);
    } else if (i < 198656) {
        int j = i - 196608;
        int h = j >> 7, k = j & 127;
        wet[j] = (h < 8) ? bfbits(We[k * 8 + h]) : (ushort)0;
    } else if (i < 198656 + 384) {
        int j = i - 198656;
        b384[j] = (j < 128) ? bq[j] : (j < 256) ? bk[j - 128] : bv[j - 256];
    }
}

// ---------------- Fused LN1 + QKV GEMM ----------------
// out: Qb[N,128] bf16;  KVp[N,128] uint (lo16=K[d], hi16=V[d])
__global__ __launch_bounds__(256)
void ln_qkv_kernel(const float* __restrict__ x, const float* __restrict__ g1,
                   const float* __restrict__ b1, const ushort* __restrict__ wt4,
                   const float* __restrict__ b384, ushort* __restrict__ Qb,
                   uint* __restrict__ KVp, int M) {
    __shared__ ushort An[64 * 128];   // swizzled bf16 xn tile
    int tid = threadIdx.x, lane = tid & 63, wave = tid >> 6;
    int row0b = blockIdx.x * 64;
    float2 gg = reinterpret_cast<const float2*>(g1)[lane];
    float2 bb = reinterpret_cast<const float2*>(b1)[lane];
    for (int r = 0; r < 16; ++r) {
        int rl = wave * 16 + r;
        int srow = min(row0b + rl, M - 1);
        float2 v = reinterpret_cast<const float2*>(x + (size_t)srow * 128)[lane];
        float s = v.x + v.y, sq = v.x * v.x + v.y * v.y;
        #pragma unroll
        for (int mm = 1; mm < 64; mm <<= 1) {
            s  += __shfl_xor(s, mm, 64);
            sq += __shfl_xor(sq, mm, 64);
        }
        float mean = s * (1.0f / DIM);
        float var  = sq * (1.0f / DIM) - mean * mean;
        float rs = rsqrtf(var + 1e-5f);
        float ox = (v.x - mean) * rs * gg.x + bb.x;
        float oy = (v.y - mean) * rs * gg.y + bb.y;
        int byte = rl * 256 + ((lane * 4) ^ ((rl & 7) << 4));
        *reinterpret_cast<uint*>(reinterpret_cast<char*>(An) + byte) = pack2(ox, oy);
    }
    __syncthreads();
    int er = lane & 15, kg = lane >> 4;
    int lrow = wave * 16 + er;
    int rsw = (er & 7) << 4;
    f32x4_t acc[24];
    #pragma unroll
    for (int f = 0; f < 24; ++f) acc[f] = (f32x4_t){0.f, 0.f, 0.f, 0.f};
    #pragma unroll
    for (int ks = 0; ks < 4; ++ks) {
        int k2 = ks * 64 + kg * 16;
        bf16x8_t af = *reinterpret_cast<const bf16x8_t*>(
            reinterpret_cast<char*>(An) + lrow * 256 + (k2 ^ rsw));
        #pragma unroll
        for (int f = 0; f < 24; ++f) {
            bf16x8_t bfr = *reinterpret_cast<const bf16x8_t*>(wt4 + (size_t)(f * 16 + er) * 128 + ks * 32 + kg * 8);
            acc[f] = __builtin_amdgcn_mfma_f32_16x16x32_bf16(af, bfr, acc[f], 0, 0, 0);
        }
    }
    #pragma unroll
    for (int f = 0; f < 24; ++f) {
        int col = f * 16 + er;
        float bc = b384[col];
        #pragma unroll
        for (int r = 0; r < 4; ++r) {
            int row = row0b + wave * 16 + kg * 4 + r;
            if (row < M) {
                float v = acc[f][r] + bc;
                if (col < 128) {
                    Qb[(size_t)row * 128 + col] = bfbits(v);
                } else if (col < 256) {
                    reinterpret_cast<ushort*>(KVp + (size_t)row * 128 + (col - 128))[0] = bfbits(v);
                } else {
                    reinterpret_cast<ushort*>(KVp + (size_t)row * 128 + (col - 256))[1] = bfbits(v);
                }
            }
        }
    }
}

// ---------------- Merged Wo + residual + LN2 + FFN (x1 in regs, H in LDS quarters) ----------------
__global__ __launch_bounds__(256)
void wo_ffn_kernel(const ushort* __restrict__ A, const ushort* __restrict__ woT,
                   const float* __restrict__ bo, const float* __restrict__ xres,
                   const float* __restrict__ g2, const float* __restrict__ b2,
                   const ushort* __restrict__ w1t, const float* __restrict__ bf1,
                   const ushort* __restrict__ w2t, const float* __restrict__ bf2,
                   float* __restrict__ out, int M) {
    __shared__ ushort An[64 * 128];
    __shared__ ushort Hb[64 * 128];
    int tid = threadIdx.x, lane = tid & 63, wave = tid >> 6;
    int row0 = blockIdx.x * 64 + wave * 16;
    int er = lane & 15, kg = lane >> 4;
    int arow = min(row0 + er, M - 1);

    f32x4_t acc[8];
    #pragma unroll
    for (int f = 0; f < 8; ++f) acc[f] = (f32x4_t){0.f, 0.f, 0.f, 0.f};
    #pragma unroll
    for (int ks = 0; ks < 4; ++ks) {
        int k0 = ks * 32 + kg * 8;
        bf16x8_t af = *reinterpret_cast<const bf16x8_t*>(A + (size_t)arow * 128 + k0);
        #pragma unroll
        for (int f = 0; f < 8; ++f) {
            bf16x8_t bfr = *reinterpret_cast<const bf16x8_t*>(woT + (size_t)(f * 16 + er) * 128 + k0);
            acc[f] = __builtin_amdgcn_mfma_f32_16x16x32_bf16(af, bfr, acc[f], 0, 0, 0);
        }
    }
    float g2l[8], b2l[8];
    #pragma unroll
    for (int f = 0; f < 8; ++f) {
        int col = f * 16 + er;
        float bc = bo[col];
        g2l[f] = g2[col]; b2l[f] = b2[col];
        #pragma unroll
        for (int r = 0; r < 4; ++r) {
            int row = min(row0 + kg * 4 + r, M - 1);
            acc[f][r] += bc + xres[(size_t)row * 128 + col];
        }
    }
    #pragma unroll
    for (int r = 0; r < 4; ++r) {
        float s = 0.f, sq = 0.f;
        #pragma unroll
        for (int f = 0; f < 8; ++f) { s += acc[f][r]; sq += acc[f][r] * acc[f][r]; }
        #pragma unroll
        for (int m = 1; m < 16; m <<= 1) {
            s  += __shfl_xor(s, m, 64);
            sq += __shfl_xor(sq, m, 64);
        }
        float mean = s * (1.0f / DIM);
        float var  = sq * (1.0f / DIM) - mean * mean;
        float rs = rsqrtf(var + 1e-5f);
        int rl = wave * 16 + kg * 4 + r;
        #pragma unroll
        for (int f = 0; f < 8; ++f) {
            int col = f * 16 + er;
            float xv = (acc[f][r] - mean) * rs * g2l[f] + b2l[f];
            int byte = rl * 256 + ((col * 2) ^ ((rl & 7) << 4));
            *reinterpret_cast<ushort*>(reinterpret_cast<char*>(An) + byte) = bfbits(xv);
        }
    }
    __syncthreads();

    int lrow = wave * 16 + er;
    int rsw = (lrow & 7) << 4;
    f32x4_t acc2[8];
    #pragma unroll
    for (int f = 0; f < 8; ++f) acc2[f] = (f32x4_t){0.f, 0.f, 0.f, 0.f};

    for (int q = 0; q < 4; ++q) {
        f32x4_t acch[8];
        #pragma unroll
        for (int f = 0; f < 8; ++f) acch[f] = (f32x4_t){0.f, 0.f, 0.f, 0.f};
        #pragma unroll
        for (int ks = 0; ks < 4; ++ks) {
            int k2 = ks * 64 + kg * 16;
            bf16x8_t af = *reinterpret_cast<const bf16x8_t*>(
                reinterpret_cast<char*>(An) + lrow * 256 + (k2 ^ rsw));
            #pragma unroll
            for (int f = 0; f < 8; ++f) {
                int c = q * 128 + f * 16 + er;
                bf16x8_t bfr = *reinterpret_cast<const bf16x8_t*>(w1t + (size_t)c * 128 + ks * 32 + kg * 8);
                acch[f] = __builtin_amdgcn_mfma_f32_16x16x32_bf16(af, bfr, acch[f], 0, 0, 0);
            }
        }
        #pragma unroll
        for (int f = 0; f < 8; ++f) {
            int colq = f * 16 + er;
            float bc = bf1[q * 128 + colq];
            #pragma unroll
            for (int r = 0; r < 4; ++r) {
                int rl2 = wave * 16 + kg * 4 + r;
                float hv = gelu_exact(acch[f][r] + bc);
                int byte = rl2 * 256 + ((colq * 2) ^ ((rl2 & 7) << 4));
                *reinterpret_cast<ushort*>(reinterpret_cast<char*>(Hb) + byte) = bfbits(hv);
            }
        }
        __syncthreads();
        #pragma unroll
        for (int ks2 = 0; ks2 < 4; ++ks2) {
            int k2 = ks2 * 64 + kg * 16;
            bf16x8_t af2 = *reinterpret_cast<const bf16x8_t*>(
                reinterpret_cast<char*>(Hb) + lrow * 256 + (k2 ^ rsw));
            #pragma unroll
            for (int f = 0; f < 8; ++f) {
                bf16x8_t bfr = *reinterpret_cast<const bf16x8_t*>(
                    w2t + (size_t)(f * 16 + er) * 512 + q * 128 + ks2 * 32 + kg * 8);
                acc2[f] = __builtin_amdgcn_mfma_f32_16x16x32_bf16(af2, bfr, acc2[f], 0, 0, 0);
            }
        }
        __syncthreads();
    }
    #pragma unroll
    for (int f = 0; f < 8; ++f) {
        int col = f * 16 + er;
        float bc = bf2[col];
        #pragma unroll
        for (int r = 0; r < 4; ++r) {
            int row = row0 + kg * 4 + r;
            if (row < M) out[(size_t)row * 128 + col] = acc2[f][r] + bc + acc[f][r];
        }
    }
}

// ---------------- 3-phase multi-block exclusive scan ----------------
#define SCAN_BLOCKS ((NNODES + 255) / 256)   // 196
__global__ void scan_ph1(const int* __restrict__ counts, int* __restrict__ rowstart,
                         int* __restrict__ blocksum) {
    __shared__ int sh[256];
    int t = threadIdx.x, i = blockIdx.x * 256 + t;
    int c = (i < NNODES) ? counts[i] : 0;
    sh[t] = c; __syncthreads();
    int v = c;
    #pragma unroll
    for (int off = 1; off < 256; off <<= 1) {
        int u = (t >= off) ? sh[t - off] : 0;
        __syncthreads();
        v += u; sh[t] = v;
        __syncthreads();
    }
    if (i < NNODES) rowstart[i] = v - c;
    if (t == 255) blocksum[blockIdx.x] = v;
}
__global__ void scan_ph2(const int* __restrict__ blocksum, int* __restrict__ blockoff,
                         int* __restrict__ rowstart) {
    __shared__ int sh[256];
    int t = threadIdx.x;
    int c = (t < SCAN_BLOCKS) ? blocksum[t] : 0;
    sh[t] = c; __syncthreads();
    int v = c;
    #pragma unroll
    for (int off = 1; off < 256; off <<= 1) {
        int u = (t >= off) ? sh[t - off] : 0;
        __syncthreads();
        v += u; sh[t] = v;
        __syncthreads();
    }
    if (t < SCAN_BLOCKS) blockoff[t] = v - c;
    if (t == 255) rowstart[NNODES] = v;
}
__global__ void scan_ph3(int* __restrict__ rowstart, const int* __restrict__ blockoff) {
    int i = blockIdx.x * 256 + threadIdx.x;
    if (i < NNODES) rowstart[i] += blockoff[blockIdx.x];
}

// ---------------- Edge bias + CSR scatter (rank-based, no atomics) ----------------
__global__ __launch_bounds__(256)
void edge_bias_scatter(const float* __restrict__ EA, const ushort* __restrict__ wet,
                       const float* __restrict__ be, const int* __restrict__ ei,
                       const int* __restrict__ rowstart, const int* __restrict__ rank,
                       ushort* __restrict__ ebs_sorted, int* __restrict__ col_sorted) {
    __shared__ ushort lds[64 * 128];
    int tid = threadIdx.x, lane = tid & 63, wave = tid >> 6;
    size_t blockE = (size_t)blockIdx.x * 64;
    const float4* src = reinterpret_cast<const float4*>(EA + blockE * 128);
    #pragma unroll
    for (int it = 0; it < 8; ++it) {
        int idx = it * 256 + tid;
        float4 a = src[idx];
        int elem = idx * 4;
        int row = elem >> 7, col = elem & 127;
        uint2 pk;
        pk.x = pack2(a.x, a.y);
        pk.y = pack2(a.z, a.w);
        int byte = row * 256 + ((col * 2) ^ ((row & 7) << 4));
        *reinterpret_cast<uint2*>(reinterpret_cast<char*>(lds) + byte) = pk;
    }
    __syncthreads();
    int er = lane & 15, kg = lane >> 4;
    int lrow = wave * 16 + er;
    f32x4_t acc = (f32x4_t){0.f, 0.f, 0.f, 0.f};
    #pragma unroll
    for (int ks = 0; ks < 4; ++ks) {
        int cb = (ks * 64 + kg * 16) ^ ((er & 7) << 4);
        bf16x8_t af = *reinterpret_cast<const bf16x8_t*>(
            reinterpret_cast<char*>(lds) + lrow * 256 + cb);
        bf16x8_t bfr = *reinterpret_cast<const bf16x8_t*>(wet + er * 128 + ks * 32 + kg * 8);
        acc = __builtin_amdgcn_mfma_f32_16x16x32_bf16(af, bfr, acc, 0, 0, 0);
    }
    int e0 = (int)blockE + wave * 16;
    int pos = 0;
    if (lane < 16) {
        int e = e0 + lane;
        int row = ei[e], col = ei[NEDGES + e];
        pos = rowstart[row] + rank[e];
        col_sorted[pos] = col;
    }
    float beh = be[er & 7];
    #pragma unroll
    for (int r = 0; r < 4; ++r) {
        int pj = __shfl(pos, kg * 4 + r, 64);
        if (er < 8) ebs_sorted[(size_t)pj * 8 + er] = bfbits(acc[r] + beh);
    }
}

// ---------------- Fused attention: 8-deep batched prefetch flash aggregation ----------------
__global__ __launch_bounds__(256)
void attn_node_kernel(const int* __restrict__ rowstart, const int* __restrict__ col_sorted,
                      const ushort* __restrict__ ebs_sorted, const ushort* __restrict__ Qb,
                      const uint* __restrict__ KVp, ushort* __restrict__ agg) {
    int wave = threadIdx.x >> 6;
    int lane = threadIdx.x & 63;
    int n = blockIdx.x * 4 + wave;
    if (n >= NNODES) return;
    int s0 = rowstart[n], s1 = rowstart[n + 1];
    int h = lane >> 3;

    uint qu = *reinterpret_cast<const uint*>(Qb + (size_t)n * 128 + lane * 2);
    float q0 = lo16(qu), q1 = hi16(qu);

    float m = NEG_SENTINEL, ssum = 0.f, a0 = 0.f, a1 = 0.f;
    int p = s0;
    // 8-edge batches: all 16 loads issued before any compute
    for (; p + 8 <= s1; p += 8) {
        int cc[8]; uint2 kv[8]; float ebv[8], dd[8];
        #pragma unroll
        for (int i = 0; i < 8; ++i) cc[i] = col_sorted[p + i];
        #pragma unroll
        for (int i = 0; i < 8; ++i)
            kv[i] = *reinterpret_cast<const uint2*>(KVp + (size_t)cc[i] * 128 + lane * 2);
        #pragma unroll
        for (int i = 0; i < 8; ++i) ebv[i] = b2f(ebs_sorted[(size_t)(p + i) * 8 + h]);
        #pragma unroll
        for (int i = 0; i < 8; ++i) {
            float d = q0 * lo16(kv[i].x) + q1 * lo16(kv[i].y);
            d += __shfl_xor(d, 1, 64);
            d += __shfl_xor(d, 2, 64);
            d += __shfl_xor(d, 4, 64);
            dd[i] = d * 0.25f + ebv[i];
        }
        float mx = m;
        #pragma unroll
        for (int i = 0; i < 8; ++i) mx = fmaxf(mx, dd[i]);
        float sc = __expf(m - mx);
        float pv[8];
        #pragma unroll
        for (int i = 0; i < 8; ++i) pv[i] = __expf(dd[i] - mx);
        float psum = ((pv[0] + pv[1]) + (pv[2] + pv[3])) + ((pv[4] + pv[5]) + (pv[6] + pv[7]));
        float v0 = 0.f, v1 = 0.f;
        #pragma unroll
        for (int i = 0; i < 8; ++i) {
            v0 += pv[i] * hi16(kv[i].x);
            v1 += pv[i] * hi16(kv[i].y);
        }
        ssum = ssum * sc + psum;
        a0 = a0 * sc + v0;
        a1 = a1 * sc + v1;
        m = mx;
    }
    for (; p + 4 <= s1; p += 4) {
        int cc[4]; uint2 kv[4]; float ebv[4], dd[4];
        #pragma unroll
        for (int i = 0; i < 4; ++i) cc[i] = col_sorted[p + i];
        #pragma unroll
        for (int i = 0; i < 4; ++i)
            kv[i] = *reinterpret_cast<const uint2*>(KVp + (size_t)cc[i] * 128 + lane * 2);
        #pragma unroll
        for (int i = 0; i < 4; ++i) ebv[i] = b2f(ebs_sorted[(size_t)(p + i) * 8 + h]);
        #pragma unroll
        for (int i = 0; i < 4; ++i) {
            float d = q0 * lo16(kv[i].x) + q1 * lo16(kv[i].y);
            d += __shfl_xor(d, 1, 64);
            d += __shfl_xor(d, 2, 64);
            d += __shfl_xor(d, 4, 64);
            dd[i] = d * 0.25f + ebv[i];
        }
        float mx = fmaxf(fmaxf(fmaxf(dd[0], dd[1]), fmaxf(dd[2], dd[3])), m);
        float sc = __expf(m - mx);
        float p0 = __expf(dd[0] - mx), p1 = __expf(dd[1] - mx);
        float p2 = __expf(dd[2] - mx), p3 = __expf(dd[3] - mx);
        ssum = ssum * sc + ((p0 + p1) + (p2 + p3));
        a0 = a0 * sc + p0 * hi16(kv[0].x) + p1 * hi16(kv[1].x) + p2 * hi16(kv[2].x) + p3 * hi16(kv[3].x);
        a1 = a1 * sc + p0 * hi16(kv[0].y) + p1 * hi16(kv[1].y) + p2 * hi16(kv[2].y) + p3 * hi16(kv[3].y);
        m = mx;
    }
    for (; p < s1; ++p) {
        int c = col_sorted[p];
        uint2 kv = *reinterpret_cast<const uint2*>(KVp + (size_t)c * 128 + lane * 2);
        float eb = b2f(ebs_sorted[(size_t)p * 8 + h]);
        float d = q0 * lo16(kv.x) + q1 * lo16(kv.y);
        d += __shfl_xor(d, 1, 64);
        d += __shfl_xor(d, 2, 64);
        d += __shfl_xor(d, 4, 64);
        float s = d * 0.25f + eb;
        float mn = fmaxf(m, s);
        float sc = __expf(m - mn);
        float pv = __expf(s - mn);
        ssum = ssum * sc + pv;
        a0 = a0 * sc + pv * hi16(kv.x);
        a1 = a1 * sc + pv * hi16(kv.y);
        m = mn;
    }
    float inv = (ssum > 0.f) ? 1.0f / ssum : 0.f;
    reinterpret_cast<uint*>(agg + (size_t)n * 128)[lane] = pack2(a0 * inv, a1 * inv);
}

extern "C" void kernel_launch(void* const* d_in, const int* in_sizes, int n_in,
                              void* d_out, int out_size, void* d_ws, size_t ws_size,
                              hipStream_t stream) {
    const float* x   = (const float*)d_in[0];
    const int*   ei  = (const int*)d_in[1];
    const float* ea  = (const float*)d_in[2];
    const float* Wq  = (const float*)d_in[3];  const float* bq  = (const float*)d_in[4];
    const float* Wk  = (const float*)d_in[5];  const float* bk  = (const float*)d_in[6];
    const float* Wv  = (const float*)d_in[7];  const float* bv  = (const float*)d_in[8];
    const float* Wo  = (const float*)d_in[9];  const float* bo  = (const float*)d_in[10];
    const float* We  = (const float*)d_in[11]; const float* be  = (const float*)d_in[12];
    const float* W1  = (const float*)d_in[13]; const float* bf1 = (const float*)d_in[14];
    const float* W2  = (const float*)d_in[15]; const float* bf2 = (const float*)d_in[16];
    const float* g1  = (const float*)d_in[17]; const float* b1  = (const float*)d_in[18];
    const float* g2  = (const float*)d_in[19]; const float* b2  = (const float*)d_in[20];

    char* base = (char*)d_ws;
    ushort* agg       = (ushort*)(base);               // bf16 [N,128] = 12.8 MB
    ushort* Qb        = (ushort*)(base + 12800000);    // bf16 [N,128] = 12.8 MB
    uint*   KVp       = (uint*)(base + 25600000);      // uint [N,128] = 25.6 MB (K lo | V hi)
    ushort* ebs_sorted= (ushort*)(base + 51200000);    // bf16 [E,8] = 12.8 MB (CSR order)
    int*    col_sorted= (int*)(base + 64000000);       // [E] = 3.2 MB
    int*    rank      = (int*)(base + 67200000);       // [E] = 3.2 MB
    int*    counts    = (int*)(base + 70400000);       // [N]
    int*    rowstart  = (int*)(base + 70600000);       // [N+1]
    ushort* wt4       = (ushort*)(base + 70800016);    // [512][128] (Wq|Wk|Wv|Wo)^T
    ushort* w1t       = (ushort*)(base + 70931088);    // [512][128]
    ushort* w2t       = (ushort*)(base + 71062160);    // [128][512]
    ushort* wet       = (ushort*)(base + 71193232);    // [16][128]
    float*  b384      = (float*)(base + 71197328);     // [384]
    int*    blocksum  = (int*)(base + 71198864);       // [196]
    int*    blockoff  = (int*)(base + 71199648);       // [196]
    // peak ~71.2 MB

    hipMemsetAsync(counts, 0, (size_t)NNODES * 4, stream);

    setup_kernel<<<NEDGES / 256 + 778, 256, 0, stream>>>(ei, counts, rank, Wq, Wk, Wv, Wo,
                                                         W1, W2, We, bq, bk, bv,
                                                         wt4, w1t, w2t, wet, b384);

    dim3 g128((NNODES + 63) / 64, 1);
    ln_qkv_kernel<<<g128, 256, 0, stream>>>(x, g1, b1, wt4, b384, Qb, KVp, NNODES);

    scan_ph1<<<SCAN_BLOCKS, 256, 0, stream>>>(counts, rowstart, blocksum);
    scan_ph2<<<1, 256, 0, stream>>>(blocksum, blockoff, rowstart);
    scan_ph3<<<SCAN_BLOCKS, 256, 0, stream>>>(rowstart, blockoff);

    edge_bias_scatter<<<NEDGES / 64, 256, 0, stream>>>(ea, wet, be, ei, rowstart, rank,
                                                       ebs_sorted, col_sorted);
    attn_node_kernel<<<(NNODES + 3) / 4, 256, 0, stream>>>(rowstart, col_sorted, ebs_sorted,
                                                           Qb, KVp, agg);

    wo_ffn_kernel<<<g128, 256, 0, stream>>>(agg, wt4 + 49152, bo, x, g2, b2,
                                            w1t, bf1, w2t, bf2, (float*)d_out, NNODES);
}

// Round 11
// 455.720 us; speedup vs baseline: 4.5994x; 1.0068x over previous
//
#include <hip/hip_runtime.h>
#include <hip/hip_bf16.h>
#include <math.h>

#define NNODES 50000
#define NEDGES 800000
#define DIM 128
#define NH 8

#define NEG_SENTINEL -3.0e38f

typedef __attribute__((ext_vector_type(8))) short bf16x8_t;
typedef __attribute__((ext_vector_type(4))) float f32x4_t;

__device__ __forceinline__ float gelu_exact(float v) {
    return 0.5f * v * (1.0f + erff(v * 0.70710678118654752f));
}
__device__ __forceinline__ ushort bfbits(float f) {
    uint u = __float_as_uint(f);
    u += 0x7fffu + ((u >> 16) & 1u);
    return (ushort)(u >> 16);
}
__device__ __forceinline__ uint pack2(float a, float b) {
    return (uint)bfbits(a) | ((uint)bfbits(b) << 16);
}
__device__ __forceinline__ float lo16(uint u) { return __uint_as_float(u << 16); }
__device__ __forceinline__ float hi16(uint u) { return __uint_as_float(u & 0xffff0000u); }
__device__ __forceinline__ float b2f(ushort u) { return __uint_as_float(((uint)u) << 16); }

// ---------------- setup: edge histogram (+rank) + weight transpose/convert + bias pack ----------------
__global__ void setup_kernel(const int* __restrict__ ei, int* __restrict__ counts,
                             int* __restrict__ rank,
                             const float* __restrict__ Wq, const float* __restrict__ Wk,
                             const float* __restrict__ Wv, const float* __restrict__ Wo,
                             const float* __restrict__ W1, const float* __restrict__ W2,
                             const float* __restrict__ We,
                             const float* __restrict__ bq, const float* __restrict__ bk,
                             const float* __restrict__ bv,
                             ushort* __restrict__ wt4, ushort* __restrict__ w1t,
                             ushort* __restrict__ w2t, ushort* __restrict__ wet,
                             float* __restrict__ b384) {
    int b = blockIdx.x;
    if (b < NEDGES / 256) {
        int e = b * 256 + threadIdx.x;
        rank[e] = atomicAdd(&counts[ei[e]], 1);   // rank within row (order arbitrary)
        return;
    }
    int i = (b - NEDGES / 256) * 256 + threadIdx.x;
    if (i < 65536) {
        int w = i >> 14, j = i & 16383;
        int c = j >> 7, k = j & 127;
        const float* src = (w == 0) ? Wq : (w == 1) ? Wk : (w == 2) ? Wv : Wo;
        wt4[i] = bfbits(src[k * 128 + c]);
    } else if (i < 131072) {
        int j = i - 65536;
        int c = j >> 7, k = j & 127;
        w1t[j] = bfbits(W1[k * 512 + c]);
    } else if (i < 196608) {
        int j = i - 131072;
        int c = j >> 9, k = j & 511;
        w2t[j] = bfbits(W2[k * 128 + c]);
    } else if (i < 198656) {
        int j = i - 196608;
        int h = j >> 7, k = j & 127;
        wet[j] = (h < 8) ? bfbits(We[k * 8 + h]) : (ushort)0;
    } else if (i < 198656 + 384) {
        int j = i - 198656;
        b384[j] = (j < 128) ? bq[j] : (j < 256) ? bk[j - 128] : bv[j - 256];
    }
}

// ---------------- Fused LN1 + QKV GEMM (LN: 4 rows in parallel per wave) ----------------
__global__ __launch_bounds__(256)
void ln_qkv_kernel(const float* __restrict__ x, const float* __restrict__ g1,
                   const float* __restrict__ b1, const ushort* __restrict__ wt4,
                   const float* __restrict__ b384, ushort* __restrict__ Qb,
                   uint* __restrict__ KVp, int M) {
    __shared__ ushort An[64 * 128];   // swizzled bf16 xn tile
    int tid = threadIdx.x, lane = tid & 63, wave = tid >> 6;
    int row0b = blockIdx.x * 64;
    int sr = lane >> 4;               // subrow 0..3
    int sl = lane & 15;               // sublane: dims 8*sl..8*sl+7
    float4 ga = reinterpret_cast<const float4*>(g1)[sl * 2];
    float4 gb = reinterpret_cast<const float4*>(g1)[sl * 2 + 1];
    float4 ba = reinterpret_cast<const float4*>(b1)[sl * 2];
    float4 bbv = reinterpret_cast<const float4*>(b1)[sl * 2 + 1];
    #pragma unroll
    for (int g = 0; g < 4; ++g) {
        int rl = wave * 16 + g * 4 + sr;
        int srow = min(row0b + rl, M - 1);
        const float4* xp = reinterpret_cast<const float4*>(x + (size_t)srow * 128 + sl * 8);
        float4 a = xp[0], b = xp[1];
        float s  = ((a.x + a.y) + (a.z + a.w)) + ((b.x + b.y) + (b.z + b.w));
        float sq = ((a.x*a.x + a.y*a.y) + (a.z*a.z + a.w*a.w)) +
                   ((b.x*b.x + b.y*b.y) + (b.z*b.z + b.w*b.w));
        #pragma unroll
        for (int mm = 1; mm < 16; mm <<= 1) {
            s  += __shfl_xor(s, mm, 64);
            sq += __shfl_xor(sq, mm, 64);
        }
        float mean = s * (1.0f / DIM);
        float var  = sq * (1.0f / DIM) - mean * mean;
        float rs = rsqrtf(var + 1e-5f);
        uint4 pk;
        pk.x = pack2((a.x - mean) * rs * ga.x + ba.x, (a.y - mean) * rs * ga.y + ba.y);
        pk.y = pack2((a.z - mean) * rs * ga.z + ba.z, (a.w - mean) * rs * ga.w + ba.w);
        pk.z = pack2((b.x - mean) * rs * gb.x + bbv.x, (b.y - mean) * rs * gb.y + bbv.y);
        pk.w = pack2((b.z - mean) * rs * gb.z + bbv.z, (b.w - mean) * rs * gb.w + bbv.w);
        int byte = rl * 256 + ((sl * 16) ^ ((rl & 7) << 4));
        *reinterpret_cast<uint4*>(reinterpret_cast<char*>(An) + byte) = pk;
    }
    __syncthreads();
    int er = lane & 15, kg = lane >> 4;
    int lrow = wave * 16 + er;
    int rsw = (er & 7) << 4;
    f32x4_t acc[24];
    #pragma unroll
    for (int f = 0; f < 24; ++f) acc[f] = (f32x4_t){0.f, 0.f, 0.f, 0.f};
    #pragma unroll
    for (int ks = 0; ks < 4; ++ks) {
        int k2 = ks * 64 + kg * 16;
        bf16x8_t af = *reinterpret_cast<const bf16x8_t*>(
            reinterpret_cast<char*>(An) + lrow * 256 + (k2 ^ rsw));
        #pragma unroll
        for (int f = 0; f < 24; ++f) {
            bf16x8_t bfr = *reinterpret_cast<const bf16x8_t*>(wt4 + (size_t)(f * 16 + er) * 128 + ks * 32 + kg * 8);
            acc[f] = __builtin_amdgcn_mfma_f32_16x16x32_bf16(af, bfr, acc[f], 0, 0, 0);
        }
    }
    #pragma unroll
    for (int f = 0; f < 24; ++f) {
        int col = f * 16 + er;
        float bc = b384[col];
        #pragma unroll
        for (int r = 0; r < 4; ++r) {
            int row = row0b + wave * 16 + kg * 4 + r;
            if (row < M) {
                float v = acc[f][r] + bc;
                if (col < 128) {
                    Qb[(size_t)row * 128 + col] = bfbits(v);
                } else if (col < 256) {
                    reinterpret_cast<ushort*>(KVp + (size_t)row * 128 + (col - 128))[0] = bfbits(v);
                } else {
                    reinterpret_cast<ushort*>(KVp + (size_t)row * 128 + (col - 256))[1] = bfbits(v);
                }
            }
        }
    }
}

// ---------------- Merged Wo + residual + LN2 + FFN (x1 in regs, H in LDS quarters) ----------------
__global__ __launch_bounds__(256)
void wo_ffn_kernel(const ushort* __restrict__ A, const ushort* __restrict__ woT,
                   const float* __restrict__ bo, const float* __restrict__ xres,
                   const float* __restrict__ g2, const float* __restrict__ b2,
                   const ushort* __restrict__ w1t, const float* __restrict__ bf1,
                   const ushort* __restrict__ w2t, const float* __restrict__ bf2,
                   float* __restrict__ out, int M) {
    __shared__ ushort An[64 * 128];
    __shared__ ushort Hb[64 * 128];
    int tid = threadIdx.x, lane = tid & 63, wave = tid >> 6;
    int row0 = blockIdx.x * 64 + wave * 16;
    int er = lane & 15, kg = lane >> 4;
    int arow = min(row0 + er, M - 1);

    f32x4_t acc[8];
    #pragma unroll
    for (int f = 0; f < 8; ++f) acc[f] = (f32x4_t){0.f, 0.f, 0.f, 0.f};
    #pragma unroll
    for (int ks = 0; ks < 4; ++ks) {
        int k0 = ks * 32 + kg * 8;
        bf16x8_t af = *reinterpret_cast<const bf16x8_t*>(A + (size_t)arow * 128 + k0);
        #pragma unroll
        for (int f = 0; f < 8; ++f) {
            bf16x8_t bfr = *reinterpret_cast<const bf16x8_t*>(woT + (size_t)(f * 16 + er) * 128 + k0);
            acc[f] = __builtin_amdgcn_mfma_f32_16x16x32_bf16(af, bfr, acc[f], 0, 0, 0);
        }
    }
    float g2l[8], b2l[8];
    #pragma unroll
    for (int f = 0; f < 8; ++f) {
        int col = f * 16 + er;
        float bc = bo[col];
        g2l[f] = g2[col]; b2l[f] = b2[col];
        #pragma unroll
        for (int r = 0; r < 4; ++r) {
            int row = min(row0 + kg * 4 + r, M - 1);
            acc[f][r] += bc + xres[(size_t)row * 128 + col];
        }
    }
    #pragma unroll
    for (int r = 0; r < 4; ++r) {
        float s = 0.f, sq = 0.f;
        #pragma unroll
        for (int f = 0; f < 8; ++f) { s += acc[f][r]; sq += acc[f][r] * acc[f][r]; }
        #pragma unroll
        for (int m = 1; m < 16; m <<= 1) {
            s  += __shfl_xor(s, m, 64);
            sq += __shfl_xor(sq, m, 64);
        }
        float mean = s * (1.0f / DIM);
        float var  = sq * (1.0f / DIM) - mean * mean;
        float rs = rsqrtf(var + 1e-5f);
        int rl = wave * 16 + kg * 4 + r;
        #pragma unroll
        for (int f = 0; f < 8; ++f) {
            int col = f * 16 + er;
            float xv = (acc[f][r] - mean) * rs * g2l[f] + b2l[f];
            int byte = rl * 256 + ((col * 2) ^ ((rl & 7) << 4));
            *reinterpret_cast<ushort*>(reinterpret_cast<char*>(An) + byte) = bfbits(xv);
        }
    }
    __syncthreads();

    int lrow = wave * 16 + er;
    int rsw = (lrow & 7) << 4;
    f32x4_t acc2[8];
    #pragma unroll
    for (int f = 0; f < 8; ++f) acc2[f] = (f32x4_t){0.f, 0.f, 0.f, 0.f};

    for (int q = 0; q < 4; ++q) {
        f32x4_t acch[8];
        #pragma unroll
        for (int f = 0; f < 8; ++f) acch[f] = (f32x4_t){0.f, 0.f, 0.f, 0.f};
        #pragma unroll
        for (int ks = 0; ks < 4; ++ks) {
            int k2 = ks * 64 + kg * 16;
            bf16x8_t af = *reinterpret_cast<const bf16x8_t*>(
                reinterpret_cast<char*>(An) + lrow * 256 + (k2 ^ rsw));
            #pragma unroll
            for (int f = 0; f < 8; ++f) {
                int c = q * 128 + f * 16 + er;
                bf16x8_t bfr = *reinterpret_cast<const bf16x8_t*>(w1t + (size_t)c * 128 + ks * 32 + kg * 8);
                acch[f] = __builtin_amdgcn_mfma_f32_16x16x32_bf16(af, bfr, acch[f], 0, 0, 0);
            }
        }
        #pragma unroll
        for (int f = 0; f < 8; ++f) {
            int colq = f * 16 + er;
            float bc = bf1[q * 128 + colq];
            #pragma unroll
            for (int r = 0; r < 4; ++r) {
                int rl2 = wave * 16 + kg * 4 + r;
                float hv = gelu_exact(acch[f][r] + bc);
                int byte = rl2 * 256 + ((colq * 2) ^ ((rl2 & 7) << 4));
                *reinterpret_cast<ushort*>(reinterpret_cast<char*>(Hb) + byte) = bfbits(hv);
            }
        }
        __syncthreads();
        #pragma unroll
        for (int ks2 = 0; ks2 < 4; ++ks2) {
            int k2 = ks2 * 64 + kg * 16;
            bf16x8_t af2 = *reinterpret_cast<const bf16x8_t*>(
                reinterpret_cast<char*>(Hb) + lrow * 256 + (k2 ^ rsw));
            #pragma unroll
            for (int f = 0; f < 8; ++f) {
                bf16x8_t bfr = *reinterpret_cast<const bf16x8_t*>(
                    w2t + (size_t)(f * 16 + er) * 512 + q * 128 + ks2 * 32 + kg * 8);
                acc2[f] = __builtin_amdgcn_mfma_f32_16x16x32_bf16(af2, bfr, acc2[f], 0, 0, 0);
            }
        }
        __syncthreads();
    }
    #pragma unroll
    for (int f = 0; f < 8; ++f) {
        int col = f * 16 + er;
        float bc = bf2[col];
        #pragma unroll
        for (int r = 0; r < 4; ++r) {
            int row = row0 + kg * 4 + r;
            if (row < M) out[(size_t)row * 128 + col] = acc2[f][r] + bc + acc[f][r];
        }
    }
}

// ---------------- 2-phase scan (ph3 folded into consumers via blockoff) ----------------
#define SCAN_BLOCKS ((NNODES + 255) / 256)   // 196
__global__ void scan_ph1(const int* __restrict__ counts, int* __restrict__ rowstart,
                         int* __restrict__ blocksum) {
    __shared__ int sh[256];
    int t = threadIdx.x, i = blockIdx.x * 256 + t;
    int c = (i < NNODES) ? counts[i] : 0;
    sh[t] = c; __syncthreads();
    int v = c;
    #pragma unroll
    for (int off = 1; off < 256; off <<= 1) {
        int u = (t >= off) ? sh[t - off] : 0;
        __syncthreads();
        v += u; sh[t] = v;
        __syncthreads();
    }
    if (i < NNODES) rowstart[i] = v - c;
    if (t == 255) blocksum[blockIdx.x] = v;
}
__global__ void scan_ph2(const int* __restrict__ blocksum, int* __restrict__ blockoff) {
    __shared__ int sh[256];
    int t = threadIdx.x;
    int c = (t < SCAN_BLOCKS) ? blocksum[t] : 0;
    sh[t] = c; __syncthreads();
    int v = c;
    #pragma unroll
    for (int off = 1; off < 256; off <<= 1) {
        int u = (t >= off) ? sh[t - off] : 0;
        __syncthreads();
        v += u; sh[t] = v;
        __syncthreads();
    }
    if (t < SCAN_BLOCKS) blockoff[t] = v - c;
}

// ---------------- Edge bias + CSR scatter (grid-stride, reg double-buffered stream) ----------------
#define EB_TILES (NEDGES / 64)   // 12500
__global__ __launch_bounds__(256)
void edge_bias_scatter(const float* __restrict__ EA, const ushort* __restrict__ wet,
                       const float* __restrict__ be, const int* __restrict__ ei,
                       const int* __restrict__ rowstart, const int* __restrict__ blockoff,
                       const int* __restrict__ rank,
                       ushort* __restrict__ ebs_sorted, int* __restrict__ col_sorted) {
    __shared__ ushort lds[64 * 128];
    int tid = threadIdx.x, lane = tid & 63, wave = tid >> 6;
    int er = lane & 15, kg = lane >> 4;
    int lrow = wave * 16 + er;
    float beh = be[er & 7];
    int stride = gridDim.x;
    int tile = blockIdx.x;
    float4 r[8];
    if (tile < EB_TILES) {
        const float4* src = reinterpret_cast<const float4*>(EA + (size_t)tile * 64 * 128);
        #pragma unroll
        for (int it = 0; it < 8; ++it) r[it] = src[it * 256 + tid];
    }
    for (; tile < EB_TILES; tile += stride) {
        // drain prev iter's LDS readers before overwrite handled by loop-end barrier
        #pragma unroll
        for (int it = 0; it < 8; ++it) {
            int idx = it * 256 + tid;
            int elem = idx * 4;
            int row = elem >> 7, col = elem & 127;
            uint2 pk;
            pk.x = pack2(r[it].x, r[it].y);
            pk.y = pack2(r[it].z, r[it].w);
            int byte = row * 256 + ((col * 2) ^ ((row & 7) << 4));
            *reinterpret_cast<uint2*>(reinterpret_cast<char*>(lds) + byte) = pk;
        }
        __syncthreads();
        // prefetch next tile while computing this one
        int ntile = tile + stride;
        if (ntile < EB_TILES) {
            const float4* src = reinterpret_cast<const float4*>(EA + (size_t)ntile * 64 * 128);
            #pragma unroll
            for (int it = 0; it < 8; ++it) r[it] = src[it * 256 + tid];
        }
        f32x4_t acc = (f32x4_t){0.f, 0.f, 0.f, 0.f};
        #pragma unroll
        for (int ks = 0; ks < 4; ++ks) {
            int cb = (ks * 64 + kg * 16) ^ ((er & 7) << 4);
            bf16x8_t af = *reinterpret_cast<const bf16x8_t*>(
                reinterpret_cast<char*>(lds) + lrow * 256 + cb);
            bf16x8_t bfr = *reinterpret_cast<const bf16x8_t*>(wet + er * 128 + ks * 32 + kg * 8);
            acc = __builtin_amdgcn_mfma_f32_16x16x32_bf16(af, bfr, acc, 0, 0, 0);
        }
        int e0 = tile * 64 + wave * 16;
        int pos = 0;
        if (lane < 16) {
            int e = e0 + lane;
            int row = ei[e], col = ei[NEDGES + e];
            pos = rowstart[row] + blockoff[row >> 8] + rank[e];
            col_sorted[pos] = col;
        }
        #pragma unroll
        for (int rr = 0; rr < 4; ++rr) {
            int pj = __shfl(pos, kg * 4 + rr, 64);
            if (er < 8) ebs_sorted[(size_t)pj * 8 + er] = bfbits(acc[rr] + beh);
        }
        __syncthreads();
    }
}

// ---------------- Fused attention: 8-deep batched prefetch flash aggregation ----------------
__global__ __launch_bounds__(256)
void attn_node_kernel(const int* __restrict__ rowstart, const int* __restrict__ blockoff,
                      const int* __restrict__ col_sorted,
                      const ushort* __restrict__ ebs_sorted, const ushort* __restrict__ Qb,
                      const uint* __restrict__ KVp, ushort* __restrict__ agg) {
    int wave = threadIdx.x >> 6;
    int lane = threadIdx.x & 63;
    int n = blockIdx.x * 4 + wave;
    if (n >= NNODES) return;
    int s0 = rowstart[n] + blockoff[n >> 8];
    int s1 = (n + 1 == NNODES) ? NEDGES : rowstart[n + 1] + blockoff[(n + 1) >> 8];
    int h = lane >> 3;

    uint qu = *reinterpret_cast<const uint*>(Qb + (size_t)n * 128 + lane * 2);
    float q0 = lo16(qu), q1 = hi16(qu);

    float m = NEG_SENTINEL, ssum = 0.f, a0 = 0.f, a1 = 0.f;
    int p = s0;
    for (; p + 8 <= s1; p += 8) {
        int cc[8]; uint2 kv[8]; float ebv[8], dd[8];
        #pragma unroll
        for (int i = 0; i < 8; ++i) cc[i] = col_sorted[p + i];
        #pragma unroll
        for (int i = 0; i < 8; ++i)
            kv[i] = *reinterpret_cast<const uint2*>(KVp + (size_t)cc[i] * 128 + lane * 2);
        #pragma unroll
        for (int i = 0; i < 8; ++i) ebv[i] = b2f(ebs_sorted[(size_t)(p + i) * 8 + h]);
        #pragma unroll
        for (int i = 0; i < 8; ++i) {
            float d = q0 * lo16(kv[i].x) + q1 * lo16(kv[i].y);
            d += __shfl_xor(d, 1, 64);
            d += __shfl_xor(d, 2, 64);
            d += __shfl_xor(d, 4, 64);
            dd[i] = d * 0.25f + ebv[i];
        }
        float mx = m;
        #pragma unroll
        for (int i = 0; i < 8; ++i) mx = fmaxf(mx, dd[i]);
        float sc = __expf(m - mx);
        float pv[8];
        #pragma unroll
        for (int i = 0; i < 8; ++i) pv[i] = __expf(dd[i] - mx);
        float psum = ((pv[0] + pv[1]) + (pv[2] + pv[3])) + ((pv[4] + pv[5]) + (pv[6] + pv[7]));
        float v0 = 0.f, v1 = 0.f;
        #pragma unroll
        for (int i = 0; i < 8; ++i) {
            v0 += pv[i] * hi16(kv[i].x);
            v1 += pv[i] * hi16(kv[i].y);
        }
        ssum = ssum * sc + psum;
        a0 = a0 * sc + v0;
        a1 = a1 * sc + v1;
        m = mx;
    }
    for (; p + 4 <= s1; p += 4) {
        int cc[4]; uint2 kv[4]; float ebv[4], dd[4];
        #pragma unroll
        for (int i = 0; i < 4; ++i) cc[i] = col_sorted[p + i];
        #pragma unroll
        for (int i = 0; i < 4; ++i)
            kv[i] = *reinterpret_cast<const uint2*>(KVp + (size_t)cc[i] * 128 + lane * 2);
        #pragma unroll
        for (int i = 0; i < 4; ++i) ebv[i] = b2f(ebs_sorted[(size_t)(p + i) * 8 + h]);
        #pragma unroll
        for (int i = 0; i < 4; ++i) {
            float d = q0 * lo16(kv[i].x) + q1 * lo16(kv[i].y);
            d += __shfl_xor(d, 1, 64);
            d += __shfl_xor(d, 2, 64);
            d += __shfl_xor(d, 4, 64);
            dd[i] = d * 0.25f + ebv[i];
        }
        float mx = fmaxf(fmaxf(fmaxf(dd[0], dd[1]), fmaxf(dd[2], dd[3])), m);
        float sc = __expf(m - mx);
        float p0 = __expf(dd[0] - mx), p1 = __expf(dd[1] - mx);
        float p2 = __expf(dd[2] - mx), p3 = __expf(dd[3] - mx);
        ssum = ssum * sc + ((p0 + p1) + (p2 + p3));
        a0 = a0 * sc + p0 * hi16(kv[0].x) + p1 * hi16(kv[1].x) + p2 * hi16(kv[2].x) + p3 * hi16(kv[3].x);
        a1 = a1 * sc + p0 * hi16(kv[0].y) + p1 * hi16(kv[1].y) + p2 * hi16(kv[2].y) + p3 * hi16(kv[3].y);
        m = mx;
    }
    for (; p < s1; ++p) {
        int c = col_sorted[p];
        uint2 kv = *reinterpret_cast<const uint2*>(KVp + (size_t)c * 128 + lane * 2);
        float eb = b2f(ebs_sorted[(size_t)p * 8 + h]);
        float d = q0 * lo16(kv.x) + q1 * lo16(kv.y);
        d += __shfl_xor(d, 1, 64);
        d += __shfl_xor(d, 2, 64);
        d += __shfl_xor(d, 4, 64);
        float s = d * 0.25f + eb;
        float mn = fmaxf(m, s);
        float sc = __expf(m - mn);
        float pv = __expf(s - mn);
        ssum = ssum * sc + pv;
        a0 = a0 * sc + pv * hi16(kv.x);
        a1 = a1 * sc + pv * hi16(kv.y);
        m = mn;
    }
    float inv = (ssum > 0.f) ? 1.0f / ssum : 0.f;
    reinterpret_cast<uint*>(agg + (size_t)n * 128)[lane] = pack2(a0 * inv, a1 * inv);
}

extern "C" void kernel_launch(void* const* d_in, const int* in_sizes, int n_in,
                              void* d_out, int out_size, void* d_ws, size_t ws_size,
                              hipStream_t stream) {
    const float* x   = (const float*)d_in[0];
    const int*   ei  = (const int*)d_in[1];
    const float* ea  = (const float*)d_in[2];
    const float* Wq  = (const float*)d_in[3];  const float* bq  = (const float*)d_in[4];
    const float* Wk  = (const float*)d_in[5];  const float* bk  = (const float*)d_in[6];
    const float* Wv  = (const float*)d_in[7];  const float* bv  = (const float*)d_in[8];
    const float* Wo  = (const float*)d_in[9];  const float* bo  = (const float*)d_in[10];
    const float* We  = (const float*)d_in[11]; const float* be  = (const float*)d_in[12];
    const float* W1  = (const float*)d_in[13]; const float* bf1 = (const float*)d_in[14];
    const float* W2  = (const float*)d_in[15]; const float* bf2 = (const float*)d_in[16];
    const float* g1  = (const float*)d_in[17]; const float* b1  = (const float*)d_in[18];
    const float* g2  = (const float*)d_in[19]; const float* b2  = (const float*)d_in[20];

    char* base = (char*)d_ws;
    ushort* agg       = (ushort*)(base);               // bf16 [N,128] = 12.8 MB
    ushort* Qb        = (ushort*)(base + 12800000);    // bf16 [N,128] = 12.8 MB
    uint*   KVp       = (uint*)(base + 25600000);      // uint [N,128] = 25.6 MB (K lo | V hi)
    ushort* ebs_sorted= (ushort*)(base + 51200000);    // bf16 [E,8] = 12.8 MB (CSR order)
    int*    col_sorted= (int*)(base + 64000000);       // [E] = 3.2 MB
    int*    rank      = (int*)(base + 67200000);       // [E] = 3.2 MB
    int*    counts    = (int*)(base + 70400000);       // [N]
    int*    rowstart  = (int*)(base + 70600000);       // [N]
    ushort* wt4       = (ushort*)(base + 70800016);    // [512][128] (Wq|Wk|Wv|Wo)^T
    ushort* w1t       = (ushort*)(base + 70931088);    // [512][128]
    ushort* w2t       = (ushort*)(base + 71062160);    // [128][512]
    ushort* wet       = (ushort*)(base + 71193232);    // [16][128]
    float*  b384      = (float*)(base + 71197328);     // [384]
    int*    blocksum  = (int*)(base + 71198864);       // [196]
    int*    blockoff  = (int*)(base + 71199648);       // [196]
    // peak ~71.2 MB

    hipMemsetAsync(counts, 0, (size_t)NNODES * 4, stream);

    setup_kernel<<<NEDGES / 256 + 778, 256, 0, stream>>>(ei, counts, rank, Wq, Wk, Wv, Wo,
                                                         W1, W2, We, bq, bk, bv,
                                                         wt4, w1t, w2t, wet, b384);

    dim3 g128((NNODES + 63) / 64, 1);
    ln_qkv_kernel<<<g128, 256, 0, stream>>>(x, g1, b1, wt4, b384, Qb, KVp, NNODES);

    scan_ph1<<<SCAN_BLOCKS, 256, 0, stream>>>(counts, rowstart, blocksum);
    scan_ph2<<<1, 256, 0, stream>>>(blocksum, blockoff);

    edge_bias_scatter<<<2048, 256, 0, stream>>>(ea, wet, be, ei, rowstart, blockoff, rank,
                                                ebs_sorted, col_sorted);
    attn_node_kernel<<<(NNODES + 3) / 4, 256, 0, stream>>>(rowstart, blockoff, col_sorted,
                                                           ebs_sorted, Qb, KVp, agg);

    wo_ffn_kernel<<<g128, 256, 0, stream>>>(agg, wt4 + 49152, bo, x, g2, b2,
                                            w1t, bf1, w2t, bf2, (float*)d_out, NNODES);
}